// Round 1
// baseline (13695.657 us; speedup 1.0000x reference)
//
#include <hip/hip_runtime.h>

// ============================================================================
// numpy RNG replication: SeedSequence + PCG64 (XSL-RR 128/64), next32 buffering
// ============================================================================
struct U128 { unsigned long long hi, lo; };

__device__ __forceinline__ U128 u128_mul(U128 a, U128 b) {
  U128 r;
  r.lo = a.lo * b.lo;
  r.hi = __umul64hi(a.lo, b.lo) + a.hi * b.lo + a.lo * b.hi;
  return r;
}
__device__ __forceinline__ U128 u128_add(U128 a, U128 b) {
  U128 r; r.lo = a.lo + b.lo; r.hi = a.hi + b.hi + (r.lo < a.lo ? 1ull : 0ull); return r;
}

struct Pcg64 {
  U128 state, inc;
  unsigned int cached; int has;
};

__device__ __forceinline__ void pcg_step(Pcg64* r) {
  const U128 M = {0x2360ed051fc65da4ull, 0x4385df649fccf645ull};
  r->state = u128_add(u128_mul(r->state, M), r->inc);
}
__device__ __forceinline__ unsigned long long pcg_next64(Pcg64* r) {
  pcg_step(r);
  unsigned int rot = (unsigned int)(r->state.hi >> 58);   // state >> 122
  unsigned long long x = r->state.hi ^ r->state.lo;       // XSL
  return (x >> rot) | (x << ((64u - rot) & 63u));         // RR
}
__device__ __forceinline__ unsigned int pcg_next32(Pcg64* r) {
  if (r->has) { r->has = 0; return r->cached; }
  unsigned long long n = pcg_next64(r);
  r->has = 1; r->cached = (unsigned int)(n >> 32);
  return (unsigned int)n;     // low 32 first (numpy pcg64_next32)
}

// SeedSequence constants (numpy bit_generator.pyx)
__device__ __forceinline__ unsigned int ss_hashmix(unsigned int v, unsigned int* hc) {
  v ^= *hc; *hc = *hc * 0x931e8875u; v *= *hc; v ^= v >> 16; return v;
}
__device__ __forceinline__ unsigned int ss_mix(unsigned int x, unsigned int y) {
  unsigned int r = x * 0xca01f9ddu ^ y * 0x4973f715u; r ^= r >> 16; return r;
}
__device__ void pcg_seed(Pcg64* rng, unsigned int seed) {
  unsigned int pool[4]; unsigned int hc = 0x43b0d7e5u;   // INIT_A
  pool[0] = ss_hashmix(seed, &hc);
  for (int i = 1; i < 4; ++i) pool[i] = ss_hashmix(0u, &hc);
  for (int s = 0; s < 4; ++s)
    for (int d = 0; d < 4; ++d)
      if (s != d) pool[d] = ss_mix(pool[d], ss_hashmix(pool[s], &hc));
  // generate_state(4, uint64): 8 uint32 words, cycling pool, paired little-endian
  unsigned int hc2 = 0x8b51f9ddu;                        // INIT_B
  unsigned long long w64[4];
  for (int i = 0; i < 4; ++i) {
    unsigned int lo = pool[(2*i) & 3];
    lo ^= hc2; hc2 *= 0x58f38dedu; lo *= hc2; lo ^= lo >> 16;
    unsigned int hi = pool[(2*i+1) & 3];
    hi ^= hc2; hc2 *= 0x58f38dedu; hi *= hc2; hi ^= hi >> 16;
    w64[i] = (unsigned long long)lo | ((unsigned long long)hi << 32);
  }
  U128 initstate = {w64[0], w64[1]};   // PCG_128BIT_CONSTANT(seed[0], seed[1]): [0] is HIGH
  U128 initseq   = {w64[2], w64[3]};
  rng->inc.hi = (initseq.hi << 1) | (initseq.lo >> 63);
  rng->inc.lo = (initseq.lo << 1) | 1ull;
  rng->state.hi = 0; rng->state.lo = 0;
  pcg_step(rng);
  rng->state = u128_add(rng->state, initstate);
  pcg_step(rng);
  rng->has = 0; rng->cached = 0;
}

// ============================================================================
// Problem constants
// ============================================================================
#define S_LEN   16384
#define Q_LEN   65536
#define Q_TOT   327680     // 5*65536
#define DFEAT   256
#define MAXS    256

// meta layout: [0..4]=ns_full, [5..9]=nq_full, [10..14]=na, [15..19]=nb

// ============================================================================
// K1: collect class index lists (in reference order) + generate Fisher-Yates
//     j-sequence for i in [256, n)  (only these affect the first-256 SET)
// ============================================================================
__global__ __launch_bounds__(64) void k_collect(const int* __restrict__ ls,
                                                const int* __restrict__ lq,
                                                int* meta, int* sup_list, int* qry_list,
                                                int* Jsup, int* Jqry) {
  int t = blockIdx.x; int lane = threadIdx.x;
  int cls = t % 5; int isq = t / 5;
  const int* src; int n_src, matchval; int* out; int* J;
  if (!isq) { src = ls + cls * S_LEN; n_src = S_LEN; matchval = 1;
              out = sup_list + cls * S_LEN; J = Jsup + cls * S_LEN; }
  else      { src = lq; n_src = Q_TOT; matchval = cls + 1;
              out = qry_list + (size_t)cls * Q_TOT; J = Jqry + (size_t)cls * Q_TOT; }
  int base = 0;
  unsigned long long lmask = (1ull << lane) - 1ull;
  for (int i0 = 0; i0 < n_src; i0 += 64) {
    int i = i0 + lane;
    int val = (i < n_src) ? src[i] : -1;
    bool p = (val == matchval);
    unsigned long long m = __ballot(p);
    if (p) out[base + __popcll(m & lmask)] = i;
    base += __popcll(m);
  }
  if (lane == 0) {
    meta[isq * 5 + cls] = base;
    meta[10 + isq * 5 + cls] = base < MAXS ? base : MAXS;
    if (base > MAXS) {
      Pcg64 rng; pcg_seed(&rng, (unsigned)(1000 + isq * 1000 + cls + 1));
      for (int i = base - 1; i >= MAXS; --i) {
        unsigned int mask = (unsigned int)i;
        mask |= mask >> 1; mask |= mask >> 2; mask |= mask >> 4;
        mask |= mask >> 8; mask |= mask >> 16;
        unsigned int v;
        do { v = pcg_next32(&rng) & mask; } while (v > (unsigned int)i);
        J[i] = (int)v;
      }
    }
  }
}

// ============================================================================
// K2: provenance walk (reverse of FY execution order = i ascending 256..n-1):
//     each of 256 lanes tracks one window slot's origin position.
// ============================================================================
__global__ __launch_bounds__(256) void k_prov(const int* __restrict__ meta,
                                              const int* __restrict__ sup_list,
                                              const int* __restrict__ qry_list,
                                              const int* __restrict__ Jsup,
                                              const int* __restrict__ Jqry,
                                              int* sel) {
  int t = blockIdx.x; int tid = threadIdx.x;
  int cls = t % 5; int isq = t / 5;
  int n = meta[isq * 5 + cls];
  const int* list; const int* J;
  if (!isq) { list = sup_list + cls * S_LEN; J = Jsup + cls * S_LEN; }
  else      { list = qry_list + (size_t)cls * Q_TOT; J = Jqry + (size_t)cls * Q_TOT; }
  int* s = sel + t * MAXS;
  if (n <= MAXS) { if (tid < n) s[tid] = list[tid]; return; }
  int pos = tid;
  #pragma unroll 4
  for (int i = MAXS; i < n; ++i) {
    int jv = J[i];
    pos = (pos == i) ? jv : ((pos == jv) ? i : pos);
  }
  s[tid] = list[pos];
}

// ============================================================================
// K3: gather selected feature rows and row-normalize (x / (||x|| + 1e-12))
// ============================================================================
__global__ __launch_bounds__(256) void k_gather(const float* __restrict__ f_s,
                                                const float* __restrict__ f_q,
                                                const int* __restrict__ meta,
                                                const int* __restrict__ sel,
                                                float* xa, float* xb) {
  int t = blockIdx.x; int r = threadIdx.x;
  int cls = t % 5; int isq = t / 5;
  int n = meta[10 + isq * 5 + cls];
  if (r >= n) return;
  int id = sel[t * MAXS + r];
  const float* src; size_t stride; float* dst;
  if (!isq) {
    src = f_s + (size_t)cls * DFEAT * S_LEN + id; stride = S_LEN;
    dst = xa + cls * (MAXS * DFEAT) + r * DFEAT;
  } else {
    int m = id >> 16; int nn = id & 0xFFFF;
    src = f_q + (size_t)m * DFEAT * Q_LEN + nn; stride = Q_LEN;
    dst = xb + cls * (MAXS * DFEAT) + r * DFEAT;
  }
  float ss = 0.f;
  for (int d = 0; d < DFEAT; ++d) { float v = src[(size_t)d * stride]; ss += v * v; dst[d] = v; }
  float inv = 1.0f / (sqrtf(ss) + 1e-12f);
  for (int d = 0; d < DFEAT; ++d) dst[d] *= inv;
}

// ============================================================================
// K4: 35 Gram matrices (256x256, K=256): Ga[k]=xa_k xa_k^T, Gb[c], Gab[k,c]
// ============================================================================
__global__ __launch_bounds__(1024) void k_gram(const float* __restrict__ xa,
                                               const float* __restrict__ xb,
                                               float* Ga, float* Gb, float* Gab) {
  int j = blockIdx.x;
  const float *A, *B; float* G;
  if (j < 5)       { A = xa + j * 65536; B = A; G = Ga + j * 65536; }
  else if (j < 10) { int c = j - 5; A = xb + c * 65536; B = A; G = Gb + c * 65536; }
  else             { int p = j - 10; int k = p / 5, c = p % 5;
                     A = xa + k * 65536; B = xb + c * 65536; G = Gab + p * 65536; }
  __shared__ float As[256][17];
  __shared__ float Bs[256][17];
  int tid = threadIdx.x;
  int ti = tid >> 5, tj = tid & 31;
  float acc[8][8];
  #pragma unroll
  for (int r = 0; r < 8; ++r)
    #pragma unroll
    for (int s = 0; s < 8; ++s) acc[r][s] = 0.f;
  for (int k0 = 0; k0 < 256; k0 += 16) {
    #pragma unroll
    for (int e = 0; e < 4; ++e) {
      int idx = tid + e * 1024;
      int i = idx >> 4, kk = idx & 15;
      As[i][kk] = A[i * 256 + k0 + kk];
      Bs[i][kk] = B[i * 256 + k0 + kk];
    }
    __syncthreads();
    #pragma unroll
    for (int kk = 0; kk < 16; ++kk) {
      float a[8], b[8];
      #pragma unroll
      for (int r = 0; r < 8; ++r) a[r] = As[ti * 8 + r][kk];
      #pragma unroll
      for (int s = 0; s < 8; ++s) b[s] = Bs[tj * 8 + s][kk];
      #pragma unroll
      for (int r = 0; r < 8; ++r)
        #pragma unroll
        for (int s = 0; s < 8; ++s) acc[r][s] += a[r] * b[s];
    }
    __syncthreads();
  }
  #pragma unroll
  for (int r = 0; r < 8; ++r)
    #pragma unroll
    for (int s = 0; s < 8; ++s)
      G[(ti * 8 + r) * 256 + tj * 8 + s] = acc[r][s];
}

// ============================================================================
// K5: extract Gram diagonals (squared norms)
// ============================================================================
__global__ __launch_bounds__(256) void k_diag(const float* __restrict__ Ga,
                                              const float* __restrict__ Gb,
                                              float* diagA, float* diagB) {
  int t = blockIdx.x; int i = threadIdx.x;
  if (t < 5) diagA[t * 256 + i] = Ga[t * 65536 + i * 257];
  else { int c = t - 5; diagB[c * 256 + i] = Gb[c * 65536 + i * 257]; }
}

// ============================================================================
// K6: G -> D in place: D_ij = max(dA_i + dB_j - 2 g_ij, 0)  (diag exactly 0)
// ============================================================================
__global__ __launch_bounds__(256) void k_conv(float* Ga, float* Gb, float* Gab,
                                              const float* __restrict__ diagA,
                                              const float* __restrict__ diagB) {
  int j = blockIdx.x; int tid = threadIdx.x;
  float* G; const float *dA, *dB;
  if (j < 5)       { G = Ga + j * 65536; dA = diagA + j * 256; dB = dA; }
  else if (j < 10) { int c = j - 5; G = Gb + c * 65536; dA = diagB + c * 256; dB = dA; }
  else             { int p = j - 10; int k = p / 5, c = p % 5;
                     G = Gab + p * 65536; dA = diagA + k * 256; dB = diagB + c * 256; }
  float db = dB[tid];
  for (int i = 0; i < 256; ++i) {
    float g = G[i * 256 + tid];
    float d = dA[i] + db - 2.0f * g;
    G[i * 256 + tid] = d > 0.f ? d : 0.f;
  }
}

// ============================================================================
// K7: per (k,c) pair: exact median (3-pass radix select over float bits, Dab
//     counted twice, nz = exact-zero count) -> sigma -> multi-sigma MMD^2
// ============================================================================
__global__ __launch_bounds__(256) void k_medmmd(const int* __restrict__ meta,
                                                const float* __restrict__ Da_all,
                                                const float* __restrict__ Db_all,
                                                const float* __restrict__ Dab_all,
                                                float* mmd_out) {
  int p = blockIdx.x; int kcl = p / 5, ccl = p % 5;
  int tid = threadIdx.x;
  int nsf = meta[kcl], nqf = meta[5 + ccl];
  if (nsf < 2 || nqf < 2) { if (tid == 0) mmd_out[p] = 0.0f; return; }
  int na = meta[10 + kcl], nb = meta[15 + ccl];
  const float* Da  = Da_all  + kcl * 65536;
  const float* Db  = Db_all  + ccl * 65536;
  const float* Dab = Dab_all + p * 65536;

  __shared__ unsigned int hist[2048];
  __shared__ unsigned int sh[8];   // 0:zcnt 1:allzero 2:b1 3:r1 4:b2 5:r2 6:medkey
  __shared__ double dred[256];

  unsigned int N = (unsigned int)(na + nb) * (unsigned int)(na + nb);

  // ---- pass 1: top 11 bits ----
  for (int b = tid; b < 2048; b += 256) hist[b] = 0;
  if (tid < 8) sh[tid] = 0;
  __syncthreads();
  for (int i = 0; i < na; ++i) if (tid < na) {
    unsigned int key = __float_as_uint(Da[i * 256 + tid]);
    atomicAdd(&hist[key >> 21], 1u);
    if (key == 0u) atomicAdd(&sh[0], 1u);
  }
  for (int i = 0; i < nb; ++i) if (tid < nb) {
    unsigned int key = __float_as_uint(Db[i * 256 + tid]);
    atomicAdd(&hist[key >> 21], 1u);
    if (key == 0u) atomicAdd(&sh[0], 1u);
  }
  for (int i = 0; i < na; ++i) if (tid < nb) {
    unsigned int key = __float_as_uint(Dab[i * 256 + tid]);
    atomicAdd(&hist[key >> 21], 2u);
    if (key == 0u) atomicAdd(&sh[0], 2u);
  }
  __syncthreads();
  if (tid == 0) {
    unsigned int nz = sh[0];
    if (nz >= N) sh[1] = 1u;
    else {
      unsigned int r = nz + (N - nz - 1u) / 2u;   // 0-based rank
      unsigned int cum = 0, bsel = 2047;
      for (int b = 0; b < 2048; ++b) {
        unsigned int nc = cum + hist[b];
        if (nc > r) { bsel = (unsigned int)b; break; }
        cum = nc;
      }
      sh[1] = 0u; sh[2] = bsel; sh[3] = r - cum;
    }
  }
  __syncthreads();
  float base;
  if (!sh[1]) {
    unsigned int b1 = sh[2];
    // ---- pass 2: next 11 bits ----
    for (int b = tid; b < 2048; b += 256) hist[b] = 0;
    __syncthreads();
    for (int i = 0; i < na; ++i) if (tid < na) {
      unsigned int key = __float_as_uint(Da[i * 256 + tid]);
      if ((key >> 21) == b1) atomicAdd(&hist[(key >> 10) & 0x7FFu], 1u);
    }
    for (int i = 0; i < nb; ++i) if (tid < nb) {
      unsigned int key = __float_as_uint(Db[i * 256 + tid]);
      if ((key >> 21) == b1) atomicAdd(&hist[(key >> 10) & 0x7FFu], 1u);
    }
    for (int i = 0; i < na; ++i) if (tid < nb) {
      unsigned int key = __float_as_uint(Dab[i * 256 + tid]);
      if ((key >> 21) == b1) atomicAdd(&hist[(key >> 10) & 0x7FFu], 2u);
    }
    __syncthreads();
    if (tid == 0) {
      unsigned int r = sh[3];
      unsigned int cum = 0, bsel = 2047;
      for (int b = 0; b < 2048; ++b) {
        unsigned int nc = cum + hist[b];
        if (nc > r) { bsel = (unsigned int)b; break; }
        cum = nc;
      }
      sh[4] = bsel; sh[5] = r - cum;
    }
    __syncthreads();
    unsigned int pref2 = (b1 << 11) | sh[4];
    // ---- pass 3: low 10 bits ----
    for (int b = tid; b < 1024; b += 256) hist[b] = 0;
    __syncthreads();
    for (int i = 0; i < na; ++i) if (tid < na) {
      unsigned int key = __float_as_uint(Da[i * 256 + tid]);
      if ((key >> 10) == pref2) atomicAdd(&hist[key & 0x3FFu], 1u);
    }
    for (int i = 0; i < nb; ++i) if (tid < nb) {
      unsigned int key = __float_as_uint(Db[i * 256 + tid]);
      if ((key >> 10) == pref2) atomicAdd(&hist[key & 0x3FFu], 1u);
    }
    for (int i = 0; i < na; ++i) if (tid < nb) {
      unsigned int key = __float_as_uint(Dab[i * 256 + tid]);
      if ((key >> 10) == pref2) atomicAdd(&hist[key & 0x3FFu], 2u);
    }
    __syncthreads();
    if (tid == 0) {
      unsigned int r = sh[5];
      unsigned int cum = 0, bsel = 1023;
      for (int b = 0; b < 1024; ++b) {
        unsigned int nc = cum + hist[b];
        if (nc > r) { bsel = (unsigned int)b; break; }
        cum = nc;
      }
      sh[6] = (pref2 << 10) | bsel;
    }
    __syncthreads();
    base = sqrtf(__uint_as_float(sh[6]) + 1e-6f);
  } else {
    base = 1.0f;
  }

  // ---- multi-sigma RBF sums:  sum_s exp(-d / (2 (base*s)^2)),  s in {.5,1,2,4}
  float g2 = base * base;
  float c0 = 1.0f / (2.0f * g2 * 0.25f);
  float c1 = 1.0f / (2.0f * g2 * 1.0f);
  float c2 = 1.0f / (2.0f * g2 * 4.0f);
  float c3 = 1.0f / (2.0f * g2 * 16.0f);
  double accA = 0.0, accB = 0.0, accAB = 0.0;
  for (int i = 0; i < na; ++i) if (tid < na) {
    float d = Da[i * 256 + tid];
    accA += (double)(expf(-d * c0) + expf(-d * c1) + expf(-d * c2) + expf(-d * c3));
  }
  for (int i = 0; i < nb; ++i) if (tid < nb) {
    float d = Db[i * 256 + tid];
    accB += (double)(expf(-d * c0) + expf(-d * c1) + expf(-d * c2) + expf(-d * c3));
  }
  for (int i = 0; i < na; ++i) if (tid < nb) {
    float d = Dab[i * 256 + tid];
    accAB += (double)(expf(-d * c0) + expf(-d * c1) + expf(-d * c2) + expf(-d * c3));
  }
  // block reductions
  dred[tid] = accA; __syncthreads();
  for (int s = 128; s > 0; s >>= 1) { if (tid < s) dred[tid] += dred[tid + s]; __syncthreads(); }
  double SA = dred[0]; __syncthreads();
  dred[tid] = accB; __syncthreads();
  for (int s = 128; s > 0; s >>= 1) { if (tid < s) dred[tid] += dred[tid + s]; __syncthreads(); }
  double SB = dred[0]; __syncthreads();
  dred[tid] = accAB; __syncthreads();
  for (int s = 128; s > 0; s >>= 1) { if (tid < s) dred[tid] += dred[tid + s]; __syncthreads(); }
  double SAB = dred[0];
  if (tid == 0) {
    double meanA  = SA  / ((double)na * (double)na);
    double meanB  = SB  / ((double)nb * (double)nb);
    double meanAB = SAB / ((double)na * (double)nb);
    double m = meanA + meanB - 2.0 * meanAB;
    mmd_out[p] = (float)(m > 0.0 ? m : 0.0);
  }
}

// ============================================================================
// K8: final weighted loss. pick = argmin_k mmd[k][c] (HARD_POOL >= #negs makes
//     the sig_pos pre-ranking irrelevant); loss_c = relu(pos - neg + 0.1)
// ============================================================================
__global__ void k_final(const int* __restrict__ meta, const float* __restrict__ mmd,
                        float* out) {
  if (threadIdx.x != 0 || blockIdx.x != 0) return;
  double total = 0.0, vw = 0.0;
  for (int c = 0; c < 5; ++c) {
    int nsf = meta[c], nqf = meta[5 + c];
    if (nsf < 2 || nqf < 2) continue;
    double pos = (double)mmd[c * 5 + c];
    bool any = false; double best = 0.0;
    for (int k = 0; k < 5; ++k) {
      if (k == c || meta[k] < 2) continue;
      double v = (double)mmd[k * 5 + c];
      if (!any || v < best) { best = v; any = true; }
    }
    double lc = any ? fmax(pos - best + 0.1, 0.0) : pos;
    double w = sqrt((double)nsf * (double)nqf);
    total += w * lc; vw += w;
  }
  out[0] = (float)(0.1 * total / fmax(vw, 1e-12));
}

// ============================================================================
// host launcher
// ============================================================================
extern "C" void kernel_launch(void* const* d_in, const int* in_sizes, int n_in,
                              void* d_out, int out_size, void* d_ws, size_t ws_size,
                              hipStream_t stream) {
  const float* f_s = (const float*)d_in[0];
  const int*   l_s = (const int*)d_in[1];
  const float* f_q = (const float*)d_in[2];
  const int*   l_q = (const int*)d_in[3];
  float* out = (float*)d_out;
  char* ws = (char*)d_ws;

  size_t off = 0;
  auto take = [&](size_t bytes) -> void* {
    void* p = ws + off;
    off = (off + bytes + 255) & ~(size_t)255;
    return p;
  };
  int*   meta     = (int*)take(32 * 4);
  int*   sup_list = (int*)take((size_t)5 * S_LEN * 4);
  int*   qry_list = (int*)take((size_t)5 * Q_TOT * 4);
  int*   Jsup     = (int*)take((size_t)5 * S_LEN * 4);
  int*   Jqry     = (int*)take((size_t)5 * Q_TOT * 4);
  int*   sel      = (int*)take((size_t)10 * MAXS * 4);
  float* xa       = (float*)take((size_t)5 * 65536 * 4);
  float* xb       = (float*)take((size_t)5 * 65536 * 4);
  float* Ga       = (float*)take((size_t)5 * 65536 * 4);
  float* Gb       = (float*)take((size_t)5 * 65536 * 4);
  float* Gab      = (float*)take((size_t)25 * 65536 * 4);
  float* diagA    = (float*)take((size_t)5 * 256 * 4);
  float* diagB    = (float*)take((size_t)5 * 256 * 4);
  float* mmd      = (float*)take(25 * 4);
  if (off > ws_size) return;   // insufficient scratch: fail loudly (no write)

  k_collect<<<10, 64, 0, stream>>>(l_s, l_q, meta, sup_list, qry_list, Jsup, Jqry);
  k_prov<<<10, 256, 0, stream>>>(meta, sup_list, qry_list, Jsup, Jqry, sel);
  k_gather<<<10, 256, 0, stream>>>(f_s, f_q, meta, sel, xa, xb);
  k_gram<<<35, 1024, 0, stream>>>(xa, xb, Ga, Gb, Gab);
  k_diag<<<10, 256, 0, stream>>>(Ga, Gb, diagA, diagB);
  k_conv<<<35, 256, 0, stream>>>(Ga, Gb, Gab, diagA, diagB);
  k_medmmd<<<25, 256, 0, stream>>>(meta, Ga, Gb, Gab, mmd);
  k_final<<<1, 64, 0, stream>>>(meta, mmd, out);
}

// Round 2
// 9491.932 us; speedup vs baseline: 1.4429x; 1.4429x over previous
//
#include <hip/hip_runtime.h>

// ============================================================================
// numpy RNG replication: SeedSequence + PCG64 (XSL-RR 128/64), next32 buffering
// ============================================================================
struct U128 { unsigned long long hi, lo; };

__device__ __forceinline__ U128 u128_mul(U128 a, U128 b) {
  U128 r;
  r.lo = a.lo * b.lo;
  r.hi = __umul64hi(a.lo, b.lo) + a.hi * b.lo + a.lo * b.hi;
  return r;
}
__device__ __forceinline__ U128 u128_add(U128 a, U128 b) {
  U128 r; r.lo = a.lo + b.lo; r.hi = a.hi + b.hi + (r.lo < a.lo ? 1ull : 0ull); return r;
}

struct Pcg64 {
  U128 state, inc;
};

__device__ __forceinline__ void pcg_step(Pcg64* r) {
  const U128 M = {0x2360ed051fc65da4ull, 0x4385df649fccf645ull};
  r->state = u128_add(u128_mul(r->state, M), r->inc);
}
__device__ __forceinline__ unsigned long long pcg_next64(Pcg64* r) {
  pcg_step(r);
  unsigned int rot = (unsigned int)(r->state.hi >> 58);   // state >> 122
  unsigned long long x = r->state.hi ^ r->state.lo;       // XSL
  return (x >> rot) | (x << ((64u - rot) & 63u));         // RR
}

// SeedSequence constants (numpy bit_generator.pyx)
__device__ __forceinline__ unsigned int ss_hashmix(unsigned int v, unsigned int* hc) {
  v ^= *hc; *hc = *hc * 0x931e8875u; v *= *hc; v ^= v >> 16; return v;
}
__device__ __forceinline__ unsigned int ss_mix(unsigned int x, unsigned int y) {
  unsigned int r = x * 0xca01f9ddu ^ y * 0x4973f715u; r ^= r >> 16; return r;
}
__device__ void pcg_seed(Pcg64* rng, unsigned int seed) {
  unsigned int pool[4]; unsigned int hc = 0x43b0d7e5u;   // INIT_A
  pool[0] = ss_hashmix(seed, &hc);
  for (int i = 1; i < 4; ++i) pool[i] = ss_hashmix(0u, &hc);
  for (int s = 0; s < 4; ++s)
    for (int d = 0; d < 4; ++d)
      if (s != d) pool[d] = ss_mix(pool[d], ss_hashmix(pool[s], &hc));
  unsigned int hc2 = 0x8b51f9ddu;                        // INIT_B
  unsigned long long w64[4];
  for (int i = 0; i < 4; ++i) {
    unsigned int lo = pool[(2*i) & 3];
    lo ^= hc2; hc2 *= 0x58f38dedu; lo *= hc2; lo ^= lo >> 16;
    unsigned int hi = pool[(2*i+1) & 3];
    hi ^= hc2; hc2 *= 0x58f38dedu; hi *= hc2; hi ^= hi >> 16;
    w64[i] = (unsigned long long)lo | ((unsigned long long)hi << 32);
  }
  U128 initstate = {w64[0], w64[1]};   // PCG_128BIT_CONSTANT(seed[0], seed[1]): [0] is HIGH
  U128 initseq   = {w64[2], w64[3]};
  rng->inc.hi = (initseq.hi << 1) | (initseq.lo >> 63);
  rng->inc.lo = (initseq.lo << 1) | 1ull;
  rng->state.hi = 0; rng->state.lo = 0;
  pcg_step(rng);
  rng->state = u128_add(rng->state, initstate);
  pcg_step(rng);
}

// affine jump-ahead: state <- A^delta * state + (A^delta-1)/(A-1)*inc
__device__ void pcg_advance(Pcg64* r, unsigned long long delta) {
  U128 acc_mult = {0ull, 1ull}, acc_plus = {0ull, 0ull};
  U128 cur_mult = {0x2360ed051fc65da4ull, 0x4385df649fccf645ull};
  U128 cur_plus = r->inc;
  while (delta) {
    if (delta & 1ull) {
      acc_mult = u128_mul(acc_mult, cur_mult);
      acc_plus = u128_add(u128_mul(acc_plus, cur_mult), cur_plus);
    }
    U128 one = {0ull, 1ull};
    U128 cm1 = u128_add(cur_mult, one);
    cur_plus = u128_mul(cm1, cur_plus);
    cur_mult = u128_mul(cur_mult, cur_mult);
    delta >>= 1;
  }
  r->state = u128_add(u128_mul(r->state, acc_mult), acc_plus);
}

// ============================================================================
// Problem constants
// ============================================================================
#define S_LEN   16384
#define Q_LEN   65536
#define Q_TOT   327680     // 5*65536
#define DFEAT   256
#define MAXS    256
#define CAPS64  24576      // next64 outputs per support class (49152 u32 draws)
#define CAPQ64  98304      // next64 outputs per query class  (196608 u32 draws)

// meta layout: [0..4]=ns_full, [5..9]=nq_full, [10..14]=na, [15..19]=nb

// ============================================================================
// K0: parallel draw-stream generation (exact numpy next32 sequence, lo first)
// ============================================================================
__global__ __launch_bounds__(256) void k_draws(unsigned int* __restrict__ draws) {
  int t = blockIdx.x; int cls = t % 5; int isq = t / 5;
  unsigned int seed = (unsigned)(1000 + isq * 1000 + cls + 1);
  unsigned long long cap64 = isq ? CAPQ64 : CAPS64;
  unsigned int* dst = draws + (isq ? (10ull * CAPS64 + (unsigned long long)cls * 2 * CAPQ64)
                                   : ((unsigned long long)cls * 2 * CAPS64));
  Pcg64 rng; pcg_seed(&rng, seed);
  int tid = threadIdx.x;
  unsigned long long C = cap64 / 256ull;     // 96 or 384
  unsigned long long k0 = (unsigned long long)tid * C;
  pcg_advance(&rng, k0);
  uint2* d2 = (uint2*)dst;
  for (unsigned long long m = 0; m < C; ++m) {
    unsigned long long o = pcg_next64(&rng);
    d2[k0 + m] = make_uint2((unsigned int)o, (unsigned int)(o >> 32));
  }
}

// ============================================================================
// K1: collect class index lists (reference order), 4-wave quarter compaction
// ============================================================================
__global__ __launch_bounds__(256) void k_collect(const int* __restrict__ ls,
                                                 const int* __restrict__ lq,
                                                 int* meta, int* sup_list, int* qry_list,
                                                 int* tmpS, int* tmpQ) {
  int t = blockIdx.x;
  int cls = t % 5; int isq = t / 5;
  const int* src; int n_src, matchval; int* out; int* tmp;
  if (!isq) { src = ls + cls * S_LEN; n_src = S_LEN; matchval = 1;
              out = sup_list + cls * S_LEN; tmp = tmpS + cls * S_LEN; }
  else      { src = lq; n_src = Q_TOT; matchval = cls + 1;
              out = qry_list + (size_t)cls * Q_TOT; tmp = tmpQ + (size_t)cls * Q_TOT; }
  int tid = threadIdx.x;
  int w = tid >> 6; int lane = tid & 63;
  int qlen = n_src >> 2;                 // 4096 or 81920, multiple of 64
  int beg = w * qlen;
  __shared__ int cnt[4];
  int base = 0;
  unsigned long long lmask = (1ull << lane) - 1ull;
  for (int i0 = beg; i0 < beg + qlen; i0 += 64) {
    int i = i0 + lane;
    bool p = (src[i] == matchval);
    unsigned long long m = __ballot(p);
    if (p) tmp[beg + base + __popcll(m & lmask)] = i;
    base += __popcll(m);
  }
  if (lane == 0) cnt[w] = base;
  __syncthreads();
  int c0 = cnt[0], c1 = cnt[1], c2 = cnt[2], c3 = cnt[3];
  int offs[4] = {0, c0, c0 + c1, c0 + c1 + c2};
  int ntot = c0 + c1 + c2 + c3;
  for (int ww = 0; ww < 4; ++ww) {
    int cw = cnt[ww];
    for (int idx = tid; idx < cw; idx += 256)
      out[offs[ww] + idx] = tmp[ww * qlen + idx];
  }
  if (tid == 0) {
    meta[isq * 5 + cls] = ntot;
    meta[10 + isq * 5 + cls] = ntot < MAXS ? ntot : MAXS;
  }
}

// ============================================================================
// K2: serial masked-rejection automaton over pre-generated draw stream.
//     J[i] for i descending n-1 .. 256 (only these affect the first-256 set).
// ============================================================================
__global__ __launch_bounds__(64) void k_consume(const int* __restrict__ meta,
                                                const unsigned int* __restrict__ draws,
                                                int* Jsup, int* Jqry) {
  if (threadIdx.x != 0) return;
  int t = blockIdx.x; int cls = t % 5; int isq = t / 5;
  int n = meta[isq * 5 + cls];
  if (n <= MAXS) return;
  const unsigned int* d = draws + (isq ? (10ull * CAPS64 + (unsigned long long)cls * 2 * CAPQ64)
                                       : ((unsigned long long)cls * 2 * CAPS64));
  int* J = isq ? (Jqry + (size_t)cls * Q_TOT) : (Jsup + cls * S_LEN);
  unsigned int mask = (unsigned int)(n - 1);
  mask |= mask >> 1; mask |= mask >> 2; mask |= mask >> 4;
  mask |= mask >> 8; mask |= mask >> 16;
  size_t p = 0;
  for (int i = n - 1; i >= MAXS; --i) {
    if ((mask >> 1) >= (unsigned int)i) mask >>= 1;
    unsigned int v;
    do { v = d[p++] & mask; } while (v > (unsigned int)i);
    J[i] = (int)v;
  }
}

// ============================================================================
// K3: provenance walk (reverse of FY execution order = i ascending 256..n-1),
//     J streamed through LDS chunks (coalesced load + broadcast read)
// ============================================================================
__global__ __launch_bounds__(256) void k_prov(const int* __restrict__ meta,
                                              const int* __restrict__ sup_list,
                                              const int* __restrict__ qry_list,
                                              const int* __restrict__ Jsup,
                                              const int* __restrict__ Jqry,
                                              int* sel) {
  __shared__ int sj[1024];
  int t = blockIdx.x; int tid = threadIdx.x;
  int cls = t % 5; int isq = t / 5;
  int n = meta[isq * 5 + cls];
  const int* list; const int* J;
  if (!isq) { list = sup_list + cls * S_LEN; J = Jsup + cls * S_LEN; }
  else      { list = qry_list + (size_t)cls * Q_TOT; J = Jqry + (size_t)cls * Q_TOT; }
  int* s = sel + t * MAXS;
  if (n <= MAXS) { if (tid < n) s[tid] = list[tid]; return; }
  int pos = tid;
  for (int i0 = MAXS; i0 < n; i0 += 1024) {
    int lim = n < i0 + 1024 ? n : i0 + 1024;
    int cntc = lim - i0;
    __syncthreads();
    for (int k = tid; k < cntc; k += 256) sj[k] = J[i0 + k];
    __syncthreads();
    #pragma unroll 4
    for (int k = 0; k < cntc; ++k) {
      int i = i0 + k; int jv = sj[k];
      pos = (pos == i) ? jv : ((pos == jv) ? i : pos);
    }
  }
  s[tid] = list[pos];
}

// ============================================================================
// K4: gather selected feature rows and row-normalize (x / (||x|| + 1e-12))
// ============================================================================
__global__ __launch_bounds__(256) void k_gather(const float* __restrict__ f_s,
                                                const float* __restrict__ f_q,
                                                const int* __restrict__ meta,
                                                const int* __restrict__ sel,
                                                float* xa, float* xb) {
  int t = blockIdx.x; int r = threadIdx.x;
  int cls = t % 5; int isq = t / 5;
  int n = meta[10 + isq * 5 + cls];
  if (r >= n) return;
  int id = sel[t * MAXS + r];
  const float* src; size_t stride; float* dst;
  if (!isq) {
    src = f_s + (size_t)cls * DFEAT * S_LEN + id; stride = S_LEN;
    dst = xa + cls * (MAXS * DFEAT) + r * DFEAT;
  } else {
    int m = id >> 16; int nn = id & 0xFFFF;
    src = f_q + (size_t)m * DFEAT * Q_LEN + nn; stride = Q_LEN;
    dst = xb + cls * (MAXS * DFEAT) + r * DFEAT;
  }
  float ss = 0.f;
  for (int d = 0; d < DFEAT; ++d) { float v = src[(size_t)d * stride]; ss += v * v; dst[d] = v; }
  float inv = 1.0f / (sqrtf(ss) + 1e-12f);
  for (int d = 0; d < DFEAT; ++d) dst[d] *= inv;
}

// ============================================================================
// K5: 35 Gram matrices (256x256, K=256)
// ============================================================================
__global__ __launch_bounds__(1024) void k_gram(const float* __restrict__ xa,
                                               const float* __restrict__ xb,
                                               float* Ga, float* Gb, float* Gab) {
  int j = blockIdx.x;
  const float *A, *B; float* G;
  if (j < 5)       { A = xa + j * 65536; B = A; G = Ga + j * 65536; }
  else if (j < 10) { int c = j - 5; A = xb + c * 65536; B = A; G = Gb + c * 65536; }
  else             { int p = j - 10; int k = p / 5, c = p % 5;
                     A = xa + k * 65536; B = xb + c * 65536; G = Gab + p * 65536; }
  __shared__ float As[256][17];
  __shared__ float Bs[256][17];
  int tid = threadIdx.x;
  int ti = tid >> 5, tj = tid & 31;
  float acc[8][8];
  #pragma unroll
  for (int r = 0; r < 8; ++r)
    #pragma unroll
    for (int s = 0; s < 8; ++s) acc[r][s] = 0.f;
  for (int k0 = 0; k0 < 256; k0 += 16) {
    #pragma unroll
    for (int e = 0; e < 4; ++e) {
      int idx = tid + e * 1024;
      int i = idx >> 4, kk = idx & 15;
      As[i][kk] = A[i * 256 + k0 + kk];
      Bs[i][kk] = B[i * 256 + k0 + kk];
    }
    __syncthreads();
    #pragma unroll
    for (int kk = 0; kk < 16; ++kk) {
      float a[8], b[8];
      #pragma unroll
      for (int r = 0; r < 8; ++r) a[r] = As[ti * 8 + r][kk];
      #pragma unroll
      for (int s = 0; s < 8; ++s) b[s] = Bs[tj * 8 + s][kk];
      #pragma unroll
      for (int r = 0; r < 8; ++r)
        #pragma unroll
        for (int s = 0; s < 8; ++s) acc[r][s] += a[r] * b[s];
    }
    __syncthreads();
  }
  #pragma unroll
  for (int r = 0; r < 8; ++r)
    #pragma unroll
    for (int s = 0; s < 8; ++s)
      G[(ti * 8 + r) * 256 + tj * 8 + s] = acc[r][s];
}

// ============================================================================
// K6: extract Gram diagonals
// ============================================================================
__global__ __launch_bounds__(256) void k_diag(const float* __restrict__ Ga,
                                              const float* __restrict__ Gb,
                                              float* diagA, float* diagB) {
  int t = blockIdx.x; int i = threadIdx.x;
  if (t < 5) diagA[t * 256 + i] = Ga[t * 65536 + i * 257];
  else { int c = t - 5; diagB[c * 256 + i] = Gb[c * 65536 + i * 257]; }
}

// ============================================================================
// K7: G -> D in place: D_ij = max(dA_i + dB_j - 2 g_ij, 0)
// ============================================================================
__global__ __launch_bounds__(256) void k_conv(float* Ga, float* Gb, float* Gab,
                                              const float* __restrict__ diagA,
                                              const float* __restrict__ diagB) {
  int j = blockIdx.x; int tid = threadIdx.x;
  float* G; const float *dA, *dB;
  if (j < 5)       { G = Ga + j * 65536; dA = diagA + j * 256; dB = dA; }
  else if (j < 10) { int c = j - 5; G = Gb + c * 65536; dA = diagB + c * 256; dB = dA; }
  else             { int p = j - 10; int k = p / 5, c = p % 5;
                     G = Gab + p * 65536; dA = diagA + k * 256; dB = diagB + c * 256; }
  float db = dB[tid];
  for (int i = 0; i < 256; ++i) {
    float g = G[i * 256 + tid];
    float d = dA[i] + db - 2.0f * g;
    G[i * 256 + tid] = d > 0.f ? d : 0.f;
  }
}

// ============================================================================
// K8: per (k,c): exact median (3-pass radix select) -> sigma -> multi-RBF MMD^2
// ============================================================================
__global__ __launch_bounds__(256) void k_medmmd(const int* __restrict__ meta,
                                                const float* __restrict__ Da_all,
                                                const float* __restrict__ Db_all,
                                                const float* __restrict__ Dab_all,
                                                float* mmd_out) {
  int p = blockIdx.x; int kcl = p / 5, ccl = p % 5;
  int tid = threadIdx.x;
  int nsf = meta[kcl], nqf = meta[5 + ccl];
  if (nsf < 2 || nqf < 2) { if (tid == 0) mmd_out[p] = 0.0f; return; }
  int na = meta[10 + kcl], nb = meta[15 + ccl];
  const float* Da  = Da_all  + kcl * 65536;
  const float* Db  = Db_all  + ccl * 65536;
  const float* Dab = Dab_all + p * 65536;

  __shared__ unsigned int hist[2048];
  __shared__ unsigned int sh[8];
  __shared__ double dred[256];

  unsigned int N = (unsigned int)(na + nb) * (unsigned int)(na + nb);

  for (int b = tid; b < 2048; b += 256) hist[b] = 0;
  if (tid < 8) sh[tid] = 0;
  __syncthreads();
  for (int i = 0; i < na; ++i) if (tid < na) {
    unsigned int key = __float_as_uint(Da[i * 256 + tid]);
    atomicAdd(&hist[key >> 21], 1u);
    if (key == 0u) atomicAdd(&sh[0], 1u);
  }
  for (int i = 0; i < nb; ++i) if (tid < nb) {
    unsigned int key = __float_as_uint(Db[i * 256 + tid]);
    atomicAdd(&hist[key >> 21], 1u);
    if (key == 0u) atomicAdd(&sh[0], 1u);
  }
  for (int i = 0; i < na; ++i) if (tid < nb) {
    unsigned int key = __float_as_uint(Dab[i * 256 + tid]);
    atomicAdd(&hist[key >> 21], 2u);
    if (key == 0u) atomicAdd(&sh[0], 2u);
  }
  __syncthreads();
  if (tid == 0) {
    unsigned int nz = sh[0];
    if (nz >= N) sh[1] = 1u;
    else {
      unsigned int r = nz + (N - nz - 1u) / 2u;
      unsigned int cum = 0, bsel = 2047;
      for (int b = 0; b < 2048; ++b) {
        unsigned int nc = cum + hist[b];
        if (nc > r) { bsel = (unsigned int)b; break; }
        cum = nc;
      }
      sh[1] = 0u; sh[2] = bsel; sh[3] = r - cum;
    }
  }
  __syncthreads();
  float base;
  if (!sh[1]) {
    unsigned int b1 = sh[2];
    for (int b = tid; b < 2048; b += 256) hist[b] = 0;
    __syncthreads();
    for (int i = 0; i < na; ++i) if (tid < na) {
      unsigned int key = __float_as_uint(Da[i * 256 + tid]);
      if ((key >> 21) == b1) atomicAdd(&hist[(key >> 10) & 0x7FFu], 1u);
    }
    for (int i = 0; i < nb; ++i) if (tid < nb) {
      unsigned int key = __float_as_uint(Db[i * 256 + tid]);
      if ((key >> 21) == b1) atomicAdd(&hist[(key >> 10) & 0x7FFu], 1u);
    }
    for (int i = 0; i < na; ++i) if (tid < nb) {
      unsigned int key = __float_as_uint(Dab[i * 256 + tid]);
      if ((key >> 21) == b1) atomicAdd(&hist[(key >> 10) & 0x7FFu], 2u);
    }
    __syncthreads();
    if (tid == 0) {
      unsigned int r = sh[3];
      unsigned int cum = 0, bsel = 2047;
      for (int b = 0; b < 2048; ++b) {
        unsigned int nc = cum + hist[b];
        if (nc > r) { bsel = (unsigned int)b; break; }
        cum = nc;
      }
      sh[4] = bsel; sh[5] = r - cum;
    }
    __syncthreads();
    unsigned int pref2 = (b1 << 11) | sh[4];
    for (int b = tid; b < 1024; b += 256) hist[b] = 0;
    __syncthreads();
    for (int i = 0; i < na; ++i) if (tid < na) {
      unsigned int key = __float_as_uint(Da[i * 256 + tid]);
      if ((key >> 10) == pref2) atomicAdd(&hist[key & 0x3FFu], 1u);
    }
    for (int i = 0; i < nb; ++i) if (tid < nb) {
      unsigned int key = __float_as_uint(Db[i * 256 + tid]);
      if ((key >> 10) == pref2) atomicAdd(&hist[key & 0x3FFu], 1u);
    }
    for (int i = 0; i < na; ++i) if (tid < nb) {
      unsigned int key = __float_as_uint(Dab[i * 256 + tid]);
      if ((key >> 10) == pref2) atomicAdd(&hist[key & 0x3FFu], 2u);
    }
    __syncthreads();
    if (tid == 0) {
      unsigned int r = sh[5];
      unsigned int cum = 0, bsel = 1023;
      for (int b = 0; b < 1024; ++b) {
        unsigned int nc = cum + hist[b];
        if (nc > r) { bsel = (unsigned int)b; break; }
        cum = nc;
      }
      sh[6] = (pref2 << 10) | bsel;
    }
    __syncthreads();
    base = sqrtf(__uint_as_float(sh[6]) + 1e-6f);
  } else {
    base = 1.0f;
  }

  float g2 = base * base;
  float c0 = 1.0f / (2.0f * g2 * 0.25f);
  float c1 = 1.0f / (2.0f * g2 * 1.0f);
  float c2 = 1.0f / (2.0f * g2 * 4.0f);
  float c3 = 1.0f / (2.0f * g2 * 16.0f);
  double accA = 0.0, accB = 0.0, accAB = 0.0;
  for (int i = 0; i < na; ++i) if (tid < na) {
    float d = Da[i * 256 + tid];
    accA += (double)(expf(-d * c0) + expf(-d * c1) + expf(-d * c2) + expf(-d * c3));
  }
  for (int i = 0; i < nb; ++i) if (tid < nb) {
    float d = Db[i * 256 + tid];
    accB += (double)(expf(-d * c0) + expf(-d * c1) + expf(-d * c2) + expf(-d * c3));
  }
  for (int i = 0; i < na; ++i) if (tid < nb) {
    float d = Dab[i * 256 + tid];
    accAB += (double)(expf(-d * c0) + expf(-d * c1) + expf(-d * c2) + expf(-d * c3));
  }
  dred[tid] = accA; __syncthreads();
  for (int s = 128; s > 0; s >>= 1) { if (tid < s) dred[tid] += dred[tid + s]; __syncthreads(); }
  double SA = dred[0]; __syncthreads();
  dred[tid] = accB; __syncthreads();
  for (int s = 128; s > 0; s >>= 1) { if (tid < s) dred[tid] += dred[tid + s]; __syncthreads(); }
  double SB = dred[0]; __syncthreads();
  dred[tid] = accAB; __syncthreads();
  for (int s = 128; s > 0; s >>= 1) { if (tid < s) dred[tid] += dred[tid + s]; __syncthreads(); }
  double SAB = dred[0];
  if (tid == 0) {
    double meanA  = SA  / ((double)na * (double)na);
    double meanB  = SB  / ((double)nb * (double)nb);
    double meanAB = SAB / ((double)na * (double)nb);
    double m = meanA + meanB - 2.0 * meanAB;
    mmd_out[p] = (float)(m > 0.0 ? m : 0.0);
  }
}

// ============================================================================
// K9: final weighted loss
// ============================================================================
__global__ void k_final(const int* __restrict__ meta, const float* __restrict__ mmd,
                        float* out) {
  if (threadIdx.x != 0 || blockIdx.x != 0) return;
  double total = 0.0, vw = 0.0;
  for (int c = 0; c < 5; ++c) {
    int nsf = meta[c], nqf = meta[5 + c];
    if (nsf < 2 || nqf < 2) continue;
    double pos = (double)mmd[c * 5 + c];
    bool any = false; double best = 0.0;
    for (int k = 0; k < 5; ++k) {
      if (k == c || meta[k] < 2) continue;
      double v = (double)mmd[k * 5 + c];
      if (!any || v < best) { best = v; any = true; }
    }
    double lc = any ? fmax(pos - best + 0.1, 0.0) : pos;
    double w = sqrt((double)nsf * (double)nqf);
    total += w * lc; vw += w;
  }
  out[0] = (float)(0.1 * total / fmax(vw, 1e-12));
}

// ============================================================================
// host launcher
// ============================================================================
extern "C" void kernel_launch(void* const* d_in, const int* in_sizes, int n_in,
                              void* d_out, int out_size, void* d_ws, size_t ws_size,
                              hipStream_t stream) {
  const float* f_s = (const float*)d_in[0];
  const int*   l_s = (const int*)d_in[1];
  const float* f_q = (const float*)d_in[2];
  const int*   l_q = (const int*)d_in[3];
  float* out = (float*)d_out;
  char* ws = (char*)d_ws;

  size_t off = 0;
  auto take = [&](size_t bytes) -> void* {
    void* p = ws + off;
    off = (off + bytes + 255) & ~(size_t)255;
    return p;
  };
  int*   meta     = (int*)take(32 * 4);
  int*   sup_list = (int*)take((size_t)5 * S_LEN * 4);
  int*   qry_list = (int*)take((size_t)5 * Q_TOT * 4);
  int*   Jsup     = (int*)take((size_t)5 * S_LEN * 4);   // also k_collect tmpS
  int*   Jqry     = (int*)take((size_t)5 * Q_TOT * 4);   // also k_collect tmpQ
  unsigned int* draws = (unsigned int*)take((10ull * CAPS64 + 10ull * CAPQ64) * 4);
  int*   sel      = (int*)take((size_t)10 * MAXS * 4);
  float* xa       = (float*)take((size_t)5 * 65536 * 4);
  float* xb       = (float*)take((size_t)5 * 65536 * 4);
  float* Ga       = (float*)take((size_t)5 * 65536 * 4);
  float* Gb       = (float*)take((size_t)5 * 65536 * 4);
  float* Gab      = (float*)take((size_t)25 * 65536 * 4);
  float* diagA    = (float*)take((size_t)5 * 256 * 4);
  float* diagB    = (float*)take((size_t)5 * 256 * 4);
  float* mmd      = (float*)take(25 * 4);
  if (off > ws_size) return;

  k_draws<<<10, 256, 0, stream>>>(draws);
  k_collect<<<10, 256, 0, stream>>>(l_s, l_q, meta, sup_list, qry_list, Jsup, Jqry);
  k_consume<<<10, 64, 0, stream>>>(meta, draws, Jsup, Jqry);
  k_prov<<<10, 256, 0, stream>>>(meta, sup_list, qry_list, Jsup, Jqry, sel);
  k_gather<<<10, 256, 0, stream>>>(f_s, f_q, meta, sel, xa, xb);
  k_gram<<<35, 1024, 0, stream>>>(xa, xb, Ga, Gb, Gab);
  k_diag<<<10, 256, 0, stream>>>(Ga, Gb, diagA, diagB);
  k_conv<<<35, 256, 0, stream>>>(Ga, Gb, Gab, diagA, diagB);
  k_medmmd<<<25, 256, 0, stream>>>(meta, Ga, Gb, Gab, mmd);
  k_final<<<1, 64, 0, stream>>>(meta, mmd, out);
}

// Round 3
// 5001.505 us; speedup vs baseline: 2.7383x; 1.8978x over previous
//
#include <hip/hip_runtime.h>

// ============================================================================
// numpy RNG replication: SeedSequence + PCG64 (XSL-RR 128/64), next32 buffering
// ============================================================================
struct U128 { unsigned long long hi, lo; };

__device__ __forceinline__ U128 u128_mul(U128 a, U128 b) {
  U128 r;
  r.lo = a.lo * b.lo;
  r.hi = __umul64hi(a.lo, b.lo) + a.hi * b.lo + a.lo * b.hi;
  return r;
}
__device__ __forceinline__ U128 u128_add(U128 a, U128 b) {
  U128 r; r.lo = a.lo + b.lo; r.hi = a.hi + b.hi + (r.lo < a.lo ? 1ull : 0ull); return r;
}

struct Pcg64 {
  U128 state, inc;
};

__device__ __forceinline__ void pcg_step(Pcg64* r) {
  const U128 M = {0x2360ed051fc65da4ull, 0x4385df649fccf645ull};
  r->state = u128_add(u128_mul(r->state, M), r->inc);
}
__device__ __forceinline__ unsigned long long pcg_next64(Pcg64* r) {
  pcg_step(r);
  unsigned int rot = (unsigned int)(r->state.hi >> 58);   // state >> 122
  unsigned long long x = r->state.hi ^ r->state.lo;       // XSL
  return (x >> rot) | (x << ((64u - rot) & 63u));         // RR
}

// SeedSequence constants (numpy bit_generator.pyx)
__device__ __forceinline__ unsigned int ss_hashmix(unsigned int v, unsigned int* hc) {
  v ^= *hc; *hc = *hc * 0x931e8875u; v *= *hc; v ^= v >> 16; return v;
}
__device__ __forceinline__ unsigned int ss_mix(unsigned int x, unsigned int y) {
  unsigned int r = x * 0xca01f9ddu ^ y * 0x4973f715u; r ^= r >> 16; return r;
}
__device__ void pcg_seed(Pcg64* rng, unsigned int seed) {
  unsigned int pool[4]; unsigned int hc = 0x43b0d7e5u;   // INIT_A
  pool[0] = ss_hashmix(seed, &hc);
  for (int i = 1; i < 4; ++i) pool[i] = ss_hashmix(0u, &hc);
  for (int s = 0; s < 4; ++s)
    for (int d = 0; d < 4; ++d)
      if (s != d) pool[d] = ss_mix(pool[d], ss_hashmix(pool[s], &hc));
  unsigned int hc2 = 0x8b51f9ddu;                        // INIT_B
  unsigned long long w64[4];
  for (int i = 0; i < 4; ++i) {
    unsigned int lo = pool[(2*i) & 3];
    lo ^= hc2; hc2 *= 0x58f38dedu; lo *= hc2; lo ^= lo >> 16;
    unsigned int hi = pool[(2*i+1) & 3];
    hi ^= hc2; hc2 *= 0x58f38dedu; hi *= hc2; hi ^= hi >> 16;
    w64[i] = (unsigned long long)lo | ((unsigned long long)hi << 32);
  }
  U128 initstate = {w64[0], w64[1]};   // PCG_128BIT_CONSTANT(seed[0], seed[1]): [0] is HIGH
  U128 initseq   = {w64[2], w64[3]};
  rng->inc.hi = (initseq.hi << 1) | (initseq.lo >> 63);
  rng->inc.lo = (initseq.lo << 1) | 1ull;
  rng->state.hi = 0; rng->state.lo = 0;
  pcg_step(rng);
  rng->state = u128_add(rng->state, initstate);
  pcg_step(rng);
}

// affine jump-ahead: state <- A^delta * state + (A^delta-1)/(A-1)*inc
__device__ void pcg_advance(Pcg64* r, unsigned long long delta) {
  U128 acc_mult = {0ull, 1ull}, acc_plus = {0ull, 0ull};
  U128 cur_mult = {0x2360ed051fc65da4ull, 0x4385df649fccf645ull};
  U128 cur_plus = r->inc;
  while (delta) {
    if (delta & 1ull) {
      acc_mult = u128_mul(acc_mult, cur_mult);
      acc_plus = u128_add(u128_mul(acc_plus, cur_mult), cur_plus);
    }
    U128 one = {0ull, 1ull};
    U128 cm1 = u128_add(cur_mult, one);
    cur_plus = u128_mul(cm1, cur_plus);
    cur_mult = u128_mul(cur_mult, cur_mult);
    delta >>= 1;
  }
  r->state = u128_add(u128_mul(r->state, acc_mult), acc_plus);
}

// ============================================================================
// Problem constants
// ============================================================================
#define S_LEN   16384
#define Q_LEN   65536
#define Q_TOT   327680     // 5*65536
#define DFEAT   256
#define MAXS    256
#define CAPS64  24576      // next64 outputs per support class (49152 u32 draws)
#define CAPQ64  98304      // next64 outputs per query class  (196608 u32 draws)

// meta layout: [0..4]=ns_full, [5..9]=nq_full, [10..14]=na, [15..19]=nb

// ============================================================================
// K0: parallel draw-stream generation (exact numpy next32 sequence, lo first)
// ============================================================================
__global__ __launch_bounds__(256) void k_draws(unsigned int* __restrict__ draws) {
  int t = blockIdx.x; int cls = t % 5; int isq = t / 5;
  unsigned int seed = (unsigned)(1000 + isq * 1000 + cls + 1);
  unsigned long long cap64 = isq ? CAPQ64 : CAPS64;
  unsigned int* dst = draws + (isq ? (10ull * CAPS64 + (unsigned long long)cls * 2 * CAPQ64)
                                   : ((unsigned long long)cls * 2 * CAPS64));
  Pcg64 rng; pcg_seed(&rng, seed);
  int tid = threadIdx.x;
  unsigned long long C = cap64 / 256ull;     // 96 or 384
  unsigned long long k0 = (unsigned long long)tid * C;
  pcg_advance(&rng, k0);
  uint2* d2 = (uint2*)dst;
  for (unsigned long long m = 0; m < C; ++m) {
    unsigned long long o = pcg_next64(&rng);
    d2[k0 + m] = make_uint2((unsigned int)o, (unsigned int)(o >> 32));
  }
}

// ============================================================================
// K1: collect class index lists (reference order), 4-wave quarter compaction
// ============================================================================
__global__ __launch_bounds__(256) void k_collect(const int* __restrict__ ls,
                                                 const int* __restrict__ lq,
                                                 int* meta, int* sup_list, int* qry_list,
                                                 int* tmpS, int* tmpQ) {
  int t = blockIdx.x;
  int cls = t % 5; int isq = t / 5;
  const int* src; int n_src, matchval; int* out; int* tmp;
  if (!isq) { src = ls + cls * S_LEN; n_src = S_LEN; matchval = 1;
              out = sup_list + cls * S_LEN; tmp = tmpS + cls * S_LEN; }
  else      { src = lq; n_src = Q_TOT; matchval = cls + 1;
              out = qry_list + (size_t)cls * Q_TOT; tmp = tmpQ + (size_t)cls * Q_TOT; }
  int tid = threadIdx.x;
  int w = tid >> 6; int lane = tid & 63;
  int qlen = n_src >> 2;                 // 4096 or 81920, multiple of 64
  int beg = w * qlen;
  __shared__ int cnt[4];
  int base = 0;
  unsigned long long lmask = (1ull << lane) - 1ull;
  for (int i0 = beg; i0 < beg + qlen; i0 += 64) {
    int i = i0 + lane;
    bool p = (src[i] == matchval);
    unsigned long long m = __ballot(p);
    if (p) tmp[beg + base + __popcll(m & lmask)] = i;
    base += __popcll(m);
  }
  if (lane == 0) cnt[w] = base;
  __syncthreads();
  int c0 = cnt[0], c1 = cnt[1], c2 = cnt[2], c3 = cnt[3];
  int offs[4] = {0, c0, c0 + c1, c0 + c1 + c2};
  int ntot = c0 + c1 + c2 + c3;
  for (int ww = 0; ww < 4; ++ww) {
    int cw = cnt[ww];
    for (int idx = tid; idx < cw; idx += 256)
      out[offs[ww] + idx] = tmp[ww * qlen + idx];
  }
  if (tid == 0) {
    meta[isq * 5 + cls] = ntot;
    meta[10 + isq * 5 + cls] = ntot < MAXS ? ntot : MAXS;
  }
}

// ============================================================================
// K2: wave-parallel masked-rejection automaton (ballot-chase).
//     64 draws/chunk; rejections resolved one ballot each (first-failure is
//     provably exact); accepts committed en masse. J[i] for i in [256, n).
// ============================================================================
__global__ __launch_bounds__(64) void k_consume(const int* __restrict__ meta,
                                                const unsigned int* __restrict__ draws,
                                                int* Jsup, int* Jqry) {
  int t = blockIdx.x; int cls = t % 5; int isq = t / 5;
  int n = meta[isq * 5 + cls];
  if (n <= MAXS) return;
  const unsigned int* d = draws + (isq ? (10ull * CAPS64 + (unsigned long long)cls * 2 * CAPQ64)
                                       : ((unsigned long long)cls * 2 * CAPS64));
  int* J = isq ? (Jqry + (size_t)cls * Q_TOT) : (Jsup + cls * S_LEN);
  int lane = threadIdx.x;
  unsigned long long lmask = (1ull << lane) - 1ull;
  unsigned long long lbit  = (1ull << lane);
  int i = n - 1;
  size_t p = 0;
  unsigned int v = d[lane];
  while (i >= MAXS) {
    unsigned int vnext = d[p + 64 + lane];     // prefetch next chunk
    unsigned long long rej = 0ull;
    for (;;) {
      int A  = lane - __popcll(rej & lmask);   // accepts before this lane (assumed)
      int il = i - A;                          // trial index (>= 193 always)
      unsigned int m = 0xFFFFFFFFu >> __clz(il);
      bool fail = ((v & m) > (unsigned int)il) && !(rej & lbit);
      unsigned long long cand = __ballot(fail);
      if (!cand) break;
      rej |= (cand & (~cand + 1ull));          // commit lowest-lane failure (exact)
    }
    int A  = lane - __popcll(rej & lmask);
    int il = i - A;
    unsigned int m = 0xFFFFFFFFu >> __clz(il);
    bool acc = !(rej & lbit);
    int totAcc = 64 - __popcll(rej);
    if (acc && il >= MAXS) J[il] = (int)(v & m);
    int needed = i - (MAXS - 1);
    if (totAcc >= needed) break;
    i -= totAcc; p += 64; v = vnext;
  }
}

// ============================================================================
// K3: provenance walk (i ascending 256..n-1), LDS-staged J, 8-wide register
//     window so ds_reads batch off the dependent compare-select chain
// ============================================================================
__global__ __launch_bounds__(256) void k_prov(const int* __restrict__ meta,
                                              const int* __restrict__ sup_list,
                                              const int* __restrict__ qry_list,
                                              const int* __restrict__ Jsup,
                                              const int* __restrict__ Jqry,
                                              int* sel) {
  __shared__ int sj[2048];
  int t = blockIdx.x; int tid = threadIdx.x;
  int cls = t % 5; int isq = t / 5;
  int n = meta[isq * 5 + cls];
  const int* list; const int* J;
  if (!isq) { list = sup_list + cls * S_LEN; J = Jsup + cls * S_LEN; }
  else      { list = qry_list + (size_t)cls * Q_TOT; J = Jqry + (size_t)cls * Q_TOT; }
  int* s = sel + t * MAXS;
  if (n <= MAXS) { if (tid < n) s[tid] = list[tid]; return; }
  int pos = tid;
  int i0 = MAXS;
  while (i0 < n) {
    int lim = n < i0 + 2048 ? n : i0 + 2048;
    int cntc = lim - i0;
    __syncthreads();
    for (int k = tid; k < cntc; k += 256) sj[k] = J[i0 + k];
    __syncthreads();
    int k = 0;
    for (; k + 8 <= cntc; k += 8) {
      int j0 = sj[k+0], j1 = sj[k+1], j2 = sj[k+2], j3 = sj[k+3];
      int j4 = sj[k+4], j5 = sj[k+5], j6 = sj[k+6], j7 = sj[k+7];
      int i = i0 + k;
      pos = (pos == i)     ? j0 : ((pos == j0) ? i     : pos);
      pos = (pos == i + 1) ? j1 : ((pos == j1) ? i + 1 : pos);
      pos = (pos == i + 2) ? j2 : ((pos == j2) ? i + 2 : pos);
      pos = (pos == i + 3) ? j3 : ((pos == j3) ? i + 3 : pos);
      pos = (pos == i + 4) ? j4 : ((pos == j4) ? i + 4 : pos);
      pos = (pos == i + 5) ? j5 : ((pos == j5) ? i + 5 : pos);
      pos = (pos == i + 6) ? j6 : ((pos == j6) ? i + 6 : pos);
      pos = (pos == i + 7) ? j7 : ((pos == j7) ? i + 7 : pos);
    }
    for (; k < cntc; ++k) {
      int jv = sj[k]; int i = i0 + k;
      pos = (pos == i) ? jv : ((pos == jv) ? i : pos);
    }
    i0 = lim;
  }
  s[tid] = list[pos];
}

// ============================================================================
// K4: gather selected feature rows + fused row-norm (x / (||x|| + 1e-12)).
//     80 blocks; 8 lanes per row; 32 batched independent loads per thread.
// ============================================================================
__global__ __launch_bounds__(256) void k_gather(const float* __restrict__ f_s,
                                                const float* __restrict__ f_q,
                                                const int* __restrict__ meta,
                                                const int* __restrict__ sel,
                                                float* xa, float* xb) {
  int blk = blockIdx.x;
  int t = blk >> 3;          // class-pair 0..9
  int slab = blk & 7;        // 8 slabs x 32 rows
  int cls = t % 5; int isq = t / 5;
  int n = meta[10 + isq * 5 + cls];
  int tid = threadIdx.x;
  int row = slab * 32 + (tid >> 3);
  int dg = tid & 7;          // 8 d-groups of 32
  if (row >= n) return;      // group-uniform (8 lanes share row)
  int id = sel[t * MAXS + row];
  const float* src; size_t stride; float* dst;
  if (!isq) {
    src = f_s + (size_t)cls * DFEAT * S_LEN + id; stride = S_LEN;
    dst = xa + cls * (MAXS * DFEAT) + row * DFEAT;
  } else {
    int m = id >> 16; int nn = id & 0xFFFF;
    src = f_q + (size_t)m * DFEAT * Q_LEN + nn; stride = Q_LEN;
    dst = xb + cls * (MAXS * DFEAT) + row * DFEAT;
  }
  float v[32];
  #pragma unroll
  for (int dd = 0; dd < 32; ++dd)
    v[dd] = src[(size_t)(dg * 32 + dd) * stride];
  float ss = 0.f;
  #pragma unroll
  for (int dd = 0; dd < 32; ++dd) ss += v[dd] * v[dd];
  ss += __shfl_xor(ss, 1);
  ss += __shfl_xor(ss, 2);
  ss += __shfl_xor(ss, 4);
  float inv = 1.0f / (sqrtf(ss) + 1e-12f);
  #pragma unroll
  for (int dd = 0; dd < 32; ++dd) dst[dg * 32 + dd] = v[dd] * inv;
}

// ============================================================================
// K5: 35 Gram matrices (256x256, K=256)
// ============================================================================
__global__ __launch_bounds__(1024) void k_gram(const float* __restrict__ xa,
                                               const float* __restrict__ xb,
                                               float* Ga, float* Gb, float* Gab) {
  int j = blockIdx.x;
  const float *A, *B; float* G;
  if (j < 5)       { A = xa + j * 65536; B = A; G = Ga + j * 65536; }
  else if (j < 10) { int c = j - 5; A = xb + c * 65536; B = A; G = Gb + c * 65536; }
  else             { int p = j - 10; int k = p / 5, c = p % 5;
                     A = xa + k * 65536; B = xb + c * 65536; G = Gab + p * 65536; }
  __shared__ float As[256][17];
  __shared__ float Bs[256][17];
  int tid = threadIdx.x;
  int ti = tid >> 5, tj = tid & 31;
  float acc[8][8];
  #pragma unroll
  for (int r = 0; r < 8; ++r)
    #pragma unroll
    for (int s = 0; s < 8; ++s) acc[r][s] = 0.f;
  for (int k0 = 0; k0 < 256; k0 += 16) {
    #pragma unroll
    for (int e = 0; e < 4; ++e) {
      int idx = tid + e * 1024;
      int i = idx >> 4, kk = idx & 15;
      As[i][kk] = A[i * 256 + k0 + kk];
      Bs[i][kk] = B[i * 256 + k0 + kk];
    }
    __syncthreads();
    #pragma unroll
    for (int kk = 0; kk < 16; ++kk) {
      float a[8], b[8];
      #pragma unroll
      for (int r = 0; r < 8; ++r) a[r] = As[ti * 8 + r][kk];
      #pragma unroll
      for (int s = 0; s < 8; ++s) b[s] = Bs[tj * 8 + s][kk];
      #pragma unroll
      for (int r = 0; r < 8; ++r)
        #pragma unroll
        for (int s = 0; s < 8; ++s) acc[r][s] += a[r] * b[s];
    }
    __syncthreads();
  }
  #pragma unroll
  for (int r = 0; r < 8; ++r)
    #pragma unroll
    for (int s = 0; s < 8; ++s)
      G[(ti * 8 + r) * 256 + tj * 8 + s] = acc[r][s];
}

// ============================================================================
// K6: extract Gram diagonals
// ============================================================================
__global__ __launch_bounds__(256) void k_diag(const float* __restrict__ Ga,
                                              const float* __restrict__ Gb,
                                              float* diagA, float* diagB) {
  int t = blockIdx.x; int i = threadIdx.x;
  if (t < 5) diagA[t * 256 + i] = Ga[t * 65536 + i * 257];
  else { int c = t - 5; diagB[c * 256 + i] = Gb[c * 65536 + i * 257]; }
}

// ============================================================================
// K7: G -> D in place: D_ij = max(dA_i + dB_j - 2 g_ij, 0)
// ============================================================================
__global__ __launch_bounds__(256) void k_conv(float* Ga, float* Gb, float* Gab,
                                              const float* __restrict__ diagA,
                                              const float* __restrict__ diagB) {
  int j = blockIdx.x; int tid = threadIdx.x;
  float* G; const float *dA, *dB;
  if (j < 5)       { G = Ga + j * 65536; dA = diagA + j * 256; dB = dA; }
  else if (j < 10) { int c = j - 5; G = Gb + c * 65536; dA = diagB + c * 256; dB = dA; }
  else             { int p = j - 10; int k = p / 5, c = p % 5;
                     G = Gab + p * 65536; dA = diagA + k * 256; dB = diagB + c * 256; }
  float db = dB[tid];
  for (int i = 0; i < 256; ++i) {
    float g = G[i * 256 + tid];
    float d = dA[i] + db - 2.0f * g;
    G[i * 256 + tid] = d > 0.f ? d : 0.f;
  }
}

// ============================================================================
// K8: per (k,c): exact median (3-pass radix select) -> sigma -> multi-RBF MMD^2
// ============================================================================
__global__ __launch_bounds__(256) void k_medmmd(const int* __restrict__ meta,
                                                const float* __restrict__ Da_all,
                                                const float* __restrict__ Db_all,
                                                const float* __restrict__ Dab_all,
                                                float* mmd_out) {
  int p = blockIdx.x; int kcl = p / 5, ccl = p % 5;
  int tid = threadIdx.x;
  int nsf = meta[kcl], nqf = meta[5 + ccl];
  if (nsf < 2 || nqf < 2) { if (tid == 0) mmd_out[p] = 0.0f; return; }
  int na = meta[10 + kcl], nb = meta[15 + ccl];
  const float* Da  = Da_all  + kcl * 65536;
  const float* Db  = Db_all  + ccl * 65536;
  const float* Dab = Dab_all + p * 65536;

  __shared__ unsigned int hist[2048];
  __shared__ unsigned int sh[8];
  __shared__ double dred[256];

  unsigned int N = (unsigned int)(na + nb) * (unsigned int)(na + nb);

  for (int b = tid; b < 2048; b += 256) hist[b] = 0;
  if (tid < 8) sh[tid] = 0;
  __syncthreads();
  for (int i = 0; i < na; ++i) if (tid < na) {
    unsigned int key = __float_as_uint(Da[i * 256 + tid]);
    atomicAdd(&hist[key >> 21], 1u);
    if (key == 0u) atomicAdd(&sh[0], 1u);
  }
  for (int i = 0; i < nb; ++i) if (tid < nb) {
    unsigned int key = __float_as_uint(Db[i * 256 + tid]);
    atomicAdd(&hist[key >> 21], 1u);
    if (key == 0u) atomicAdd(&sh[0], 1u);
  }
  for (int i = 0; i < na; ++i) if (tid < nb) {
    unsigned int key = __float_as_uint(Dab[i * 256 + tid]);
    atomicAdd(&hist[key >> 21], 2u);
    if (key == 0u) atomicAdd(&sh[0], 2u);
  }
  __syncthreads();
  if (tid == 0) {
    unsigned int nz = sh[0];
    if (nz >= N) sh[1] = 1u;
    else {
      unsigned int r = nz + (N - nz - 1u) / 2u;
      unsigned int cum = 0, bsel = 2047;
      for (int b = 0; b < 2048; ++b) {
        unsigned int nc = cum + hist[b];
        if (nc > r) { bsel = (unsigned int)b; break; }
        cum = nc;
      }
      sh[1] = 0u; sh[2] = bsel; sh[3] = r - cum;
    }
  }
  __syncthreads();
  float base;
  if (!sh[1]) {
    unsigned int b1 = sh[2];
    for (int b = tid; b < 2048; b += 256) hist[b] = 0;
    __syncthreads();
    for (int i = 0; i < na; ++i) if (tid < na) {
      unsigned int key = __float_as_uint(Da[i * 256 + tid]);
      if ((key >> 21) == b1) atomicAdd(&hist[(key >> 10) & 0x7FFu], 1u);
    }
    for (int i = 0; i < nb; ++i) if (tid < nb) {
      unsigned int key = __float_as_uint(Db[i * 256 + tid]);
      if ((key >> 21) == b1) atomicAdd(&hist[(key >> 10) & 0x7FFu], 1u);
    }
    for (int i = 0; i < na; ++i) if (tid < nb) {
      unsigned int key = __float_as_uint(Dab[i * 256 + tid]);
      if ((key >> 21) == b1) atomicAdd(&hist[(key >> 10) & 0x7FFu], 2u);
    }
    __syncthreads();
    if (tid == 0) {
      unsigned int r = sh[3];
      unsigned int cum = 0, bsel = 2047;
      for (int b = 0; b < 2048; ++b) {
        unsigned int nc = cum + hist[b];
        if (nc > r) { bsel = (unsigned int)b; break; }
        cum = nc;
      }
      sh[4] = bsel; sh[5] = r - cum;
    }
    __syncthreads();
    unsigned int pref2 = (b1 << 11) | sh[4];
    for (int b = tid; b < 1024; b += 256) hist[b] = 0;
    __syncthreads();
    for (int i = 0; i < na; ++i) if (tid < na) {
      unsigned int key = __float_as_uint(Da[i * 256 + tid]);
      if ((key >> 10) == pref2) atomicAdd(&hist[key & 0x3FFu], 1u);
    }
    for (int i = 0; i < nb; ++i) if (tid < nb) {
      unsigned int key = __float_as_uint(Db[i * 256 + tid]);
      if ((key >> 10) == pref2) atomicAdd(&hist[key & 0x3FFu], 1u);
    }
    for (int i = 0; i < na; ++i) if (tid < nb) {
      unsigned int key = __float_as_uint(Dab[i * 256 + tid]);
      if ((key >> 10) == pref2) atomicAdd(&hist[key & 0x3FFu], 2u);
    }
    __syncthreads();
    if (tid == 0) {
      unsigned int r = sh[5];
      unsigned int cum = 0, bsel = 1023;
      for (int b = 0; b < 1024; ++b) {
        unsigned int nc = cum + hist[b];
        if (nc > r) { bsel = (unsigned int)b; break; }
        cum = nc;
      }
      sh[6] = (pref2 << 10) | bsel;
    }
    __syncthreads();
    base = sqrtf(__uint_as_float(sh[6]) + 1e-6f);
  } else {
    base = 1.0f;
  }

  float g2 = base * base;
  float c0 = 1.0f / (2.0f * g2 * 0.25f);
  float c1 = 1.0f / (2.0f * g2 * 1.0f);
  float c2 = 1.0f / (2.0f * g2 * 4.0f);
  float c3 = 1.0f / (2.0f * g2 * 16.0f);
  double accA = 0.0, accB = 0.0, accAB = 0.0;
  for (int i = 0; i < na; ++i) if (tid < na) {
    float d = Da[i * 256 + tid];
    accA += (double)(expf(-d * c0) + expf(-d * c1) + expf(-d * c2) + expf(-d * c3));
  }
  for (int i = 0; i < nb; ++i) if (tid < nb) {
    float d = Db[i * 256 + tid];
    accB += (double)(expf(-d * c0) + expf(-d * c1) + expf(-d * c2) + expf(-d * c3));
  }
  for (int i = 0; i < na; ++i) if (tid < nb) {
    float d = Dab[i * 256 + tid];
    accAB += (double)(expf(-d * c0) + expf(-d * c1) + expf(-d * c2) + expf(-d * c3));
  }
  dred[tid] = accA; __syncthreads();
  for (int s = 128; s > 0; s >>= 1) { if (tid < s) dred[tid] += dred[tid + s]; __syncthreads(); }
  double SA = dred[0]; __syncthreads();
  dred[tid] = accB; __syncthreads();
  for (int s = 128; s > 0; s >>= 1) { if (tid < s) dred[tid] += dred[tid + s]; __syncthreads(); }
  double SB = dred[0]; __syncthreads();
  dred[tid] = accAB; __syncthreads();
  for (int s = 128; s > 0; s >>= 1) { if (tid < s) dred[tid] += dred[tid + s]; __syncthreads(); }
  double SAB = dred[0];
  if (tid == 0) {
    double meanA  = SA  / ((double)na * (double)na);
    double meanB  = SB  / ((double)nb * (double)nb);
    double meanAB = SAB / ((double)na * (double)nb);
    double m = meanA + meanB - 2.0 * meanAB;
    mmd_out[p] = (float)(m > 0.0 ? m : 0.0);
  }
}

// ============================================================================
// K9: final weighted loss
// ============================================================================
__global__ void k_final(const int* __restrict__ meta, const float* __restrict__ mmd,
                        float* out) {
  if (threadIdx.x != 0 || blockIdx.x != 0) return;
  double total = 0.0, vw = 0.0;
  for (int c = 0; c < 5; ++c) {
    int nsf = meta[c], nqf = meta[5 + c];
    if (nsf < 2 || nqf < 2) continue;
    double pos = (double)mmd[c * 5 + c];
    bool any = false; double best = 0.0;
    for (int k = 0; k < 5; ++k) {
      if (k == c || meta[k] < 2) continue;
      double v = (double)mmd[k * 5 + c];
      if (!any || v < best) { best = v; any = true; }
    }
    double lc = any ? fmax(pos - best + 0.1, 0.0) : pos;
    double w = sqrt((double)nsf * (double)nqf);
    total += w * lc; vw += w;
  }
  out[0] = (float)(0.1 * total / fmax(vw, 1e-12));
}

// ============================================================================
// host launcher
// ============================================================================
extern "C" void kernel_launch(void* const* d_in, const int* in_sizes, int n_in,
                              void* d_out, int out_size, void* d_ws, size_t ws_size,
                              hipStream_t stream) {
  const float* f_s = (const float*)d_in[0];
  const int*   l_s = (const int*)d_in[1];
  const float* f_q = (const float*)d_in[2];
  const int*   l_q = (const int*)d_in[3];
  float* out = (float*)d_out;
  char* ws = (char*)d_ws;

  size_t off = 0;
  auto take = [&](size_t bytes) -> void* {
    void* p = ws + off;
    off = (off + bytes + 255) & ~(size_t)255;
    return p;
  };
  int*   meta     = (int*)take(32 * 4);
  int*   sup_list = (int*)take((size_t)5 * S_LEN * 4);
  int*   qry_list = (int*)take((size_t)5 * Q_TOT * 4);
  int*   Jsup     = (int*)take((size_t)5 * S_LEN * 4);   // also k_collect tmpS
  int*   Jqry     = (int*)take((size_t)5 * Q_TOT * 4);   // also k_collect tmpQ
  unsigned int* draws = (unsigned int*)take((10ull * CAPS64 + 10ull * CAPQ64) * 4);
  int*   sel      = (int*)take((size_t)10 * MAXS * 4);
  float* xa       = (float*)take((size_t)5 * 65536 * 4);
  float* xb       = (float*)take((size_t)5 * 65536 * 4);
  float* Ga       = (float*)take((size_t)5 * 65536 * 4);
  float* Gb       = (float*)take((size_t)5 * 65536 * 4);
  float* Gab      = (float*)take((size_t)25 * 65536 * 4);
  float* diagA    = (float*)take((size_t)5 * 256 * 4);
  float* diagB    = (float*)take((size_t)5 * 256 * 4);
  float* mmd      = (float*)take(25 * 4);
  if (off > ws_size) return;

  k_draws<<<10, 256, 0, stream>>>(draws);
  k_collect<<<10, 256, 0, stream>>>(l_s, l_q, meta, sup_list, qry_list, Jsup, Jqry);
  k_consume<<<10, 64, 0, stream>>>(meta, draws, Jsup, Jqry);
  k_prov<<<10, 256, 0, stream>>>(meta, sup_list, qry_list, Jsup, Jqry, sel);
  k_gather<<<80, 256, 0, stream>>>(f_s, f_q, meta, sel, xa, xb);
  k_gram<<<35, 1024, 0, stream>>>(xa, xb, Ga, Gb, Gab);
  k_diag<<<10, 256, 0, stream>>>(Ga, Gb, diagA, diagB);
  k_conv<<<35, 256, 0, stream>>>(Ga, Gb, Gab, diagA, diagB);
  k_medmmd<<<25, 256, 0, stream>>>(meta, Ga, Gb, Gab, mmd);
  k_final<<<1, 64, 0, stream>>>(meta, mmd, out);
}

// Round 4
// 3460.962 us; speedup vs baseline: 3.9572x; 1.4451x over previous
//
#include <hip/hip_runtime.h>

// ============================================================================
// numpy RNG replication: SeedSequence + PCG64 (XSL-RR 128/64), next32 buffering
// ============================================================================
struct U128 { unsigned long long hi, lo; };

__device__ __forceinline__ U128 u128_mul(U128 a, U128 b) {
  U128 r;
  r.lo = a.lo * b.lo;
  r.hi = __umul64hi(a.lo, b.lo) + a.hi * b.lo + a.lo * b.hi;
  return r;
}
__device__ __forceinline__ U128 u128_add(U128 a, U128 b) {
  U128 r; r.lo = a.lo + b.lo; r.hi = a.hi + b.hi + (r.lo < a.lo ? 1ull : 0ull); return r;
}

struct Pcg64 {
  U128 state, inc;
};

__device__ __forceinline__ void pcg_step(Pcg64* r) {
  const U128 M = {0x2360ed051fc65da4ull, 0x4385df649fccf645ull};
  r->state = u128_add(u128_mul(r->state, M), r->inc);
}
__device__ __forceinline__ unsigned long long pcg_next64(Pcg64* r) {
  pcg_step(r);
  unsigned int rot = (unsigned int)(r->state.hi >> 58);   // state >> 122
  unsigned long long x = r->state.hi ^ r->state.lo;       // XSL
  return (x >> rot) | (x << ((64u - rot) & 63u));         // RR
}

// SeedSequence constants (numpy bit_generator.pyx)
__device__ __forceinline__ unsigned int ss_hashmix(unsigned int v, unsigned int* hc) {
  v ^= *hc; *hc = *hc * 0x931e8875u; v *= *hc; v ^= v >> 16; return v;
}
__device__ __forceinline__ unsigned int ss_mix(unsigned int x, unsigned int y) {
  unsigned int r = x * 0xca01f9ddu ^ y * 0x4973f715u; r ^= r >> 16; return r;
}
__device__ void pcg_seed(Pcg64* rng, unsigned int seed) {
  unsigned int pool[4]; unsigned int hc = 0x43b0d7e5u;   // INIT_A
  pool[0] = ss_hashmix(seed, &hc);
  for (int i = 1; i < 4; ++i) pool[i] = ss_hashmix(0u, &hc);
  for (int s = 0; s < 4; ++s)
    for (int d = 0; d < 4; ++d)
      if (s != d) pool[d] = ss_mix(pool[d], ss_hashmix(pool[s], &hc));
  unsigned int hc2 = 0x8b51f9ddu;                        // INIT_B
  unsigned long long w64[4];
  for (int i = 0; i < 4; ++i) {
    unsigned int lo = pool[(2*i) & 3];
    lo ^= hc2; hc2 *= 0x58f38dedu; lo *= hc2; lo ^= lo >> 16;
    unsigned int hi = pool[(2*i+1) & 3];
    hi ^= hc2; hc2 *= 0x58f38dedu; hi *= hc2; hi ^= hi >> 16;
    w64[i] = (unsigned long long)lo | ((unsigned long long)hi << 32);
  }
  U128 initstate = {w64[0], w64[1]};   // PCG_128BIT_CONSTANT(seed[0], seed[1]): [0] is HIGH
  U128 initseq   = {w64[2], w64[3]};
  rng->inc.hi = (initseq.hi << 1) | (initseq.lo >> 63);
  rng->inc.lo = (initseq.lo << 1) | 1ull;
  rng->state.hi = 0; rng->state.lo = 0;
  pcg_step(rng);
  rng->state = u128_add(rng->state, initstate);
  pcg_step(rng);
}

// affine jump-ahead: state <- A^delta * state + (A^delta-1)/(A-1)*inc
__device__ void pcg_advance(Pcg64* r, unsigned long long delta) {
  U128 acc_mult = {0ull, 1ull}, acc_plus = {0ull, 0ull};
  U128 cur_mult = {0x2360ed051fc65da4ull, 0x4385df649fccf645ull};
  U128 cur_plus = r->inc;
  while (delta) {
    if (delta & 1ull) {
      acc_mult = u128_mul(acc_mult, cur_mult);
      acc_plus = u128_add(u128_mul(acc_plus, cur_mult), cur_plus);
    }
    U128 one = {0ull, 1ull};
    U128 cm1 = u128_add(cur_mult, one);
    cur_plus = u128_mul(cm1, cur_plus);
    cur_mult = u128_mul(cur_mult, cur_mult);
    delta >>= 1;
  }
  r->state = u128_add(u128_mul(r->state, acc_mult), acc_plus);
}

// ============================================================================
// Problem constants
// ============================================================================
#define S_LEN   16384
#define Q_LEN   65536
#define Q_TOT   327680     // 5*65536
#define DFEAT   256
#define MAXS    256
#define CAPS64  24576      // next64 outputs per support class (49152 u32 draws)
#define CAPQ64  98304      // next64 outputs per query class  (196608 u32 draws)

// meta layout: [0..4]=ns_full, [5..9]=nq_full, [10..14]=na, [15..19]=nb

// ============================================================================
// K0: parallel draw-stream generation (exact numpy next32 sequence, lo first)
// ============================================================================
__global__ __launch_bounds__(256) void k_draws(unsigned int* __restrict__ draws) {
  int t = blockIdx.x; int cls = t % 5; int isq = t / 5;
  unsigned int seed = (unsigned)(1000 + isq * 1000 + cls + 1);
  unsigned long long cap64 = isq ? CAPQ64 : CAPS64;
  unsigned int* dst = draws + (isq ? (10ull * CAPS64 + (unsigned long long)cls * 2 * CAPQ64)
                                   : ((unsigned long long)cls * 2 * CAPS64));
  Pcg64 rng; pcg_seed(&rng, seed);
  int tid = threadIdx.x;
  unsigned long long C = cap64 / 256ull;     // 96 or 384
  unsigned long long k0 = (unsigned long long)tid * C;
  pcg_advance(&rng, k0);
  uint2* d2 = (uint2*)dst;
  for (unsigned long long m = 0; m < C; ++m) {
    unsigned long long o = pcg_next64(&rng);
    d2[k0 + m] = make_uint2((unsigned int)o, (unsigned int)(o >> 32));
  }
}

// ============================================================================
// K1: collect class index lists (reference order), 4-wave quarter compaction
// ============================================================================
__global__ __launch_bounds__(256) void k_collect(const int* __restrict__ ls,
                                                 const int* __restrict__ lq,
                                                 int* meta, int* sup_list, int* qry_list,
                                                 int* tmpS, int* tmpQ) {
  int t = blockIdx.x;
  int cls = t % 5; int isq = t / 5;
  const int* src; int n_src, matchval; int* out; int* tmp;
  if (!isq) { src = ls + cls * S_LEN; n_src = S_LEN; matchval = 1;
              out = sup_list + cls * S_LEN; tmp = tmpS + cls * S_LEN; }
  else      { src = lq; n_src = Q_TOT; matchval = cls + 1;
              out = qry_list + (size_t)cls * Q_TOT; tmp = tmpQ + (size_t)cls * Q_TOT; }
  int tid = threadIdx.x;
  int w = tid >> 6; int lane = tid & 63;
  int qlen = n_src >> 2;                 // 4096 or 81920, multiple of 64
  int beg = w * qlen;
  __shared__ int cnt[4];
  int base = 0;
  unsigned long long lmask = (1ull << lane) - 1ull;
  for (int i0 = beg; i0 < beg + qlen; i0 += 64) {
    int i = i0 + lane;
    bool p = (src[i] == matchval);
    unsigned long long m = __ballot(p);
    if (p) tmp[beg + base + __popcll(m & lmask)] = i;
    base += __popcll(m);
  }
  if (lane == 0) cnt[w] = base;
  __syncthreads();
  int c0 = cnt[0], c1 = cnt[1], c2 = cnt[2], c3 = cnt[3];
  int offs[4] = {0, c0, c0 + c1, c0 + c1 + c2};
  int ntot = c0 + c1 + c2 + c3;
  for (int ww = 0; ww < 4; ++ww) {
    int cw = cnt[ww];
    for (int idx = tid; idx < cw; idx += 256)
      out[offs[ww] + idx] = tmp[ww * qlen + idx];
  }
  if (tid == 0) {
    meta[isq * 5 + cls] = ntot;
    meta[10 + isq * 5 + cls] = ntot < MAXS ? ntot : MAXS;
  }
}

// ============================================================================
// K2: wave-parallel masked-rejection automaton, INTERVAL-COMMIT resolution.
//     Each uncommitted lane's trial index lies in [il_min, il_min+U] where
//     U = #uncommitted lanes below. With mask constant over the interval:
//       w > il_max  -> reject under EVERY resolution -> commit reject
//       w <= il_min -> accept under EVERY resolution -> commit accept
//     Middle band is ~U/i probable (~0.03/chunk) -> ~1 pass resolves all 64.
//     Lowest uncertain lane has U=0 -> guaranteed progress (exact, <=64 iters).
// ============================================================================
__global__ __launch_bounds__(64) void k_consume(const int* __restrict__ meta,
                                                const unsigned int* __restrict__ draws,
                                                int* Jsup, int* Jqry) {
  int t = blockIdx.x; int cls = t % 5; int isq = t / 5;
  int n = meta[isq * 5 + cls];
  if (n <= MAXS) return;
  const unsigned int* d = draws + (isq ? (10ull * CAPS64 + (unsigned long long)cls * 2 * CAPQ64)
                                       : ((unsigned long long)cls * 2 * CAPS64));
  int* J = isq ? (Jqry + (size_t)cls * Q_TOT) : (Jsup + cls * S_LEN);
  int lane = threadIdx.x;
  unsigned long long lmask = (1ull << lane) - 1ull;
  unsigned long long lbit  = (1ull << lane);
  int i = n - 1;
  size_t p = 0;
  unsigned int v = d[lane];
  for (;;) {
    unsigned int vnext = d[p + 64 + lane];     // prefetch next chunk
    unsigned long long rej = 0ull, acc = 0ull;
    for (int it = 0; it < 72; ++it) {
      unsigned long long unc = ~(rej | acc);
      if (!unc) break;
      int rbelow = __popcll(rej & lmask);
      int ubelow = __popcll(unc & lmask);
      int il_min = i - lane + rbelow;          // >= 193 always
      int il_max = il_min + ubelow;
      bool def_rej = false, def_acc = false;
      if (unc & lbit) {
        unsigned int mlo = 0xFFFFFFFFu >> __clz(il_min);
        unsigned int mhi = 0xFFFFFFFFu >> __clz(il_max);
        if (mlo == mhi) {
          unsigned int w = v & mlo;
          def_rej = (w > (unsigned int)il_max);
          def_acc = (w <= (unsigned int)il_min);
        } else if (ubelow == 0) {              // octave boundary: exact resolve
          unsigned int w = v & mlo;
          def_rej = (w > (unsigned int)il_min);
          def_acc = !def_rej;
        }
      }
      unsigned long long nr = __ballot(def_rej);
      unsigned long long nc = __ballot(def_acc);
      rej |= nr; acc |= nc;
    }
    int rbelow = __popcll(rej & lmask);
    int il = i - lane + rbelow;
    int totAcc = 64 - __popcll(rej);
    if ((acc & lbit) && il >= MAXS)
      J[il] = (int)(v & (0xFFFFFFFFu >> __clz(il)));
    int needed = i - (MAXS - 1);
    if (totAcc >= needed) break;
    i -= totAcc; p += 64; v = vnext;
  }
}

// ============================================================================
// K3: provenance walk (i ascending 256..n-1), LDS-staged J, 8-wide register
//     window so ds_reads batch off the dependent compare-select chain
// ============================================================================
__global__ __launch_bounds__(256) void k_prov(const int* __restrict__ meta,
                                              const int* __restrict__ sup_list,
                                              const int* __restrict__ qry_list,
                                              const int* __restrict__ Jsup,
                                              const int* __restrict__ Jqry,
                                              int* sel) {
  __shared__ int sj[2048];
  int t = blockIdx.x; int tid = threadIdx.x;
  int cls = t % 5; int isq = t / 5;
  int n = meta[isq * 5 + cls];
  const int* list; const int* J;
  if (!isq) { list = sup_list + cls * S_LEN; J = Jsup + cls * S_LEN; }
  else      { list = qry_list + (size_t)cls * Q_TOT; J = Jqry + (size_t)cls * Q_TOT; }
  int* s = sel + t * MAXS;
  if (n <= MAXS) { if (tid < n) s[tid] = list[tid]; return; }
  int pos = tid;
  int i0 = MAXS;
  while (i0 < n) {
    int lim = n < i0 + 2048 ? n : i0 + 2048;
    int cntc = lim - i0;
    __syncthreads();
    for (int k = tid; k < cntc; k += 256) sj[k] = J[i0 + k];
    __syncthreads();
    int k = 0;
    for (; k + 8 <= cntc; k += 8) {
      int j0 = sj[k+0], j1 = sj[k+1], j2 = sj[k+2], j3 = sj[k+3];
      int j4 = sj[k+4], j5 = sj[k+5], j6 = sj[k+6], j7 = sj[k+7];
      int i = i0 + k;
      pos = (pos == i)     ? j0 : ((pos == j0) ? i     : pos);
      pos = (pos == i + 1) ? j1 : ((pos == j1) ? i + 1 : pos);
      pos = (pos == i + 2) ? j2 : ((pos == j2) ? i + 2 : pos);
      pos = (pos == i + 3) ? j3 : ((pos == j3) ? i + 3 : pos);
      pos = (pos == i + 4) ? j4 : ((pos == j4) ? i + 4 : pos);
      pos = (pos == i + 5) ? j5 : ((pos == j5) ? i + 5 : pos);
      pos = (pos == i + 6) ? j6 : ((pos == j6) ? i + 6 : pos);
      pos = (pos == i + 7) ? j7 : ((pos == j7) ? i + 7 : pos);
    }
    for (; k < cntc; ++k) {
      int jv = sj[k]; int i = i0 + k;
      pos = (pos == i) ? jv : ((pos == jv) ? i : pos);
    }
    i0 = lim;
  }
  s[tid] = list[pos];
}

// ============================================================================
// K4: gather selected feature rows + fused row-norm (x / (||x|| + 1e-12)).
//     80 blocks; 8 lanes per row; 32 batched independent loads per thread.
// ============================================================================
__global__ __launch_bounds__(256) void k_gather(const float* __restrict__ f_s,
                                                const float* __restrict__ f_q,
                                                const int* __restrict__ meta,
                                                const int* __restrict__ sel,
                                                float* xa, float* xb) {
  int blk = blockIdx.x;
  int t = blk >> 3;          // class-pair 0..9
  int slab = blk & 7;        // 8 slabs x 32 rows
  int cls = t % 5; int isq = t / 5;
  int n = meta[10 + isq * 5 + cls];
  int tid = threadIdx.x;
  int row = slab * 32 + (tid >> 3);
  int dg = tid & 7;          // 8 d-groups of 32
  if (row >= n) return;      // group-uniform (8 lanes share row)
  int id = sel[t * MAXS + row];
  const float* src; size_t stride; float* dst;
  if (!isq) {
    src = f_s + (size_t)cls * DFEAT * S_LEN + id; stride = S_LEN;
    dst = xa + cls * (MAXS * DFEAT) + row * DFEAT;
  } else {
    int m = id >> 16; int nn = id & 0xFFFF;
    src = f_q + (size_t)m * DFEAT * Q_LEN + nn; stride = Q_LEN;
    dst = xb + cls * (MAXS * DFEAT) + row * DFEAT;
  }
  float v[32];
  #pragma unroll
  for (int dd = 0; dd < 32; ++dd)
    v[dd] = src[(size_t)(dg * 32 + dd) * stride];
  float ss = 0.f;
  #pragma unroll
  for (int dd = 0; dd < 32; ++dd) ss += v[dd] * v[dd];
  ss += __shfl_xor(ss, 1);
  ss += __shfl_xor(ss, 2);
  ss += __shfl_xor(ss, 4);
  float inv = 1.0f / (sqrtf(ss) + 1e-12f);
  #pragma unroll
  for (int dd = 0; dd < 32; ++dd) dst[dg * 32 + dd] = v[dd] * inv;
}

// ============================================================================
// K5: 35 Gram matrices (256x256, K=256)
// ============================================================================
__global__ __launch_bounds__(1024) void k_gram(const float* __restrict__ xa,
                                               const float* __restrict__ xb,
                                               float* Ga, float* Gb, float* Gab) {
  int j = blockIdx.x;
  const float *A, *B; float* G;
  if (j < 5)       { A = xa + j * 65536; B = A; G = Ga + j * 65536; }
  else if (j < 10) { int c = j - 5; A = xb + c * 65536; B = A; G = Gb + c * 65536; }
  else             { int p = j - 10; int k = p / 5, c = p % 5;
                     A = xa + k * 65536; B = xb + c * 65536; G = Gab + p * 65536; }
  __shared__ float As[256][17];
  __shared__ float Bs[256][17];
  int tid = threadIdx.x;
  int ti = tid >> 5, tj = tid & 31;
  float acc[8][8];
  #pragma unroll
  for (int r = 0; r < 8; ++r)
    #pragma unroll
    for (int s = 0; s < 8; ++s) acc[r][s] = 0.f;
  for (int k0 = 0; k0 < 256; k0 += 16) {
    #pragma unroll
    for (int e = 0; e < 4; ++e) {
      int idx = tid + e * 1024;
      int i = idx >> 4, kk = idx & 15;
      As[i][kk] = A[i * 256 + k0 + kk];
      Bs[i][kk] = B[i * 256 + k0 + kk];
    }
    __syncthreads();
    #pragma unroll
    for (int kk = 0; kk < 16; ++kk) {
      float a[8], b[8];
      #pragma unroll
      for (int r = 0; r < 8; ++r) a[r] = As[ti * 8 + r][kk];
      #pragma unroll
      for (int s = 0; s < 8; ++s) b[s] = Bs[tj * 8 + s][kk];
      #pragma unroll
      for (int r = 0; r < 8; ++r)
        #pragma unroll
        for (int s = 0; s < 8; ++s) acc[r][s] += a[r] * b[s];
    }
    __syncthreads();
  }
  #pragma unroll
  for (int r = 0; r < 8; ++r)
    #pragma unroll
    for (int s = 0; s < 8; ++s)
      G[(ti * 8 + r) * 256 + tj * 8 + s] = acc[r][s];
}

// ============================================================================
// K6: extract Gram diagonals
// ============================================================================
__global__ __launch_bounds__(256) void k_diag(const float* __restrict__ Ga,
                                              const float* __restrict__ Gb,
                                              float* diagA, float* diagB) {
  int t = blockIdx.x; int i = threadIdx.x;
  if (t < 5) diagA[t * 256 + i] = Ga[t * 65536 + i * 257];
  else { int c = t - 5; diagB[c * 256 + i] = Gb[c * 65536 + i * 257]; }
}

// ============================================================================
// K7: G -> D in place: D_ij = max(dA_i + dB_j - 2 g_ij, 0)
// ============================================================================
__global__ __launch_bounds__(256) void k_conv(float* Ga, float* Gb, float* Gab,
                                              const float* __restrict__ diagA,
                                              const float* __restrict__ diagB) {
  int j = blockIdx.x; int tid = threadIdx.x;
  float* G; const float *dA, *dB;
  if (j < 5)       { G = Ga + j * 65536; dA = diagA + j * 256; dB = dA; }
  else if (j < 10) { int c = j - 5; G = Gb + c * 65536; dA = diagB + c * 256; dB = dA; }
  else             { int p = j - 10; int k = p / 5, c = p % 5;
                     G = Gab + p * 65536; dA = diagA + k * 256; dB = diagB + c * 256; }
  float db = dB[tid];
  for (int i = 0; i < 256; ++i) {
    float g = G[i * 256 + tid];
    float d = dA[i] + db - 2.0f * g;
    G[i * 256 + tid] = d > 0.f ? d : 0.f;
  }
}

// ============================================================================
// K8: per (k,c): exact median via 31-step BISECTION on float bits (no LDS
//     atomics — distance keys concentrate, histogram buckets serialized).
//     count(<= pivot) with Dab doubled; rank r = nz + (N-nz-1)/2.
//     Then multi-sigma RBF MMD^2.
// ============================================================================
__global__ __launch_bounds__(256) void k_medmmd(const int* __restrict__ meta,
                                                const float* __restrict__ Da_all,
                                                const float* __restrict__ Db_all,
                                                const float* __restrict__ Dab_all,
                                                float* mmd_out) {
  int p = blockIdx.x; int kcl = p / 5, ccl = p % 5;
  int tid = threadIdx.x;
  int nsf = meta[kcl], nqf = meta[5 + ccl];
  if (nsf < 2 || nqf < 2) { if (tid == 0) mmd_out[p] = 0.0f; return; }
  int na = meta[10 + kcl], nb = meta[15 + ccl];
  const float* Da  = Da_all  + kcl * 65536;
  const float* Db  = Db_all  + ccl * 65536;
  const float* Dab = Dab_all + p * 65536;

  __shared__ unsigned int sred[256];
  __shared__ double dred[256];

  unsigned int N = (unsigned int)(na + nb) * (unsigned int)(na + nb);
  bool fast = (na == 256) && (nb == 256);

  // ---- exact-zero count (Dab double) ----
  unsigned int zc = 0;
  if (fast) {
    const float4* A4 = (const float4*)Da;
    const float4* B4 = (const float4*)Db;
    const float4* C4 = (const float4*)Dab;
    for (int k = 0; k < 64; ++k) {
      float4 a = A4[tid + k * 256];
      zc += (a.x == 0.f ? 1u : 0u) + (a.y == 0.f ? 1u : 0u)
          + (a.z == 0.f ? 1u : 0u) + (a.w == 0.f ? 1u : 0u);
    }
    for (int k = 0; k < 64; ++k) {
      float4 b = B4[tid + k * 256];
      zc += (b.x == 0.f ? 1u : 0u) + (b.y == 0.f ? 1u : 0u)
          + (b.z == 0.f ? 1u : 0u) + (b.w == 0.f ? 1u : 0u);
    }
    for (int k = 0; k < 64; ++k) {
      float4 c = C4[tid + k * 256];
      zc += 2u * ((c.x == 0.f ? 1u : 0u) + (c.y == 0.f ? 1u : 0u)
                + (c.z == 0.f ? 1u : 0u) + (c.w == 0.f ? 1u : 0u));
    }
  } else {
    if (tid < na) for (int i = 0; i < na; ++i) zc += (Da[i * 256 + tid] == 0.f) ? 1u : 0u;
    if (tid < nb) for (int i = 0; i < nb; ++i) zc += (Db[i * 256 + tid] == 0.f) ? 1u : 0u;
    if (tid < nb) for (int i = 0; i < na; ++i) zc += (Dab[i * 256 + tid] == 0.f) ? 2u : 0u;
  }
  sred[tid] = zc; __syncthreads();
  for (int s = 128; s > 0; s >>= 1) { if (tid < s) sred[tid] += sred[tid + s]; __syncthreads(); }
  unsigned int nz = sred[0]; __syncthreads();

  float base;
  if (nz >= N) {
    base = 1.0f;
  } else {
    unsigned int r = nz + (N - nz - 1u) / 2u;   // 0-based target rank
    unsigned int lo = 0u, hi = 0x41000000u;     // keys in [0, 8.0): unit rows => d <= ~4
    while (lo < hi) {
      unsigned int mid = (lo + hi) >> 1;
      float piv = __uint_as_float(mid);
      unsigned int cnt = 0;
      if (fast) {
        const float4* A4 = (const float4*)Da;
        const float4* B4 = (const float4*)Db;
        const float4* C4 = (const float4*)Dab;
        for (int k = 0; k < 64; ++k) {
          float4 a = A4[tid + k * 256];
          cnt += (a.x <= piv ? 1u : 0u) + (a.y <= piv ? 1u : 0u)
               + (a.z <= piv ? 1u : 0u) + (a.w <= piv ? 1u : 0u);
        }
        for (int k = 0; k < 64; ++k) {
          float4 b = B4[tid + k * 256];
          cnt += (b.x <= piv ? 1u : 0u) + (b.y <= piv ? 1u : 0u)
               + (b.z <= piv ? 1u : 0u) + (b.w <= piv ? 1u : 0u);
        }
        for (int k = 0; k < 64; ++k) {
          float4 c = C4[tid + k * 256];
          cnt += 2u * ((c.x <= piv ? 1u : 0u) + (c.y <= piv ? 1u : 0u)
                     + (c.z <= piv ? 1u : 0u) + (c.w <= piv ? 1u : 0u));
        }
      } else {
        if (tid < na) for (int i = 0; i < na; ++i) cnt += (Da[i * 256 + tid] <= piv) ? 1u : 0u;
        if (tid < nb) for (int i = 0; i < nb; ++i) cnt += (Db[i * 256 + tid] <= piv) ? 1u : 0u;
        if (tid < nb) for (int i = 0; i < na; ++i) cnt += (Dab[i * 256 + tid] <= piv) ? 2u : 0u;
      }
      sred[tid] = cnt; __syncthreads();
      for (int s = 128; s > 0; s >>= 1) { if (tid < s) sred[tid] += sred[tid + s]; __syncthreads(); }
      unsigned int tot = sred[0]; __syncthreads();
      if (tot > r) hi = mid; else lo = mid + 1;
    }
    base = sqrtf(__uint_as_float(lo) + 1e-6f);
  }

  // ---- multi-sigma RBF sums: sum_s exp(-d / (2 (base*s)^2)), s in {.5,1,2,4}
  float g2 = base * base;
  float c0 = 1.0f / (2.0f * g2 * 0.25f);
  float c1 = 1.0f / (2.0f * g2 * 1.0f);
  float c2 = 1.0f / (2.0f * g2 * 4.0f);
  float c3 = 1.0f / (2.0f * g2 * 16.0f);
  double accA = 0.0, accB = 0.0, accAB = 0.0;
  for (int i = 0; i < na; ++i) if (tid < na) {
    float d = Da[i * 256 + tid];
    accA += (double)(expf(-d * c0) + expf(-d * c1) + expf(-d * c2) + expf(-d * c3));
  }
  for (int i = 0; i < nb; ++i) if (tid < nb) {
    float d = Db[i * 256 + tid];
    accB += (double)(expf(-d * c0) + expf(-d * c1) + expf(-d * c2) + expf(-d * c3));
  }
  for (int i = 0; i < na; ++i) if (tid < nb) {
    float d = Dab[i * 256 + tid];
    accAB += (double)(expf(-d * c0) + expf(-d * c1) + expf(-d * c2) + expf(-d * c3));
  }
  dred[tid] = accA; __syncthreads();
  for (int s = 128; s > 0; s >>= 1) { if (tid < s) dred[tid] += dred[tid + s]; __syncthreads(); }
  double SA = dred[0]; __syncthreads();
  dred[tid] = accB; __syncthreads();
  for (int s = 128; s > 0; s >>= 1) { if (tid < s) dred[tid] += dred[tid + s]; __syncthreads(); }
  double SB = dred[0]; __syncthreads();
  dred[tid] = accAB; __syncthreads();
  for (int s = 128; s > 0; s >>= 1) { if (tid < s) dred[tid] += dred[tid + s]; __syncthreads(); }
  double SAB = dred[0];
  if (tid == 0) {
    double meanA  = SA  / ((double)na * (double)na);
    double meanB  = SB  / ((double)nb * (double)nb);
    double meanAB = SAB / ((double)na * (double)nb);
    double m = meanA + meanB - 2.0 * meanAB;
    mmd_out[p] = (float)(m > 0.0 ? m : 0.0);
  }
}

// ============================================================================
// K9: final weighted loss
// ============================================================================
__global__ void k_final(const int* __restrict__ meta, const float* __restrict__ mmd,
                        float* out) {
  if (threadIdx.x != 0 || blockIdx.x != 0) return;
  double total = 0.0, vw = 0.0;
  for (int c = 0; c < 5; ++c) {
    int nsf = meta[c], nqf = meta[5 + c];
    if (nsf < 2 || nqf < 2) continue;
    double pos = (double)mmd[c * 5 + c];
    bool any = false; double best = 0.0;
    for (int k = 0; k < 5; ++k) {
      if (k == c || meta[k] < 2) continue;
      double v = (double)mmd[k * 5 + c];
      if (!any || v < best) { best = v; any = true; }
    }
    double lc = any ? fmax(pos - best + 0.1, 0.0) : pos;
    double w = sqrt((double)nsf * (double)nqf);
    total += w * lc; vw += w;
  }
  out[0] = (float)(0.1 * total / fmax(vw, 1e-12));
}

// ============================================================================
// host launcher
// ============================================================================
extern "C" void kernel_launch(void* const* d_in, const int* in_sizes, int n_in,
                              void* d_out, int out_size, void* d_ws, size_t ws_size,
                              hipStream_t stream) {
  const float* f_s = (const float*)d_in[0];
  const int*   l_s = (const int*)d_in[1];
  const float* f_q = (const float*)d_in[2];
  const int*   l_q = (const int*)d_in[3];
  float* out = (float*)d_out;
  char* ws = (char*)d_ws;

  size_t off = 0;
  auto take = [&](size_t bytes) -> void* {
    void* p = ws + off;
    off = (off + bytes + 255) & ~(size_t)255;
    return p;
  };
  int*   meta     = (int*)take(32 * 4);
  int*   sup_list = (int*)take((size_t)5 * S_LEN * 4);
  int*   qry_list = (int*)take((size_t)5 * Q_TOT * 4);
  int*   Jsup     = (int*)take((size_t)5 * S_LEN * 4);   // also k_collect tmpS
  int*   Jqry     = (int*)take((size_t)5 * Q_TOT * 4);   // also k_collect tmpQ
  unsigned int* draws = (unsigned int*)take((10ull * CAPS64 + 10ull * CAPQ64) * 4);
  int*   sel      = (int*)take((size_t)10 * MAXS * 4);
  float* xa       = (float*)take((size_t)5 * 65536 * 4);
  float* xb       = (float*)take((size_t)5 * 65536 * 4);
  float* Ga       = (float*)take((size_t)5 * 65536 * 4);
  float* Gb       = (float*)take((size_t)5 * 65536 * 4);
  float* Gab      = (float*)take((size_t)25 * 65536 * 4);
  float* diagA    = (float*)take((size_t)5 * 256 * 4);
  float* diagB    = (float*)take((size_t)5 * 256 * 4);
  float* mmd      = (float*)take(25 * 4);
  if (off > ws_size) return;

  k_draws<<<10, 256, 0, stream>>>(draws);
  k_collect<<<10, 256, 0, stream>>>(l_s, l_q, meta, sup_list, qry_list, Jsup, Jqry);
  k_consume<<<10, 64, 0, stream>>>(meta, draws, Jsup, Jqry);
  k_prov<<<10, 256, 0, stream>>>(meta, sup_list, qry_list, Jsup, Jqry, sel);
  k_gather<<<80, 256, 0, stream>>>(f_s, f_q, meta, sel, xa, xb);
  k_gram<<<35, 1024, 0, stream>>>(xa, xb, Ga, Gb, Gab);
  k_diag<<<10, 256, 0, stream>>>(Ga, Gb, diagA, diagB);
  k_conv<<<35, 256, 0, stream>>>(Ga, Gb, Gab, diagA, diagB);
  k_medmmd<<<25, 256, 0, stream>>>(meta, Ga, Gb, Gab, mmd);
  k_final<<<1, 64, 0, stream>>>(meta, mmd, out);
}

// Round 5
// 2099.578 us; speedup vs baseline: 6.5231x; 1.6484x over previous
//
#include <hip/hip_runtime.h>

// ============================================================================
// numpy RNG replication: SeedSequence + PCG64 (XSL-RR 128/64), next32 buffering
// ============================================================================
struct U128 { unsigned long long hi, lo; };

__device__ __forceinline__ U128 u128_mul(U128 a, U128 b) {
  U128 r;
  r.lo = a.lo * b.lo;
  r.hi = __umul64hi(a.lo, b.lo) + a.hi * b.lo + a.lo * b.hi;
  return r;
}
__device__ __forceinline__ U128 u128_add(U128 a, U128 b) {
  U128 r; r.lo = a.lo + b.lo; r.hi = a.hi + b.hi + (r.lo < a.lo ? 1ull : 0ull); return r;
}

struct Pcg64 {
  U128 state, inc;
};

__device__ __forceinline__ void pcg_step(Pcg64* r) {
  const U128 M = {0x2360ed051fc65da4ull, 0x4385df649fccf645ull};
  r->state = u128_add(u128_mul(r->state, M), r->inc);
}
__device__ __forceinline__ unsigned long long pcg_next64(Pcg64* r) {
  pcg_step(r);
  unsigned int rot = (unsigned int)(r->state.hi >> 58);   // state >> 122
  unsigned long long x = r->state.hi ^ r->state.lo;       // XSL
  return (x >> rot) | (x << ((64u - rot) & 63u));         // RR
}

// SeedSequence constants (numpy bit_generator.pyx)
__device__ __forceinline__ unsigned int ss_hashmix(unsigned int v, unsigned int* hc) {
  v ^= *hc; *hc = *hc * 0x931e8875u; v *= *hc; v ^= v >> 16; return v;
}
__device__ __forceinline__ unsigned int ss_mix(unsigned int x, unsigned int y) {
  unsigned int r = x * 0xca01f9ddu ^ y * 0x4973f715u; r ^= r >> 16; return r;
}
__device__ void pcg_seed(Pcg64* rng, unsigned int seed) {
  unsigned int pool[4]; unsigned int hc = 0x43b0d7e5u;   // INIT_A
  pool[0] = ss_hashmix(seed, &hc);
  for (int i = 1; i < 4; ++i) pool[i] = ss_hashmix(0u, &hc);
  for (int s = 0; s < 4; ++s)
    for (int d = 0; d < 4; ++d)
      if (s != d) pool[d] = ss_mix(pool[d], ss_hashmix(pool[s], &hc));
  unsigned int hc2 = 0x8b51f9ddu;                        // INIT_B
  unsigned long long w64[4];
  for (int i = 0; i < 4; ++i) {
    unsigned int lo = pool[(2*i) & 3];
    lo ^= hc2; hc2 *= 0x58f38dedu; lo *= hc2; lo ^= lo >> 16;
    unsigned int hi = pool[(2*i+1) & 3];
    hi ^= hc2; hc2 *= 0x58f38dedu; hi *= hc2; hi ^= hi >> 16;
    w64[i] = (unsigned long long)lo | ((unsigned long long)hi << 32);
  }
  U128 initstate = {w64[0], w64[1]};   // PCG_128BIT_CONSTANT(seed[0], seed[1]): [0] is HIGH
  U128 initseq   = {w64[2], w64[3]};
  rng->inc.hi = (initseq.hi << 1) | (initseq.lo >> 63);
  rng->inc.lo = (initseq.lo << 1) | 1ull;
  rng->state.hi = 0; rng->state.lo = 0;
  pcg_step(rng);
  rng->state = u128_add(rng->state, initstate);
  pcg_step(rng);
}

// affine jump-ahead: state <- A^delta * state + (A^delta-1)/(A-1)*inc
__device__ void pcg_advance(Pcg64* r, unsigned long long delta) {
  U128 acc_mult = {0ull, 1ull}, acc_plus = {0ull, 0ull};
  U128 cur_mult = {0x2360ed051fc65da4ull, 0x4385df649fccf645ull};
  U128 cur_plus = r->inc;
  while (delta) {
    if (delta & 1ull) {
      acc_mult = u128_mul(acc_mult, cur_mult);
      acc_plus = u128_add(u128_mul(acc_plus, cur_mult), cur_plus);
    }
    U128 one = {0ull, 1ull};
    U128 cm1 = u128_add(cur_mult, one);
    cur_plus = u128_mul(cm1, cur_plus);
    cur_mult = u128_mul(cur_mult, cur_mult);
    delta >>= 1;
  }
  r->state = u128_add(u128_mul(r->state, acc_mult), acc_plus);
}

// ============================================================================
// Problem constants
// ============================================================================
#define S_LEN   16384
#define Q_LEN   65536
#define Q_TOT   327680     // 5*65536
#define DFEAT   256
#define MAXS    256
#define CAPS64  24576      // next64 outputs per support class (49152 u32 draws)
#define CAPQ64  98304      // next64 outputs per query class  (196608 u32 draws)

// meta layout: [0..4]=ns_full, [5..9]=nq_full, [10..14]=na, [15..19]=nb

// ============================================================================
// K0: parallel draw-stream generation (exact numpy next32 sequence, lo first)
// ============================================================================
__global__ __launch_bounds__(256) void k_draws(unsigned int* __restrict__ draws) {
  int t = blockIdx.x; int cls = t % 5; int isq = t / 5;
  unsigned int seed = (unsigned)(1000 + isq * 1000 + cls + 1);
  unsigned long long cap64 = isq ? CAPQ64 : CAPS64;
  unsigned int* dst = draws + (isq ? (10ull * CAPS64 + (unsigned long long)cls * 2 * CAPQ64)
                                   : ((unsigned long long)cls * 2 * CAPS64));
  Pcg64 rng; pcg_seed(&rng, seed);
  int tid = threadIdx.x;
  unsigned long long C = cap64 / 256ull;     // 96 or 384
  unsigned long long k0 = (unsigned long long)tid * C;
  pcg_advance(&rng, k0);
  uint2* d2 = (uint2*)dst;
  for (unsigned long long m = 0; m < C; ++m) {
    unsigned long long o = pcg_next64(&rng);
    d2[k0 + m] = make_uint2((unsigned int)o, (unsigned int)(o >> 32));
  }
}

// ============================================================================
// K1: collect class index lists (reference order), 4-wave quarter compaction
// ============================================================================
__global__ __launch_bounds__(256) void k_collect(const int* __restrict__ ls,
                                                 const int* __restrict__ lq,
                                                 int* meta, int* sup_list, int* qry_list,
                                                 int* tmpS, int* tmpQ) {
  int t = blockIdx.x;
  int cls = t % 5; int isq = t / 5;
  const int* src; int n_src, matchval; int* out; int* tmp;
  if (!isq) { src = ls + cls * S_LEN; n_src = S_LEN; matchval = 1;
              out = sup_list + cls * S_LEN; tmp = tmpS + cls * S_LEN; }
  else      { src = lq; n_src = Q_TOT; matchval = cls + 1;
              out = qry_list + (size_t)cls * Q_TOT; tmp = tmpQ + (size_t)cls * Q_TOT; }
  int tid = threadIdx.x;
  int w = tid >> 6; int lane = tid & 63;
  int qlen = n_src >> 2;                 // 4096 or 81920, multiple of 64
  int beg = w * qlen;
  __shared__ int cnt[4];
  int base = 0;
  unsigned long long lmask = (1ull << lane) - 1ull;
  for (int i0 = beg; i0 < beg + qlen; i0 += 64) {
    int i = i0 + lane;
    bool p = (src[i] == matchval);
    unsigned long long m = __ballot(p);
    if (p) tmp[beg + base + __popcll(m & lmask)] = i;
    base += __popcll(m);
  }
  if (lane == 0) cnt[w] = base;
  __syncthreads();
  int c0 = cnt[0], c1 = cnt[1], c2 = cnt[2], c3 = cnt[3];
  int offs[4] = {0, c0, c0 + c1, c0 + c1 + c2};
  int ntot = c0 + c1 + c2 + c3;
  for (int ww = 0; ww < 4; ++ww) {
    int cw = cnt[ww];
    for (int idx = tid; idx < cw; idx += 256)
      out[offs[ww] + idx] = tmp[ww * qlen + idx];
  }
  if (tid == 0) {
    meta[isq * 5 + cls] = ntot;
    meta[10 + isq * 5 + cls] = ntot < MAXS ? ntot : MAXS;
  }
}

// ============================================================================
// K2: wave-parallel masked-rejection automaton, INTERVAL-COMMIT resolution.
// ============================================================================
__global__ __launch_bounds__(64) void k_consume(const int* __restrict__ meta,
                                                const unsigned int* __restrict__ draws,
                                                int* Jsup, int* Jqry) {
  int t = blockIdx.x; int cls = t % 5; int isq = t / 5;
  int n = meta[isq * 5 + cls];
  if (n <= MAXS) return;
  const unsigned int* d = draws + (isq ? (10ull * CAPS64 + (unsigned long long)cls * 2 * CAPQ64)
                                       : ((unsigned long long)cls * 2 * CAPS64));
  int* J = isq ? (Jqry + (size_t)cls * Q_TOT) : (Jsup + cls * S_LEN);
  int lane = threadIdx.x;
  unsigned long long lmask = (1ull << lane) - 1ull;
  unsigned long long lbit  = (1ull << lane);
  int i = n - 1;
  size_t p = 0;
  unsigned int v = d[lane];
  for (;;) {
    unsigned int vnext = d[p + 64 + lane];     // prefetch next chunk
    unsigned long long rej = 0ull, acc = 0ull;
    for (int it = 0; it < 72; ++it) {
      unsigned long long unc = ~(rej | acc);
      if (!unc) break;
      int rbelow = __popcll(rej & lmask);
      int ubelow = __popcll(unc & lmask);
      int il_min = i - lane + rbelow;          // >= 193 always
      int il_max = il_min + ubelow;
      bool def_rej = false, def_acc = false;
      if (unc & lbit) {
        unsigned int mlo = 0xFFFFFFFFu >> __clz(il_min);
        unsigned int mhi = 0xFFFFFFFFu >> __clz(il_max);
        if (mlo == mhi) {
          unsigned int w = v & mlo;
          def_rej = (w > (unsigned int)il_max);
          def_acc = (w <= (unsigned int)il_min);
        } else if (ubelow == 0) {              // octave boundary: exact resolve
          unsigned int w = v & mlo;
          def_rej = (w > (unsigned int)il_min);
          def_acc = !def_rej;
        }
      }
      unsigned long long nr = __ballot(def_rej);
      unsigned long long nc = __ballot(def_acc);
      rej |= nr; acc |= nc;
    }
    int rbelow = __popcll(rej & lmask);
    int il = i - lane + rbelow;
    int totAcc = 64 - __popcll(rej);
    if ((acc & lbit) && il >= MAXS)
      J[il] = (int)(v & (0xFFFFFFFFu >> __clz(il)));
    int needed = i - (MAXS - 1);
    if (totAcc >= needed) break;
    i -= totAcc; p += 64; v = vnext;
  }
}

// ============================================================================
// K3a: next-hitter index fill.  H[v] = min{ i > v, i in [256,n) : J[i] == v }
//      (self-swaps J[i]==i excluded; H pre-initialized to 0xFFFFFFFF).
//      Replaces the 54k-step serial provenance walk: final content of window
//      slot s is chase(H[s]) where chase follows H until INF (strictly
//      ascending -> terminates; expected length ~2).
// ============================================================================
__global__ __launch_bounds__(256) void k_hfill(const int* __restrict__ meta,
                                               const int* __restrict__ Jsup,
                                               const int* __restrict__ Jqry,
                                               unsigned int* __restrict__ Hsup,
                                               unsigned int* __restrict__ Hqry) {
  // grid: 5 * (S_LEN/256) blocks for support, then 5 * (Q_TOT/256) for query
  const int SB = 5 * (S_LEN / 256);
  int b = blockIdx.x;
  int cls, i; const int* J; unsigned int* H; int n;
  if (b < SB) {
    cls = b / (S_LEN / 256);
    i = (b % (S_LEN / 256)) * 256 + threadIdx.x;
    n = meta[cls];
    J = Jsup + cls * S_LEN; H = Hsup + cls * S_LEN;
  } else {
    b -= SB;
    cls = b / (Q_TOT / 256);
    i = (b % (Q_TOT / 256)) * 256 + threadIdx.x;
    n = meta[5 + cls];
    J = Jqry + (size_t)cls * Q_TOT; H = Hqry + (size_t)cls * Q_TOT;
  }
  if (i < MAXS || i >= n) return;
  int j = J[i];
  if (j != i) atomicMin(&H[j], (unsigned int)i);
}

// ============================================================================
// K3b: chase.  sel[t][s] = list[ c(s) ];  c: s -> (H[s]==INF ? s : ascend)
// ============================================================================
__global__ __launch_bounds__(256) void k_chase(const int* __restrict__ meta,
                                               const int* __restrict__ sup_list,
                                               const int* __restrict__ qry_list,
                                               const unsigned int* __restrict__ Hsup,
                                               const unsigned int* __restrict__ Hqry,
                                               int* sel) {
  int t = blockIdx.x; int tid = threadIdx.x;
  int cls = t % 5; int isq = t / 5;
  int n = meta[isq * 5 + cls];
  const int* list; const unsigned int* H;
  if (!isq) { list = sup_list + cls * S_LEN; H = Hsup + cls * S_LEN; }
  else      { list = qry_list + (size_t)cls * Q_TOT; H = Hqry + (size_t)cls * Q_TOT; }
  int* s = sel + t * MAXS;
  if (n <= MAXS) { if (tid < n) s[tid] = list[tid]; return; }
  unsigned int v = (unsigned int)tid;
  unsigned int h = H[v];
  while (h != 0xFFFFFFFFu) { v = h; h = H[v]; }
  s[tid] = list[v];
}

// ============================================================================
// K4: gather selected feature rows + fused row-norm (x / (||x|| + 1e-12)).
// ============================================================================
__global__ __launch_bounds__(256) void k_gather(const float* __restrict__ f_s,
                                                const float* __restrict__ f_q,
                                                const int* __restrict__ meta,
                                                const int* __restrict__ sel,
                                                float* xa, float* xb) {
  int blk = blockIdx.x;
  int t = blk >> 3;          // class-pair 0..9
  int slab = blk & 7;        // 8 slabs x 32 rows
  int cls = t % 5; int isq = t / 5;
  int n = meta[10 + isq * 5 + cls];
  int tid = threadIdx.x;
  int row = slab * 32 + (tid >> 3);
  int dg = tid & 7;          // 8 d-groups of 32
  if (row >= n) return;      // group-uniform (8 lanes share row)
  int id = sel[t * MAXS + row];
  const float* src; size_t stride; float* dst;
  if (!isq) {
    src = f_s + (size_t)cls * DFEAT * S_LEN + id; stride = S_LEN;
    dst = xa + cls * (MAXS * DFEAT) + row * DFEAT;
  } else {
    int m = id >> 16; int nn = id & 0xFFFF;
    src = f_q + (size_t)m * DFEAT * Q_LEN + nn; stride = Q_LEN;
    dst = xb + cls * (MAXS * DFEAT) + row * DFEAT;
  }
  float v[32];
  #pragma unroll
  for (int dd = 0; dd < 32; ++dd)
    v[dd] = src[(size_t)(dg * 32 + dd) * stride];
  float ss = 0.f;
  #pragma unroll
  for (int dd = 0; dd < 32; ++dd) ss += v[dd] * v[dd];
  ss += __shfl_xor(ss, 1);
  ss += __shfl_xor(ss, 2);
  ss += __shfl_xor(ss, 4);
  float inv = 1.0f / (sqrtf(ss) + 1e-12f);
  #pragma unroll
  for (int dd = 0; dd < 32; ++dd) dst[dg * 32 + dd] = v[dd] * inv;
}

// ============================================================================
// K5: 35 Gram matrices (256x256, K=256)
// ============================================================================
__global__ __launch_bounds__(1024) void k_gram(const float* __restrict__ xa,
                                               const float* __restrict__ xb,
                                               float* Ga, float* Gb, float* Gab) {
  int j = blockIdx.x;
  const float *A, *B; float* G;
  if (j < 5)       { A = xa + j * 65536; B = A; G = Ga + j * 65536; }
  else if (j < 10) { int c = j - 5; A = xb + c * 65536; B = A; G = Gb + c * 65536; }
  else             { int p = j - 10; int k = p / 5, c = p % 5;
                     A = xa + k * 65536; B = xb + c * 65536; G = Gab + p * 65536; }
  __shared__ float As[256][17];
  __shared__ float Bs[256][17];
  int tid = threadIdx.x;
  int ti = tid >> 5, tj = tid & 31;
  float acc[8][8];
  #pragma unroll
  for (int r = 0; r < 8; ++r)
    #pragma unroll
    for (int s = 0; s < 8; ++s) acc[r][s] = 0.f;
  for (int k0 = 0; k0 < 256; k0 += 16) {
    #pragma unroll
    for (int e = 0; e < 4; ++e) {
      int idx = tid + e * 1024;
      int i = idx >> 4, kk = idx & 15;
      As[i][kk] = A[i * 256 + k0 + kk];
      Bs[i][kk] = B[i * 256 + k0 + kk];
    }
    __syncthreads();
    #pragma unroll
    for (int kk = 0; kk < 16; ++kk) {
      float a[8], b[8];
      #pragma unroll
      for (int r = 0; r < 8; ++r) a[r] = As[ti * 8 + r][kk];
      #pragma unroll
      for (int s = 0; s < 8; ++s) b[s] = Bs[tj * 8 + s][kk];
      #pragma unroll
      for (int r = 0; r < 8; ++r)
        #pragma unroll
        for (int s = 0; s < 8; ++s) acc[r][s] += a[r] * b[s];
    }
    __syncthreads();
  }
  #pragma unroll
  for (int r = 0; r < 8; ++r)
    #pragma unroll
    for (int s = 0; s < 8; ++s)
      G[(ti * 8 + r) * 256 + tj * 8 + s] = acc[r][s];
}

// ============================================================================
// K6: extract Gram diagonals
// ============================================================================
__global__ __launch_bounds__(256) void k_diag(const float* __restrict__ Ga,
                                              const float* __restrict__ Gb,
                                              float* diagA, float* diagB) {
  int t = blockIdx.x; int i = threadIdx.x;
  if (t < 5) diagA[t * 256 + i] = Ga[t * 65536 + i * 257];
  else { int c = t - 5; diagB[c * 256 + i] = Gb[c * 65536 + i * 257]; }
}

// ============================================================================
// K7: G -> D in place: D_ij = max(dA_i + dB_j - 2 g_ij, 0)
// ============================================================================
__global__ __launch_bounds__(256) void k_conv(float* Ga, float* Gb, float* Gab,
                                              const float* __restrict__ diagA,
                                              const float* __restrict__ diagB) {
  int j = blockIdx.x; int tid = threadIdx.x;
  float* G; const float *dA, *dB;
  if (j < 5)       { G = Ga + j * 65536; dA = diagA + j * 256; dB = dA; }
  else if (j < 10) { int c = j - 5; G = Gb + c * 65536; dA = diagB + c * 256; dB = dA; }
  else             { int p = j - 10; int k = p / 5, c = p % 5;
                     G = Gab + p * 65536; dA = diagA + k * 256; dB = diagB + c * 256; }
  float db = dB[tid];
  for (int i = 0; i < 256; ++i) {
    float g = G[i * 256 + tid];
    float d = dA[i] + db - 2.0f * g;
    G[i * 256 + tid] = d > 0.f ? d : 0.f;
  }
}

// ============================================================================
// K8: per (k,c): exact median via bisection on float bits -> sigma -> MMD^2
// ============================================================================
__global__ __launch_bounds__(256) void k_medmmd(const int* __restrict__ meta,
                                                const float* __restrict__ Da_all,
                                                const float* __restrict__ Db_all,
                                                const float* __restrict__ Dab_all,
                                                float* mmd_out) {
  int p = blockIdx.x; int kcl = p / 5, ccl = p % 5;
  int tid = threadIdx.x;
  int nsf = meta[kcl], nqf = meta[5 + ccl];
  if (nsf < 2 || nqf < 2) { if (tid == 0) mmd_out[p] = 0.0f; return; }
  int na = meta[10 + kcl], nb = meta[15 + ccl];
  const float* Da  = Da_all  + kcl * 65536;
  const float* Db  = Db_all  + ccl * 65536;
  const float* Dab = Dab_all + p * 65536;

  __shared__ unsigned int sred[256];
  __shared__ double dred[256];

  unsigned int N = (unsigned int)(na + nb) * (unsigned int)(na + nb);
  bool fast = (na == 256) && (nb == 256);

  // ---- exact-zero count (Dab double) ----
  unsigned int zc = 0;
  if (fast) {
    const float4* A4 = (const float4*)Da;
    const float4* B4 = (const float4*)Db;
    const float4* C4 = (const float4*)Dab;
    for (int k = 0; k < 64; ++k) {
      float4 a = A4[tid + k * 256];
      zc += (a.x == 0.f ? 1u : 0u) + (a.y == 0.f ? 1u : 0u)
          + (a.z == 0.f ? 1u : 0u) + (a.w == 0.f ? 1u : 0u);
    }
    for (int k = 0; k < 64; ++k) {
      float4 b = B4[tid + k * 256];
      zc += (b.x == 0.f ? 1u : 0u) + (b.y == 0.f ? 1u : 0u)
          + (b.z == 0.f ? 1u : 0u) + (b.w == 0.f ? 1u : 0u);
    }
    for (int k = 0; k < 64; ++k) {
      float4 c = C4[tid + k * 256];
      zc += 2u * ((c.x == 0.f ? 1u : 0u) + (c.y == 0.f ? 1u : 0u)
                + (c.z == 0.f ? 1u : 0u) + (c.w == 0.f ? 1u : 0u));
    }
  } else {
    if (tid < na) for (int i = 0; i < na; ++i) zc += (Da[i * 256 + tid] == 0.f) ? 1u : 0u;
    if (tid < nb) for (int i = 0; i < nb; ++i) zc += (Db[i * 256 + tid] == 0.f) ? 1u : 0u;
    if (tid < nb) for (int i = 0; i < na; ++i) zc += (Dab[i * 256 + tid] == 0.f) ? 2u : 0u;
  }
  sred[tid] = zc; __syncthreads();
  for (int s = 128; s > 0; s >>= 1) { if (tid < s) sred[tid] += sred[tid + s]; __syncthreads(); }
  unsigned int nz = sred[0]; __syncthreads();

  float base;
  if (nz >= N) {
    base = 1.0f;
  } else {
    unsigned int r = nz + (N - nz - 1u) / 2u;   // 0-based target rank
    unsigned int lo = 0u, hi = 0x41000000u;     // keys in [0, 8.0)
    while (lo < hi) {
      unsigned int mid = (lo + hi) >> 1;
      float piv = __uint_as_float(mid);
      unsigned int cnt = 0;
      if (fast) {
        const float4* A4 = (const float4*)Da;
        const float4* B4 = (const float4*)Db;
        const float4* C4 = (const float4*)Dab;
        for (int k = 0; k < 64; ++k) {
          float4 a = A4[tid + k * 256];
          cnt += (a.x <= piv ? 1u : 0u) + (a.y <= piv ? 1u : 0u)
               + (a.z <= piv ? 1u : 0u) + (a.w <= piv ? 1u : 0u);
        }
        for (int k = 0; k < 64; ++k) {
          float4 b = B4[tid + k * 256];
          cnt += (b.x <= piv ? 1u : 0u) + (b.y <= piv ? 1u : 0u)
               + (b.z <= piv ? 1u : 0u) + (b.w <= piv ? 1u : 0u);
        }
        for (int k = 0; k < 64; ++k) {
          float4 c = C4[tid + k * 256];
          cnt += 2u * ((c.x <= piv ? 1u : 0u) + (c.y <= piv ? 1u : 0u)
                     + (c.z <= piv ? 1u : 0u) + (c.w <= piv ? 1u : 0u));
        }
      } else {
        if (tid < na) for (int i = 0; i < na; ++i) cnt += (Da[i * 256 + tid] <= piv) ? 1u : 0u;
        if (tid < nb) for (int i = 0; i < nb; ++i) cnt += (Db[i * 256 + tid] <= piv) ? 1u : 0u;
        if (tid < nb) for (int i = 0; i < na; ++i) cnt += (Dab[i * 256 + tid] <= piv) ? 2u : 0u;
      }
      sred[tid] = cnt; __syncthreads();
      for (int s = 128; s > 0; s >>= 1) { if (tid < s) sred[tid] += sred[tid + s]; __syncthreads(); }
      unsigned int tot = sred[0]; __syncthreads();
      if (tot > r) hi = mid; else lo = mid + 1;
    }
    base = sqrtf(__uint_as_float(lo) + 1e-6f);
  }

  // ---- multi-sigma RBF sums: sum_s exp(-d / (2 (base*s)^2)), s in {.5,1,2,4}
  float g2 = base * base;
  float c0 = 1.0f / (2.0f * g2 * 0.25f);
  float c1 = 1.0f / (2.0f * g2 * 1.0f);
  float c2 = 1.0f / (2.0f * g2 * 4.0f);
  float c3 = 1.0f / (2.0f * g2 * 16.0f);
  double accA = 0.0, accB = 0.0, accAB = 0.0;
  for (int i = 0; i < na; ++i) if (tid < na) {
    float d = Da[i * 256 + tid];
    accA += (double)(expf(-d * c0) + expf(-d * c1) + expf(-d * c2) + expf(-d * c3));
  }
  for (int i = 0; i < nb; ++i) if (tid < nb) {
    float d = Db[i * 256 + tid];
    accB += (double)(expf(-d * c0) + expf(-d * c1) + expf(-d * c2) + expf(-d * c3));
  }
  for (int i = 0; i < na; ++i) if (tid < nb) {
    float d = Dab[i * 256 + tid];
    accAB += (double)(expf(-d * c0) + expf(-d * c1) + expf(-d * c2) + expf(-d * c3));
  }
  dred[tid] = accA; __syncthreads();
  for (int s = 128; s > 0; s >>= 1) { if (tid < s) dred[tid] += dred[tid + s]; __syncthreads(); }
  double SA = dred[0]; __syncthreads();
  dred[tid] = accB; __syncthreads();
  for (int s = 128; s > 0; s >>= 1) { if (tid < s) dred[tid] += dred[tid + s]; __syncthreads(); }
  double SB = dred[0]; __syncthreads();
  dred[tid] = accAB; __syncthreads();
  for (int s = 128; s > 0; s >>= 1) { if (tid < s) dred[tid] += dred[tid + s]; __syncthreads(); }
  double SAB = dred[0];
  if (tid == 0) {
    double meanA  = SA  / ((double)na * (double)na);
    double meanB  = SB  / ((double)nb * (double)nb);
    double meanAB = SAB / ((double)na * (double)nb);
    double m = meanA + meanB - 2.0 * meanAB;
    mmd_out[p] = (float)(m > 0.0 ? m : 0.0);
  }
}

// ============================================================================
// K9: final weighted loss
// ============================================================================
__global__ void k_final(const int* __restrict__ meta, const float* __restrict__ mmd,
                        float* out) {
  if (threadIdx.x != 0 || blockIdx.x != 0) return;
  double total = 0.0, vw = 0.0;
  for (int c = 0; c < 5; ++c) {
    int nsf = meta[c], nqf = meta[5 + c];
    if (nsf < 2 || nqf < 2) continue;
    double pos = (double)mmd[c * 5 + c];
    bool any = false; double best = 0.0;
    for (int k = 0; k < 5; ++k) {
      if (k == c || meta[k] < 2) continue;
      double v = (double)mmd[k * 5 + c];
      if (!any || v < best) { best = v; any = true; }
    }
    double lc = any ? fmax(pos - best + 0.1, 0.0) : pos;
    double w = sqrt((double)nsf * (double)nqf);
    total += w * lc; vw += w;
  }
  out[0] = (float)(0.1 * total / fmax(vw, 1e-12));
}

// ============================================================================
// host launcher
// ============================================================================
extern "C" void kernel_launch(void* const* d_in, const int* in_sizes, int n_in,
                              void* d_out, int out_size, void* d_ws, size_t ws_size,
                              hipStream_t stream) {
  const float* f_s = (const float*)d_in[0];
  const int*   l_s = (const int*)d_in[1];
  const float* f_q = (const float*)d_in[2];
  const int*   l_q = (const int*)d_in[3];
  float* out = (float*)d_out;
  char* ws = (char*)d_ws;

  size_t off = 0;
  auto take = [&](size_t bytes) -> void* {
    void* p = ws + off;
    off = (off + bytes + 255) & ~(size_t)255;
    return p;
  };
  int*   meta     = (int*)take(32 * 4);
  int*   sup_list = (int*)take((size_t)5 * S_LEN * 4);
  int*   qry_list = (int*)take((size_t)5 * Q_TOT * 4);
  int*   Jsup     = (int*)take((size_t)5 * S_LEN * 4);   // also k_collect tmpS
  int*   Jqry     = (int*)take((size_t)5 * Q_TOT * 4);   // also k_collect tmpQ
  unsigned int* draws = (unsigned int*)take((10ull * CAPS64 + 10ull * CAPQ64) * 4);
  int*   sel      = (int*)take((size_t)10 * MAXS * 4);
  float* xa       = (float*)take((size_t)5 * 65536 * 4);
  float* xb       = (float*)take((size_t)5 * 65536 * 4);
  float* Ga       = (float*)take((size_t)5 * 65536 * 4);
  float* Gb       = (float*)take((size_t)5 * 65536 * 4);
  float* Gab      = (float*)take((size_t)25 * 65536 * 4);
  float* diagA    = (float*)take((size_t)5 * 256 * 4);
  float* diagB    = (float*)take((size_t)5 * 256 * 4);
  float* mmd      = (float*)take(25 * 4);
  if (off > ws_size) return;

  // H (next-hitter) arrays alias the draws buffer — draws dead after k_consume.
  // Hsup: 5*S_LEN u32, Hqry: 5*Q_TOT u32 -> 6.88 MB <= draws' 9.83 MB.
  unsigned int* Hsup = draws;
  unsigned int* Hqry = draws + (size_t)5 * S_LEN;
  size_t hbytes = ((size_t)5 * S_LEN + (size_t)5 * Q_TOT) * 4;

  k_draws<<<10, 256, 0, stream>>>(draws);
  k_collect<<<10, 256, 0, stream>>>(l_s, l_q, meta, sup_list, qry_list, Jsup, Jqry);
  k_consume<<<10, 64, 0, stream>>>(meta, draws, Jsup, Jqry);
  hipMemsetAsync(Hsup, 0xFF, hbytes, stream);
  {
    int nblk = 5 * (S_LEN / 256) + 5 * (Q_TOT / 256);   // 320 + 6400
    k_hfill<<<nblk, 256, 0, stream>>>(meta, Jsup, Jqry, Hsup, Hqry);
  }
  k_chase<<<10, 256, 0, stream>>>(meta, sup_list, qry_list, Hsup, Hqry, sel);
  k_gather<<<80, 256, 0, stream>>>(f_s, f_q, meta, sel, xa, xb);
  k_gram<<<35, 1024, 0, stream>>>(xa, xb, Ga, Gb, Gab);
  k_diag<<<10, 256, 0, stream>>>(Ga, Gb, diagA, diagB);
  k_conv<<<35, 256, 0, stream>>>(Ga, Gb, Gab, diagA, diagB);
  k_medmmd<<<25, 256, 0, stream>>>(meta, Ga, Gb, Gab, mmd);
  k_final<<<1, 64, 0, stream>>>(meta, mmd, out);
}

// Round 6
// 1690.077 us; speedup vs baseline: 8.1036x; 1.2423x over previous
//
#include <hip/hip_runtime.h>

// ============================================================================
// numpy RNG replication: SeedSequence + PCG64 (XSL-RR 128/64), next32 buffering
// ============================================================================
struct U128 { unsigned long long hi, lo; };

__device__ __forceinline__ U128 u128_mul(U128 a, U128 b) {
  U128 r;
  r.lo = a.lo * b.lo;
  r.hi = __umul64hi(a.lo, b.lo) + a.hi * b.lo + a.lo * b.hi;
  return r;
}
__device__ __forceinline__ U128 u128_add(U128 a, U128 b) {
  U128 r; r.lo = a.lo + b.lo; r.hi = a.hi + b.hi + (r.lo < a.lo ? 1ull : 0ull); return r;
}

struct Pcg64 {
  U128 state, inc;
};

__device__ __forceinline__ void pcg_step(Pcg64* r) {
  const U128 M = {0x2360ed051fc65da4ull, 0x4385df649fccf645ull};
  r->state = u128_add(u128_mul(r->state, M), r->inc);
}
__device__ __forceinline__ unsigned long long pcg_next64(Pcg64* r) {
  pcg_step(r);
  unsigned int rot = (unsigned int)(r->state.hi >> 58);   // state >> 122
  unsigned long long x = r->state.hi ^ r->state.lo;       // XSL
  return (x >> rot) | (x << ((64u - rot) & 63u));         // RR
}

// SeedSequence constants (numpy bit_generator.pyx)
__device__ __forceinline__ unsigned int ss_hashmix(unsigned int v, unsigned int* hc) {
  v ^= *hc; *hc = *hc * 0x931e8875u; v *= *hc; v ^= v >> 16; return v;
}
__device__ __forceinline__ unsigned int ss_mix(unsigned int x, unsigned int y) {
  unsigned int r = x * 0xca01f9ddu ^ y * 0x4973f715u; r ^= r >> 16; return r;
}
__device__ void pcg_seed(Pcg64* rng, unsigned int seed) {
  unsigned int pool[4]; unsigned int hc = 0x43b0d7e5u;   // INIT_A
  pool[0] = ss_hashmix(seed, &hc);
  for (int i = 1; i < 4; ++i) pool[i] = ss_hashmix(0u, &hc);
  for (int s = 0; s < 4; ++s)
    for (int d = 0; d < 4; ++d)
      if (s != d) pool[d] = ss_mix(pool[d], ss_hashmix(pool[s], &hc));
  unsigned int hc2 = 0x8b51f9ddu;                        // INIT_B
  unsigned long long w64[4];
  for (int i = 0; i < 4; ++i) {
    unsigned int lo = pool[(2*i) & 3];
    lo ^= hc2; hc2 *= 0x58f38dedu; lo *= hc2; lo ^= lo >> 16;
    unsigned int hi = pool[(2*i+1) & 3];
    hi ^= hc2; hc2 *= 0x58f38dedu; hi *= hc2; hi ^= hi >> 16;
    w64[i] = (unsigned long long)lo | ((unsigned long long)hi << 32);
  }
  U128 initstate = {w64[0], w64[1]};   // PCG_128BIT_CONSTANT(seed[0], seed[1]): [0] is HIGH
  U128 initseq   = {w64[2], w64[3]};
  rng->inc.hi = (initseq.hi << 1) | (initseq.lo >> 63);
  rng->inc.lo = (initseq.lo << 1) | 1ull;
  rng->state.hi = 0; rng->state.lo = 0;
  pcg_step(rng);
  rng->state = u128_add(rng->state, initstate);
  pcg_step(rng);
}

// affine jump-ahead: state <- A^delta * state + (A^delta-1)/(A-1)*inc
__device__ void pcg_advance(Pcg64* r, unsigned long long delta) {
  U128 acc_mult = {0ull, 1ull}, acc_plus = {0ull, 0ull};
  U128 cur_mult = {0x2360ed051fc65da4ull, 0x4385df649fccf645ull};
  U128 cur_plus = r->inc;
  while (delta) {
    if (delta & 1ull) {
      acc_mult = u128_mul(acc_mult, cur_mult);
      acc_plus = u128_add(u128_mul(acc_plus, cur_mult), cur_plus);
    }
    U128 one = {0ull, 1ull};
    U128 cm1 = u128_add(cur_mult, one);
    cur_plus = u128_mul(cm1, cur_plus);
    cur_mult = u128_mul(cur_mult, cur_mult);
    delta >>= 1;
  }
  r->state = u128_add(u128_mul(r->state, acc_mult), acc_plus);
}

// ============================================================================
// Problem constants
// ============================================================================
#define S_LEN   16384
#define Q_LEN   65536
#define Q_TOT   327680     // 5*65536
#define DFEAT   256
#define MAXS    256
#define CAPS64  24576      // next64 outputs per support class (49152 u32 draws)
#define CAPQ64  98304      // next64 outputs per query class  (196608 u32 draws)
#define TILE    4096
#define STILES  (S_LEN / TILE)    // 4
#define QTILES  (Q_TOT / TILE)    // 80
#define NBLK_C  (5 * STILES + 5 * QTILES)   // 420

// meta layout: [0..4]=ns_full, [5..9]=nq_full, [10..14]=na, [15..19]=nb

// ============================================================================
// K0: parallel draw-stream generation (exact numpy next32 sequence, lo first)
// ============================================================================
__global__ __launch_bounds__(256) void k_draws(unsigned int* __restrict__ draws) {
  int t = blockIdx.x; int cls = t % 5; int isq = t / 5;
  unsigned int seed = (unsigned)(1000 + isq * 1000 + cls + 1);
  unsigned long long cap64 = isq ? CAPQ64 : CAPS64;
  unsigned int* dst = draws + (isq ? (10ull * CAPS64 + (unsigned long long)cls * 2 * CAPQ64)
                                   : ((unsigned long long)cls * 2 * CAPS64));
  Pcg64 rng; pcg_seed(&rng, seed);
  int tid = threadIdx.x;
  unsigned long long C = cap64 / 256ull;     // 96 or 384
  unsigned long long k0 = (unsigned long long)tid * C;
  pcg_advance(&rng, k0);
  uint2* d2 = (uint2*)dst;
  for (unsigned long long m = 0; m < C; ++m) {
    unsigned long long o = pcg_next64(&rng);
    d2[k0 + m] = make_uint2((unsigned int)o, (unsigned int)(o >> 32));
  }
}

// ============================================================================
// K1a: per-tile match counts.  Block b: support b<20 -> (cls=b/4, tile=b%4);
//      else query (cls=(b-20)/80, tile=(b-20)%80).
// ============================================================================
__global__ __launch_bounds__(256) void k_count(const int* __restrict__ ls,
                                               const int* __restrict__ lq,
                                               int* __restrict__ cnts) {
  int b = blockIdx.x;
  const int* src; int matchval;
  if (b < 5 * STILES) {
    int cls = b / STILES, tl = b % STILES;
    src = ls + cls * S_LEN + tl * TILE; matchval = 1;
  } else {
    int bb = b - 5 * STILES; int cls = bb / QTILES, tl = bb % QTILES;
    src = lq + tl * TILE; matchval = cls + 1;
  }
  int tid = threadIdx.x;
  int cnt = 0;
  for (int k = 0; k < TILE; k += 256) cnt += (src[k + tid] == matchval) ? 1 : 0;
  __shared__ int red[256];
  red[tid] = cnt; __syncthreads();
  for (int s = 128; s > 0; s >>= 1) { if (tid < s) red[tid] += red[tid + s]; __syncthreads(); }
  if (tid == 0) cnts[b] = red[0];
}

// ============================================================================
// K1b: tiny scan: exclusive offsets per class + meta totals
// ============================================================================
__global__ void k_scan(const int* __restrict__ cnts, int* __restrict__ offs,
                       int* __restrict__ meta) {
  int t = threadIdx.x;
  if (t < 5) {
    int base = 0;
    for (int k = 0; k < STILES; ++k) {
      offs[t * STILES + k] = base; base += cnts[t * STILES + k];
    }
    meta[t] = base;
    meta[10 + t] = base < MAXS ? base : MAXS;
  } else if (t < 10) {
    int c = t - 5; int base = 0;
    for (int k = 0; k < QTILES; ++k) {
      int idx = 5 * STILES + c * QTILES + k;
      offs[idx] = base; base += cnts[idx];
    }
    meta[5 + c] = base;
    meta[15 + c] = base < MAXS ? base : MAXS;
  }
}

// ============================================================================
// K1c: stable compaction write at per-tile offsets (4-wave ballot prefix)
// ============================================================================
__global__ __launch_bounds__(256) void k_write(const int* __restrict__ ls,
                                               const int* __restrict__ lq,
                                               const int* __restrict__ offs,
                                               int* __restrict__ sup_list,
                                               int* __restrict__ qry_list) {
  int b = blockIdx.x;
  const int* src; int matchval; int* out; int ibase;
  if (b < 5 * STILES) {
    int cls = b / STILES, tl = b % STILES;
    src = ls + cls * S_LEN + tl * TILE; matchval = 1;
    out = sup_list + cls * S_LEN; ibase = tl * TILE;
  } else {
    int bb = b - 5 * STILES; int cls = bb / QTILES, tl = bb % QTILES;
    src = lq + tl * TILE; matchval = cls + 1;
    out = qry_list + (size_t)cls * Q_TOT; ibase = tl * TILE;
  }
  int tid = threadIdx.x; int w = tid >> 6, lane = tid & 63;
  unsigned long long lmask = (1ull << lane) - 1ull;
  __shared__ int wcnt[4];
  int base = offs[b];
  for (int k = 0; k < TILE; k += 256) {
    int i = k + tid;
    bool p = (src[i] == matchval);
    unsigned long long m = __ballot(p);
    if (lane == 0) wcnt[w] = __popcll(m);
    __syncthreads();
    int prev = 0;
    #pragma unroll
    for (int ww = 0; ww < 4; ++ww) prev += (ww < w) ? wcnt[ww] : 0;
    int tot = wcnt[0] + wcnt[1] + wcnt[2] + wcnt[3];
    if (p) out[base + prev + __popcll(m & lmask)] = ibase + i;
    __syncthreads();
    base += tot;
  }
}

// ============================================================================
// K2: wave-parallel masked-rejection automaton, INTERVAL-COMMIT resolution.
// ============================================================================
__global__ __launch_bounds__(64) void k_consume(const int* __restrict__ meta,
                                                const unsigned int* __restrict__ draws,
                                                int* Jsup, int* Jqry) {
  int t = blockIdx.x; int cls = t % 5; int isq = t / 5;
  int n = meta[isq * 5 + cls];
  if (n <= MAXS) return;
  const unsigned int* d = draws + (isq ? (10ull * CAPS64 + (unsigned long long)cls * 2 * CAPQ64)
                                       : ((unsigned long long)cls * 2 * CAPS64));
  int* J = isq ? (Jqry + (size_t)cls * Q_TOT) : (Jsup + cls * S_LEN);
  int lane = threadIdx.x;
  unsigned long long lmask = (1ull << lane) - 1ull;
  unsigned long long lbit  = (1ull << lane);
  int i = n - 1;
  size_t p = 0;
  unsigned int v = d[lane];
  for (;;) {
    unsigned int vnext = d[p + 64 + lane];     // prefetch next chunk
    unsigned long long rej = 0ull, acc = 0ull;
    for (int it = 0; it < 72; ++it) {
      unsigned long long unc = ~(rej | acc);
      if (!unc) break;
      int rbelow = __popcll(rej & lmask);
      int ubelow = __popcll(unc & lmask);
      int il_min = i - lane + rbelow;          // >= 193 always
      int il_max = il_min + ubelow;
      bool def_rej = false, def_acc = false;
      if (unc & lbit) {
        unsigned int mlo = 0xFFFFFFFFu >> __clz(il_min);
        unsigned int mhi = 0xFFFFFFFFu >> __clz(il_max);
        if (mlo == mhi) {
          unsigned int w = v & mlo;
          def_rej = (w > (unsigned int)il_max);
          def_acc = (w <= (unsigned int)il_min);
        } else if (ubelow == 0) {              // octave boundary: exact resolve
          unsigned int w = v & mlo;
          def_rej = (w > (unsigned int)il_min);
          def_acc = !def_rej;
        }
      }
      unsigned long long nr = __ballot(def_rej);
      unsigned long long nc = __ballot(def_acc);
      rej |= nr; acc |= nc;
    }
    int rbelow = __popcll(rej & lmask);
    int il = i - lane + rbelow;
    int totAcc = 64 - __popcll(rej);
    if ((acc & lbit) && il >= MAXS)
      J[il] = (int)(v & (0xFFFFFFFFu >> __clz(il)));
    int needed = i - (MAXS - 1);
    if (totAcc >= needed) break;
    i -= totAcc; p += 64; v = vnext;
  }
}

// ============================================================================
// K3a: next-hitter index fill.  H[v] = min{ i > v, i in [256,n) : J[i] == v }
// ============================================================================
__global__ __launch_bounds__(256) void k_hfill(const int* __restrict__ meta,
                                               const int* __restrict__ Jsup,
                                               const int* __restrict__ Jqry,
                                               unsigned int* __restrict__ Hsup,
                                               unsigned int* __restrict__ Hqry) {
  const int SB = 5 * (S_LEN / 256);
  int b = blockIdx.x;
  int cls, i; const int* J; unsigned int* H; int n;
  if (b < SB) {
    cls = b / (S_LEN / 256);
    i = (b % (S_LEN / 256)) * 256 + threadIdx.x;
    n = meta[cls];
    J = Jsup + cls * S_LEN; H = Hsup + cls * S_LEN;
  } else {
    b -= SB;
    cls = b / (Q_TOT / 256);
    i = (b % (Q_TOT / 256)) * 256 + threadIdx.x;
    n = meta[5 + cls];
    J = Jqry + (size_t)cls * Q_TOT; H = Hqry + (size_t)cls * Q_TOT;
  }
  if (i < MAXS || i >= n) return;
  int j = J[i];
  if (j != i) atomicMin(&H[j], (unsigned int)i);
}

// ============================================================================
// K3b: chase.  sel[t][s] = list[ c(s) ]
// ============================================================================
__global__ __launch_bounds__(256) void k_chase(const int* __restrict__ meta,
                                               const int* __restrict__ sup_list,
                                               const int* __restrict__ qry_list,
                                               const unsigned int* __restrict__ Hsup,
                                               const unsigned int* __restrict__ Hqry,
                                               int* sel) {
  int t = blockIdx.x; int tid = threadIdx.x;
  int cls = t % 5; int isq = t / 5;
  int n = meta[isq * 5 + cls];
  const int* list; const unsigned int* H;
  if (!isq) { list = sup_list + cls * S_LEN; H = Hsup + cls * S_LEN; }
  else      { list = qry_list + (size_t)cls * Q_TOT; H = Hqry + (size_t)cls * Q_TOT; }
  int* s = sel + t * MAXS;
  if (n <= MAXS) { if (tid < n) s[tid] = list[tid]; return; }
  unsigned int v = (unsigned int)tid;
  unsigned int h = H[v];
  while (h != 0xFFFFFFFFu) { v = h; h = H[v]; }
  s[tid] = list[v];
}

// ============================================================================
// K4: gather selected feature rows + fused row-norm (x / (||x|| + 1e-12)).
// ============================================================================
__global__ __launch_bounds__(256) void k_gather(const float* __restrict__ f_s,
                                                const float* __restrict__ f_q,
                                                const int* __restrict__ meta,
                                                const int* __restrict__ sel,
                                                float* xa, float* xb) {
  int blk = blockIdx.x;
  int t = blk >> 3;          // class-pair 0..9
  int slab = blk & 7;        // 8 slabs x 32 rows
  int cls = t % 5; int isq = t / 5;
  int n = meta[10 + isq * 5 + cls];
  int tid = threadIdx.x;
  int row = slab * 32 + (tid >> 3);
  int dg = tid & 7;          // 8 d-groups of 32
  if (row >= n) return;      // group-uniform (8 lanes share row)
  int id = sel[t * MAXS + row];
  const float* src; size_t stride; float* dst;
  if (!isq) {
    src = f_s + (size_t)cls * DFEAT * S_LEN + id; stride = S_LEN;
    dst = xa + cls * (MAXS * DFEAT) + row * DFEAT;
  } else {
    int m = id >> 16; int nn = id & 0xFFFF;
    src = f_q + (size_t)m * DFEAT * Q_LEN + nn; stride = Q_LEN;
    dst = xb + cls * (MAXS * DFEAT) + row * DFEAT;
  }
  float v[32];
  #pragma unroll
  for (int dd = 0; dd < 32; ++dd)
    v[dd] = src[(size_t)(dg * 32 + dd) * stride];
  float ss = 0.f;
  #pragma unroll
  for (int dd = 0; dd < 32; ++dd) ss += v[dd] * v[dd];
  ss += __shfl_xor(ss, 1);
  ss += __shfl_xor(ss, 2);
  ss += __shfl_xor(ss, 4);
  float inv = 1.0f / (sqrtf(ss) + 1e-12f);
  #pragma unroll
  for (int dd = 0; dd < 32; ++dd) dst[dg * 32 + dd] = v[dd] * inv;
}

// ============================================================================
// K5: 35 Gram matrices (256x256, K=256)
// ============================================================================
__global__ __launch_bounds__(1024) void k_gram(const float* __restrict__ xa,
                                               const float* __restrict__ xb,
                                               float* Ga, float* Gb, float* Gab) {
  int j = blockIdx.x;
  const float *A, *B; float* G;
  if (j < 5)       { A = xa + j * 65536; B = A; G = Ga + j * 65536; }
  else if (j < 10) { int c = j - 5; A = xb + c * 65536; B = A; G = Gb + c * 65536; }
  else             { int p = j - 10; int k = p / 5, c = p % 5;
                     A = xa + k * 65536; B = xb + c * 65536; G = Gab + p * 65536; }
  __shared__ float As[256][17];
  __shared__ float Bs[256][17];
  int tid = threadIdx.x;
  int ti = tid >> 5, tj = tid & 31;
  float acc[8][8];
  #pragma unroll
  for (int r = 0; r < 8; ++r)
    #pragma unroll
    for (int s = 0; s < 8; ++s) acc[r][s] = 0.f;
  for (int k0 = 0; k0 < 256; k0 += 16) {
    #pragma unroll
    for (int e = 0; e < 4; ++e) {
      int idx = tid + e * 1024;
      int i = idx >> 4, kk = idx & 15;
      As[i][kk] = A[i * 256 + k0 + kk];
      Bs[i][kk] = B[i * 256 + k0 + kk];
    }
    __syncthreads();
    #pragma unroll
    for (int kk = 0; kk < 16; ++kk) {
      float a[8], b[8];
      #pragma unroll
      for (int r = 0; r < 8; ++r) a[r] = As[ti * 8 + r][kk];
      #pragma unroll
      for (int s = 0; s < 8; ++s) b[s] = Bs[tj * 8 + s][kk];
      #pragma unroll
      for (int r = 0; r < 8; ++r)
        #pragma unroll
        for (int s = 0; s < 8; ++s) acc[r][s] += a[r] * b[s];
    }
    __syncthreads();
  }
  #pragma unroll
  for (int r = 0; r < 8; ++r)
    #pragma unroll
    for (int s = 0; s < 8; ++s)
      G[(ti * 8 + r) * 256 + tj * 8 + s] = acc[r][s];
}

// ============================================================================
// K6: extract Gram diagonals
// ============================================================================
__global__ __launch_bounds__(256) void k_diag(const float* __restrict__ Ga,
                                              const float* __restrict__ Gb,
                                              float* diagA, float* diagB) {
  int t = blockIdx.x; int i = threadIdx.x;
  if (t < 5) diagA[t * 256 + i] = Ga[t * 65536 + i * 257];
  else { int c = t - 5; diagB[c * 256 + i] = Gb[c * 65536 + i * 257]; }
}

// ============================================================================
// K7: G -> D in place: D_ij = max(dA_i + dB_j - 2 g_ij, 0)
// ============================================================================
__global__ __launch_bounds__(256) void k_conv(float* Ga, float* Gb, float* Gab,
                                              const float* __restrict__ diagA,
                                              const float* __restrict__ diagB) {
  int j = blockIdx.x; int tid = threadIdx.x;
  float* G; const float *dA, *dB;
  if (j < 5)       { G = Ga + j * 65536; dA = diagA + j * 256; dB = dA; }
  else if (j < 10) { int c = j - 5; G = Gb + c * 65536; dA = diagB + c * 256; dB = dA; }
  else             { int p = j - 10; int k = p / 5, c = p % 5;
                     G = Gab + p * 65536; dA = diagA + k * 256; dB = diagB + c * 256; }
  float db = dB[tid];
  for (int i = 0; i < 256; ++i) {
    float g = G[i * 256 + tid];
    float d = dA[i] + db - 2.0f * g;
    G[i * 256 + tid] = d > 0.f ? d : 0.f;
  }
}

// ============================================================================
// K8: per (k,c): exact median via bisection on float bits -> sigma -> MMD^2
// ============================================================================
__global__ __launch_bounds__(256) void k_medmmd(const int* __restrict__ meta,
                                                const float* __restrict__ Da_all,
                                                const float* __restrict__ Db_all,
                                                const float* __restrict__ Dab_all,
                                                float* mmd_out) {
  int p = blockIdx.x; int kcl = p / 5, ccl = p % 5;
  int tid = threadIdx.x;
  int nsf = meta[kcl], nqf = meta[5 + ccl];
  if (nsf < 2 || nqf < 2) { if (tid == 0) mmd_out[p] = 0.0f; return; }
  int na = meta[10 + kcl], nb = meta[15 + ccl];
  const float* Da  = Da_all  + kcl * 65536;
  const float* Db  = Db_all  + ccl * 65536;
  const float* Dab = Dab_all + p * 65536;

  __shared__ unsigned int sred[256];
  __shared__ double dred[256];

  unsigned int N = (unsigned int)(na + nb) * (unsigned int)(na + nb);
  bool fast = (na == 256) && (nb == 256);

  // ---- exact-zero count (Dab double) ----
  unsigned int zc = 0;
  if (fast) {
    const float4* A4 = (const float4*)Da;
    const float4* B4 = (const float4*)Db;
    const float4* C4 = (const float4*)Dab;
    for (int k = 0; k < 64; ++k) {
      float4 a = A4[tid + k * 256];
      zc += (a.x == 0.f ? 1u : 0u) + (a.y == 0.f ? 1u : 0u)
          + (a.z == 0.f ? 1u : 0u) + (a.w == 0.f ? 1u : 0u);
    }
    for (int k = 0; k < 64; ++k) {
      float4 b = B4[tid + k * 256];
      zc += (b.x == 0.f ? 1u : 0u) + (b.y == 0.f ? 1u : 0u)
          + (b.z == 0.f ? 1u : 0u) + (b.w == 0.f ? 1u : 0u);
    }
    for (int k = 0; k < 64; ++k) {
      float4 c = C4[tid + k * 256];
      zc += 2u * ((c.x == 0.f ? 1u : 0u) + (c.y == 0.f ? 1u : 0u)
                + (c.z == 0.f ? 1u : 0u) + (c.w == 0.f ? 1u : 0u));
    }
  } else {
    if (tid < na) for (int i = 0; i < na; ++i) zc += (Da[i * 256 + tid] == 0.f) ? 1u : 0u;
    if (tid < nb) for (int i = 0; i < nb; ++i) zc += (Db[i * 256 + tid] == 0.f) ? 1u : 0u;
    if (tid < nb) for (int i = 0; i < na; ++i) zc += (Dab[i * 256 + tid] == 0.f) ? 2u : 0u;
  }
  sred[tid] = zc; __syncthreads();
  for (int s = 128; s > 0; s >>= 1) { if (tid < s) sred[tid] += sred[tid + s]; __syncthreads(); }
  unsigned int nz = sred[0]; __syncthreads();

  float base;
  if (nz >= N) {
    base = 1.0f;
  } else {
    unsigned int r = nz + (N - nz - 1u) / 2u;   // 0-based target rank
    unsigned int lo = 0u, hi = 0x41000000u;     // keys in [0, 8.0)
    while (lo < hi) {
      unsigned int mid = (lo + hi) >> 1;
      float piv = __uint_as_float(mid);
      unsigned int cnt = 0;
      if (fast) {
        const float4* A4 = (const float4*)Da;
        const float4* B4 = (const float4*)Db;
        const float4* C4 = (const float4*)Dab;
        for (int k = 0; k < 64; ++k) {
          float4 a = A4[tid + k * 256];
          cnt += (a.x <= piv ? 1u : 0u) + (a.y <= piv ? 1u : 0u)
               + (a.z <= piv ? 1u : 0u) + (a.w <= piv ? 1u : 0u);
        }
        for (int k = 0; k < 64; ++k) {
          float4 b = B4[tid + k * 256];
          cnt += (b.x <= piv ? 1u : 0u) + (b.y <= piv ? 1u : 0u)
               + (b.z <= piv ? 1u : 0u) + (b.w <= piv ? 1u : 0u);
        }
        for (int k = 0; k < 64; ++k) {
          float4 c = C4[tid + k * 256];
          cnt += 2u * ((c.x <= piv ? 1u : 0u) + (c.y <= piv ? 1u : 0u)
                     + (c.z <= piv ? 1u : 0u) + (c.w <= piv ? 1u : 0u));
        }
      } else {
        if (tid < na) for (int i = 0; i < na; ++i) cnt += (Da[i * 256 + tid] <= piv) ? 1u : 0u;
        if (tid < nb) for (int i = 0; i < nb; ++i) cnt += (Db[i * 256 + tid] <= piv) ? 1u : 0u;
        if (tid < nb) for (int i = 0; i < na; ++i) cnt += (Dab[i * 256 + tid] <= piv) ? 2u : 0u;
      }
      sred[tid] = cnt; __syncthreads();
      for (int s = 128; s > 0; s >>= 1) { if (tid < s) sred[tid] += sred[tid + s]; __syncthreads(); }
      unsigned int tot = sred[0]; __syncthreads();
      if (tot > r) hi = mid; else lo = mid + 1;
    }
    base = sqrtf(__uint_as_float(lo) + 1e-6f);
  }

  // ---- multi-sigma RBF sums: sum_s exp(-d / (2 (base*s)^2)), s in {.5,1,2,4}
  float g2 = base * base;
  float c0 = 1.0f / (2.0f * g2 * 0.25f);
  float c1 = 1.0f / (2.0f * g2 * 1.0f);
  float c2 = 1.0f / (2.0f * g2 * 4.0f);
  float c3 = 1.0f / (2.0f * g2 * 16.0f);
  double accA = 0.0, accB = 0.0, accAB = 0.0;
  for (int i = 0; i < na; ++i) if (tid < na) {
    float d = Da[i * 256 + tid];
    accA += (double)(expf(-d * c0) + expf(-d * c1) + expf(-d * c2) + expf(-d * c3));
  }
  for (int i = 0; i < nb; ++i) if (tid < nb) {
    float d = Db[i * 256 + tid];
    accB += (double)(expf(-d * c0) + expf(-d * c1) + expf(-d * c2) + expf(-d * c3));
  }
  for (int i = 0; i < na; ++i) if (tid < nb) {
    float d = Dab[i * 256 + tid];
    accAB += (double)(expf(-d * c0) + expf(-d * c1) + expf(-d * c2) + expf(-d * c3));
  }
  dred[tid] = accA; __syncthreads();
  for (int s = 128; s > 0; s >>= 1) { if (tid < s) dred[tid] += dred[tid + s]; __syncthreads(); }
  double SA = dred[0]; __syncthreads();
  dred[tid] = accB; __syncthreads();
  for (int s = 128; s > 0; s >>= 1) { if (tid < s) dred[tid] += dred[tid + s]; __syncthreads(); }
  double SB = dred[0]; __syncthreads();
  dred[tid] = accAB; __syncthreads();
  for (int s = 128; s > 0; s >>= 1) { if (tid < s) dred[tid] += dred[tid + s]; __syncthreads(); }
  double SAB = dred[0];
  if (tid == 0) {
    double meanA  = SA  / ((double)na * (double)na);
    double meanB  = SB  / ((double)nb * (double)nb);
    double meanAB = SAB / ((double)na * (double)nb);
    double m = meanA + meanB - 2.0 * meanAB;
    mmd_out[p] = (float)(m > 0.0 ? m : 0.0);
  }
}

// ============================================================================
// K9: final weighted loss
// ============================================================================
__global__ void k_final(const int* __restrict__ meta, const float* __restrict__ mmd,
                        float* out) {
  if (threadIdx.x != 0 || blockIdx.x != 0) return;
  double total = 0.0, vw = 0.0;
  for (int c = 0; c < 5; ++c) {
    int nsf = meta[c], nqf = meta[5 + c];
    if (nsf < 2 || nqf < 2) continue;
    double pos = (double)mmd[c * 5 + c];
    bool any = false; double best = 0.0;
    for (int k = 0; k < 5; ++k) {
      if (k == c || meta[k] < 2) continue;
      double v = (double)mmd[k * 5 + c];
      if (!any || v < best) { best = v; any = true; }
    }
    double lc = any ? fmax(pos - best + 0.1, 0.0) : pos;
    double w = sqrt((double)nsf * (double)nqf);
    total += w * lc; vw += w;
  }
  out[0] = (float)(0.1 * total / fmax(vw, 1e-12));
}

// ============================================================================
// host launcher
// ============================================================================
extern "C" void kernel_launch(void* const* d_in, const int* in_sizes, int n_in,
                              void* d_out, int out_size, void* d_ws, size_t ws_size,
                              hipStream_t stream) {
  const float* f_s = (const float*)d_in[0];
  const int*   l_s = (const int*)d_in[1];
  const float* f_q = (const float*)d_in[2];
  const int*   l_q = (const int*)d_in[3];
  float* out = (float*)d_out;
  char* ws = (char*)d_ws;

  size_t off = 0;
  auto take = [&](size_t bytes) -> void* {
    void* p = ws + off;
    off = (off + bytes + 255) & ~(size_t)255;
    return p;
  };
  int*   meta     = (int*)take(32 * 4);
  int*   cnts     = (int*)take(NBLK_C * 4);
  int*   offs     = (int*)take(NBLK_C * 4);
  int*   sup_list = (int*)take((size_t)5 * S_LEN * 4);
  int*   qry_list = (int*)take((size_t)5 * Q_TOT * 4);
  int*   Jsup     = (int*)take((size_t)5 * S_LEN * 4);
  int*   Jqry     = (int*)take((size_t)5 * Q_TOT * 4);
  unsigned int* draws = (unsigned int*)take((10ull * CAPS64 + 10ull * CAPQ64) * 4);
  int*   sel      = (int*)take((size_t)10 * MAXS * 4);
  float* xa       = (float*)take((size_t)5 * 65536 * 4);
  float* xb       = (float*)take((size_t)5 * 65536 * 4);
  float* Ga       = (float*)take((size_t)5 * 65536 * 4);
  float* Gb       = (float*)take((size_t)5 * 65536 * 4);
  float* Gab      = (float*)take((size_t)25 * 65536 * 4);
  float* diagA    = (float*)take((size_t)5 * 256 * 4);
  float* diagB    = (float*)take((size_t)5 * 256 * 4);
  float* mmd      = (float*)take(25 * 4);
  if (off > ws_size) return;

  // H (next-hitter) arrays alias the draws buffer — draws dead after k_consume.
  unsigned int* Hsup = draws;
  unsigned int* Hqry = draws + (size_t)5 * S_LEN;
  size_t hbytes = ((size_t)5 * S_LEN + (size_t)5 * Q_TOT) * 4;

  k_draws<<<10, 256, 0, stream>>>(draws);
  k_count<<<NBLK_C, 256, 0, stream>>>(l_s, l_q, cnts);
  k_scan<<<1, 64, 0, stream>>>(cnts, offs, meta);
  k_write<<<NBLK_C, 256, 0, stream>>>(l_s, l_q, offs, sup_list, qry_list);
  k_consume<<<10, 64, 0, stream>>>(meta, draws, Jsup, Jqry);
  hipMemsetAsync(Hsup, 0xFF, hbytes, stream);
  {
    int nblk = 5 * (S_LEN / 256) + 5 * (Q_TOT / 256);   // 320 + 6400
    k_hfill<<<nblk, 256, 0, stream>>>(meta, Jsup, Jqry, Hsup, Hqry);
  }
  k_chase<<<10, 256, 0, stream>>>(meta, sup_list, qry_list, Hsup, Hqry, sel);
  k_gather<<<80, 256, 0, stream>>>(f_s, f_q, meta, sel, xa, xb);
  k_gram<<<35, 1024, 0, stream>>>(xa, xb, Ga, Gb, Gab);
  k_diag<<<10, 256, 0, stream>>>(Ga, Gb, diagA, diagB);
  k_conv<<<35, 256, 0, stream>>>(Ga, Gb, Gab, diagA, diagB);
  k_medmmd<<<25, 256, 0, stream>>>(meta, Ga, Gb, Gab, mmd);
  k_final<<<1, 64, 0, stream>>>(meta, mmd, out);
}

// Round 7
// 1300.271 us; speedup vs baseline: 10.5329x; 1.2998x over previous
//
#include <hip/hip_runtime.h>

// ============================================================================
// numpy RNG replication: SeedSequence + PCG64 (XSL-RR 128/64), next32 buffering
// ============================================================================
struct U128 { unsigned long long hi, lo; };

__device__ __forceinline__ U128 u128_mul(U128 a, U128 b) {
  U128 r;
  r.lo = a.lo * b.lo;
  r.hi = __umul64hi(a.lo, b.lo) + a.hi * b.lo + a.lo * b.hi;
  return r;
}
__device__ __forceinline__ U128 u128_add(U128 a, U128 b) {
  U128 r; r.lo = a.lo + b.lo; r.hi = a.hi + b.hi + (r.lo < a.lo ? 1ull : 0ull); return r;
}

struct Pcg64 {
  U128 state, inc;
};

__device__ __forceinline__ void pcg_step(Pcg64* r) {
  const U128 M = {0x2360ed051fc65da4ull, 0x4385df649fccf645ull};
  r->state = u128_add(u128_mul(r->state, M), r->inc);
}
__device__ __forceinline__ unsigned long long pcg_next64(Pcg64* r) {
  pcg_step(r);
  unsigned int rot = (unsigned int)(r->state.hi >> 58);   // state >> 122
  unsigned long long x = r->state.hi ^ r->state.lo;       // XSL
  return (x >> rot) | (x << ((64u - rot) & 63u));         // RR
}

// SeedSequence constants (numpy bit_generator.pyx)
__device__ __forceinline__ unsigned int ss_hashmix(unsigned int v, unsigned int* hc) {
  v ^= *hc; *hc = *hc * 0x931e8875u; v *= *hc; v ^= v >> 16; return v;
}
__device__ __forceinline__ unsigned int ss_mix(unsigned int x, unsigned int y) {
  unsigned int r = x * 0xca01f9ddu ^ y * 0x4973f715u; r ^= r >> 16; return r;
}
__device__ void pcg_seed(Pcg64* rng, unsigned int seed) {
  unsigned int pool[4]; unsigned int hc = 0x43b0d7e5u;   // INIT_A
  pool[0] = ss_hashmix(seed, &hc);
  for (int i = 1; i < 4; ++i) pool[i] = ss_hashmix(0u, &hc);
  for (int s = 0; s < 4; ++s)
    for (int d = 0; d < 4; ++d)
      if (s != d) pool[d] = ss_mix(pool[d], ss_hashmix(pool[s], &hc));
  unsigned int hc2 = 0x8b51f9ddu;                        // INIT_B
  unsigned long long w64[4];
  for (int i = 0; i < 4; ++i) {
    unsigned int lo = pool[(2*i) & 3];
    lo ^= hc2; hc2 *= 0x58f38dedu; lo *= hc2; lo ^= lo >> 16;
    unsigned int hi = pool[(2*i+1) & 3];
    hi ^= hc2; hc2 *= 0x58f38dedu; hi *= hc2; hi ^= hi >> 16;
    w64[i] = (unsigned long long)lo | ((unsigned long long)hi << 32);
  }
  U128 initstate = {w64[0], w64[1]};   // PCG_128BIT_CONSTANT(seed[0], seed[1]): [0] is HIGH
  U128 initseq   = {w64[2], w64[3]};
  rng->inc.hi = (initseq.hi << 1) | (initseq.lo >> 63);
  rng->inc.lo = (initseq.lo << 1) | 1ull;
  rng->state.hi = 0; rng->state.lo = 0;
  pcg_step(rng);
  rng->state = u128_add(rng->state, initstate);
  pcg_step(rng);
}

// affine jump-ahead: state <- A^delta * state + (A^delta-1)/(A-1)*inc
__device__ void pcg_advance(Pcg64* r, unsigned long long delta) {
  U128 acc_mult = {0ull, 1ull}, acc_plus = {0ull, 0ull};
  U128 cur_mult = {0x2360ed051fc65da4ull, 0x4385df649fccf645ull};
  U128 cur_plus = r->inc;
  while (delta) {
    if (delta & 1ull) {
      acc_mult = u128_mul(acc_mult, cur_mult);
      acc_plus = u128_add(u128_mul(acc_plus, cur_mult), cur_plus);
    }
    U128 one = {0ull, 1ull};
    U128 cm1 = u128_add(cur_mult, one);
    cur_plus = u128_mul(cm1, cur_plus);
    cur_mult = u128_mul(cur_mult, cur_mult);
    delta >>= 1;
  }
  r->state = u128_add(u128_mul(r->state, acc_mult), acc_plus);
}

// ============================================================================
// Problem constants
// ============================================================================
#define S_LEN   16384
#define Q_LEN   65536
#define Q_TOT   327680     // 5*65536
#define DFEAT   256
#define MAXS    256
#define CAPS64  24576
#define CAPQ64  98304
#define TILE    4096
#define STILES  (S_LEN / TILE)    // 4
#define QTILES  (Q_TOT / TILE)    // 80
#define NBLK_C  (5 * STILES + 5 * QTILES)   // 420
#define MSHARDS 8
#define MPASSES 8

// meta layout: [0..4]=ns_full, [5..9]=nq_full, [10..14]=na, [15..19]=nb

__constant__ int c_kshift[MPASSES] = {27, 23, 19, 15, 11, 7, 3, 0};

// ============================================================================
// K0: parallel draw-stream generation (exact numpy next32 sequence, lo first)
// ============================================================================
__global__ __launch_bounds__(256) void k_draws(unsigned int* __restrict__ draws) {
  int t = blockIdx.x; int cls = t % 5; int isq = t / 5;
  unsigned int seed = (unsigned)(1000 + isq * 1000 + cls + 1);
  unsigned long long cap64 = isq ? CAPQ64 : CAPS64;
  unsigned int* dst = draws + (isq ? (10ull * CAPS64 + (unsigned long long)cls * 2 * CAPQ64)
                                   : ((unsigned long long)cls * 2 * CAPS64));
  Pcg64 rng; pcg_seed(&rng, seed);
  int tid = threadIdx.x;
  unsigned long long C = cap64 / 256ull;     // 96 or 384
  unsigned long long k0 = (unsigned long long)tid * C;
  pcg_advance(&rng, k0);
  uint2* d2 = (uint2*)dst;
  for (unsigned long long m = 0; m < C; ++m) {
    unsigned long long o = pcg_next64(&rng);
    d2[k0 + m] = make_uint2((unsigned int)o, (unsigned int)(o >> 32));
  }
}

// ============================================================================
// K1a: per-tile match counts
// ============================================================================
__global__ __launch_bounds__(256) void k_count(const int* __restrict__ ls,
                                               const int* __restrict__ lq,
                                               int* __restrict__ cnts) {
  int b = blockIdx.x;
  const int* src; int matchval;
  if (b < 5 * STILES) {
    int cls = b / STILES, tl = b % STILES;
    src = ls + cls * S_LEN + tl * TILE; matchval = 1;
  } else {
    int bb = b - 5 * STILES; int cls = bb / QTILES, tl = bb % QTILES;
    src = lq + tl * TILE; matchval = cls + 1;
  }
  int tid = threadIdx.x;
  int cnt = 0;
  for (int k = 0; k < TILE; k += 256) cnt += (src[k + tid] == matchval) ? 1 : 0;
  __shared__ int red[256];
  red[tid] = cnt; __syncthreads();
  for (int s = 128; s > 0; s >>= 1) { if (tid < s) red[tid] += red[tid + s]; __syncthreads(); }
  if (tid == 0) cnts[b] = red[0];
}

// ============================================================================
// K1b: tiny scan: exclusive offsets per class + meta totals
// ============================================================================
__global__ void k_scan(const int* __restrict__ cnts, int* __restrict__ offs,
                       int* __restrict__ meta) {
  int t = threadIdx.x;
  if (t < 5) {
    int base = 0;
    for (int k = 0; k < STILES; ++k) {
      offs[t * STILES + k] = base; base += cnts[t * STILES + k];
    }
    meta[t] = base;
    meta[10 + t] = base < MAXS ? base : MAXS;
  } else if (t < 10) {
    int c = t - 5; int base = 0;
    for (int k = 0; k < QTILES; ++k) {
      int idx = 5 * STILES + c * QTILES + k;
      offs[idx] = base; base += cnts[idx];
    }
    meta[5 + c] = base;
    meta[15 + c] = base < MAXS ? base : MAXS;
  }
}

// ============================================================================
// K1c: stable compaction write at per-tile offsets (4-wave ballot prefix)
// ============================================================================
__global__ __launch_bounds__(256) void k_write(const int* __restrict__ ls,
                                               const int* __restrict__ lq,
                                               const int* __restrict__ offs,
                                               int* __restrict__ sup_list,
                                               int* __restrict__ qry_list) {
  int b = blockIdx.x;
  const int* src; int matchval; int* out; int ibase;
  if (b < 5 * STILES) {
    int cls = b / STILES, tl = b % STILES;
    src = ls + cls * S_LEN + tl * TILE; matchval = 1;
    out = sup_list + cls * S_LEN; ibase = tl * TILE;
  } else {
    int bb = b - 5 * STILES; int cls = bb / QTILES, tl = bb % QTILES;
    src = lq + tl * TILE; matchval = cls + 1;
    out = qry_list + (size_t)cls * Q_TOT; ibase = tl * TILE;
  }
  int tid = threadIdx.x; int w = tid >> 6, lane = tid & 63;
  unsigned long long lmask = (1ull << lane) - 1ull;
  __shared__ int wcnt[4];
  int base = offs[b];
  for (int k = 0; k < TILE; k += 256) {
    int i = k + tid;
    bool p = (src[i] == matchval);
    unsigned long long m = __ballot(p);
    if (lane == 0) wcnt[w] = __popcll(m);
    __syncthreads();
    int prev = 0;
    #pragma unroll
    for (int ww = 0; ww < 4; ++ww) prev += (ww < w) ? wcnt[ww] : 0;
    int tot = wcnt[0] + wcnt[1] + wcnt[2] + wcnt[3];
    if (p) out[base + prev + __popcll(m & lmask)] = ibase + i;
    __syncthreads();
    base += tot;
  }
}

// ============================================================================
// K2: wave-parallel masked-rejection automaton, INTERVAL-COMMIT resolution.
// ============================================================================
__global__ __launch_bounds__(64) void k_consume(const int* __restrict__ meta,
                                                const unsigned int* __restrict__ draws,
                                                int* Jsup, int* Jqry) {
  int t = blockIdx.x; int cls = t % 5; int isq = t / 5;
  int n = meta[isq * 5 + cls];
  if (n <= MAXS) return;
  const unsigned int* d = draws + (isq ? (10ull * CAPS64 + (unsigned long long)cls * 2 * CAPQ64)
                                       : ((unsigned long long)cls * 2 * CAPS64));
  int* J = isq ? (Jqry + (size_t)cls * Q_TOT) : (Jsup + cls * S_LEN);
  int lane = threadIdx.x;
  unsigned long long lmask = (1ull << lane) - 1ull;
  unsigned long long lbit  = (1ull << lane);
  int i = n - 1;
  size_t p = 0;
  unsigned int v = d[lane];
  for (;;) {
    unsigned int vnext = d[p + 64 + lane];     // prefetch next chunk
    unsigned long long rej = 0ull, acc = 0ull;
    for (int it = 0; it < 72; ++it) {
      unsigned long long unc = ~(rej | acc);
      if (!unc) break;
      int rbelow = __popcll(rej & lmask);
      int ubelow = __popcll(unc & lmask);
      int il_min = i - lane + rbelow;          // >= 193 always
      int il_max = il_min + ubelow;
      bool def_rej = false, def_acc = false;
      if (unc & lbit) {
        unsigned int mlo = 0xFFFFFFFFu >> __clz(il_min);
        unsigned int mhi = 0xFFFFFFFFu >> __clz(il_max);
        if (mlo == mhi) {
          unsigned int w = v & mlo;
          def_rej = (w > (unsigned int)il_max);
          def_acc = (w <= (unsigned int)il_min);
        } else if (ubelow == 0) {              // octave boundary: exact resolve
          unsigned int w = v & mlo;
          def_rej = (w > (unsigned int)il_min);
          def_acc = !def_rej;
        }
      }
      unsigned long long nr = __ballot(def_rej);
      unsigned long long nc = __ballot(def_acc);
      rej |= nr; acc |= nc;
    }
    int rbelow = __popcll(rej & lmask);
    int il = i - lane + rbelow;
    int totAcc = 64 - __popcll(rej);
    if ((acc & lbit) && il >= MAXS)
      J[il] = (int)(v & (0xFFFFFFFFu >> __clz(il)));
    int needed = i - (MAXS - 1);
    if (totAcc >= needed) break;
    i -= totAcc; p += 64; v = vnext;
  }
}

// ============================================================================
// K3a: next-hitter index fill.  H[v] = min{ i > v, i in [256,n) : J[i] == v }
// ============================================================================
__global__ __launch_bounds__(256) void k_hfill(const int* __restrict__ meta,
                                               const int* __restrict__ Jsup,
                                               const int* __restrict__ Jqry,
                                               unsigned int* __restrict__ Hsup,
                                               unsigned int* __restrict__ Hqry) {
  const int SB = 5 * (S_LEN / 256);
  int b = blockIdx.x;
  int cls, i; const int* J; unsigned int* H; int n;
  if (b < SB) {
    cls = b / (S_LEN / 256);
    i = (b % (S_LEN / 256)) * 256 + threadIdx.x;
    n = meta[cls];
    J = Jsup + cls * S_LEN; H = Hsup + cls * S_LEN;
  } else {
    b -= SB;
    cls = b / (Q_TOT / 256);
    i = (b % (Q_TOT / 256)) * 256 + threadIdx.x;
    n = meta[5 + cls];
    J = Jqry + (size_t)cls * Q_TOT; H = Hqry + (size_t)cls * Q_TOT;
  }
  if (i < MAXS || i >= n) return;
  int j = J[i];
  if (j != i) atomicMin(&H[j], (unsigned int)i);
}

// ============================================================================
// K3b: chase.  sel[t][s] = list[ c(s) ]
// ============================================================================
__global__ __launch_bounds__(256) void k_chase(const int* __restrict__ meta,
                                               const int* __restrict__ sup_list,
                                               const int* __restrict__ qry_list,
                                               const unsigned int* __restrict__ Hsup,
                                               const unsigned int* __restrict__ Hqry,
                                               int* sel) {
  int t = blockIdx.x; int tid = threadIdx.x;
  int cls = t % 5; int isq = t / 5;
  int n = meta[isq * 5 + cls];
  const int* list; const unsigned int* H;
  if (!isq) { list = sup_list + cls * S_LEN; H = Hsup + cls * S_LEN; }
  else      { list = qry_list + (size_t)cls * Q_TOT; H = Hqry + (size_t)cls * Q_TOT; }
  int* s = sel + t * MAXS;
  if (n <= MAXS) { if (tid < n) s[tid] = list[tid]; return; }
  unsigned int v = (unsigned int)tid;
  unsigned int h = H[v];
  while (h != 0xFFFFFFFFu) { v = h; h = H[v]; }
  s[tid] = list[v];
}

// ============================================================================
// K4: gather selected feature rows + fused row-norm (x / (||x|| + 1e-12)).
// ============================================================================
__global__ __launch_bounds__(256) void k_gather(const float* __restrict__ f_s,
                                                const float* __restrict__ f_q,
                                                const int* __restrict__ meta,
                                                const int* __restrict__ sel,
                                                float* xa, float* xb) {
  int blk = blockIdx.x;
  int t = blk >> 3;          // class-pair 0..9
  int slab = blk & 7;        // 8 slabs x 32 rows
  int cls = t % 5; int isq = t / 5;
  int n = meta[10 + isq * 5 + cls];
  int tid = threadIdx.x;
  int row = slab * 32 + (tid >> 3);
  int dg = tid & 7;          // 8 d-groups of 32
  if (row >= n) return;      // group-uniform (8 lanes share row)
  int id = sel[t * MAXS + row];
  const float* src; size_t stride; float* dst;
  if (!isq) {
    src = f_s + (size_t)cls * DFEAT * S_LEN + id; stride = S_LEN;
    dst = xa + cls * (MAXS * DFEAT) + row * DFEAT;
  } else {
    int m = id >> 16; int nn = id & 0xFFFF;
    src = f_q + (size_t)m * DFEAT * Q_LEN + nn; stride = Q_LEN;
    dst = xb + cls * (MAXS * DFEAT) + row * DFEAT;
  }
  float v[32];
  #pragma unroll
  for (int dd = 0; dd < 32; ++dd)
    v[dd] = src[(size_t)(dg * 32 + dd) * stride];
  float ss = 0.f;
  #pragma unroll
  for (int dd = 0; dd < 32; ++dd) ss += v[dd] * v[dd];
  ss += __shfl_xor(ss, 1);
  ss += __shfl_xor(ss, 2);
  ss += __shfl_xor(ss, 4);
  float inv = 1.0f / (sqrtf(ss) + 1e-12f);
  #pragma unroll
  for (int dd = 0; dd < 32; ++dd) dst[dg * 32 + dd] = v[dd] * inv;
}

// ============================================================================
// K5: 35 Gram matrices (256x256, K=256)
// ============================================================================
__global__ __launch_bounds__(1024) void k_gram(const float* __restrict__ xa,
                                               const float* __restrict__ xb,
                                               float* Ga, float* Gb, float* Gab) {
  int j = blockIdx.x;
  const float *A, *B; float* G;
  if (j < 5)       { A = xa + j * 65536; B = A; G = Ga + j * 65536; }
  else if (j < 10) { int c = j - 5; A = xb + c * 65536; B = A; G = Gb + c * 65536; }
  else             { int p = j - 10; int k = p / 5, c = p % 5;
                     A = xa + k * 65536; B = xb + c * 65536; G = Gab + p * 65536; }
  __shared__ float As[256][17];
  __shared__ float Bs[256][17];
  int tid = threadIdx.x;
  int ti = tid >> 5, tj = tid & 31;
  float acc[8][8];
  #pragma unroll
  for (int r = 0; r < 8; ++r)
    #pragma unroll
    for (int s = 0; s < 8; ++s) acc[r][s] = 0.f;
  for (int k0 = 0; k0 < 256; k0 += 16) {
    #pragma unroll
    for (int e = 0; e < 4; ++e) {
      int idx = tid + e * 1024;
      int i = idx >> 4, kk = idx & 15;
      As[i][kk] = A[i * 256 + k0 + kk];
      Bs[i][kk] = B[i * 256 + k0 + kk];
    }
    __syncthreads();
    #pragma unroll
    for (int kk = 0; kk < 16; ++kk) {
      float a[8], b[8];
      #pragma unroll
      for (int r = 0; r < 8; ++r) a[r] = As[ti * 8 + r][kk];
      #pragma unroll
      for (int s = 0; s < 8; ++s) b[s] = Bs[tj * 8 + s][kk];
      #pragma unroll
      for (int r = 0; r < 8; ++r)
        #pragma unroll
        for (int s = 0; s < 8; ++s) acc[r][s] += a[r] * b[s];
    }
    __syncthreads();
  }
  #pragma unroll
  for (int r = 0; r < 8; ++r)
    #pragma unroll
    for (int s = 0; s < 8; ++s)
      G[(ti * 8 + r) * 256 + tj * 8 + s] = acc[r][s];
}

// ============================================================================
// K6: extract Gram diagonals
// ============================================================================
__global__ __launch_bounds__(256) void k_diag(const float* __restrict__ Ga,
                                              const float* __restrict__ Gb,
                                              float* diagA, float* diagB) {
  int t = blockIdx.x; int i = threadIdx.x;
  if (t < 5) diagA[t * 256 + i] = Ga[t * 65536 + i * 257];
  else { int c = t - 5; diagB[c * 256 + i] = Gb[c * 65536 + i * 257]; }
}

// ============================================================================
// K7: G -> D in place (280 blocks: 35 matrices x 8 row-slabs)
// ============================================================================
__global__ __launch_bounds__(256) void k_conv(float* Ga, float* Gb, float* Gab,
                                              const float* __restrict__ diagA,
                                              const float* __restrict__ diagB) {
  int b = blockIdx.x; int j = b >> 3; int slab = b & 7; int tid = threadIdx.x;
  float* G; const float *dA, *dB;
  if (j < 5)       { G = Ga + j * 65536; dA = diagA + j * 256; dB = dA; }
  else if (j < 10) { int c = j - 5; G = Gb + c * 65536; dA = diagB + c * 256; dB = dA; }
  else             { int p = j - 10; int k = p / 5, c = p % 5;
                     G = Gab + p * 65536; dA = diagA + k * 256; dB = diagB + c * 256; }
  float db = dB[tid];
  for (int i = slab * 32; i < slab * 32 + 32; ++i) {
    float g = G[i * 256 + tid];
    float d = dA[i] + db - 2.0f * g;
    G[i * 256 + tid] = d > 0.f ? d : 0.f;
  }
}

// ============================================================================
// K8: grid-parallel 16-ary exact radix-select, one kernel per pass.
//   State per pair: lo (range start bit pattern), base (count of keys < lo).
//   Pass t: buckets of width 2^kshift[t]; blocks count cumulative
//   c[j] = #(key in [lo, lo + (j+1)<<k)) for j=0..14 (Dab weighted x2);
//   every block of pass t recomputes (lo,base) from pass t-1 counts
//   deterministically; shard-0 checkpoints them for the next pass.
// ============================================================================
__device__ __forceinline__ void med_select(const unsigned int* __restrict__ c,
                                           unsigned int lprev, unsigned int bprev,
                                           unsigned int r, int kprev,
                                           unsigned int* lo, unsigned int* base) {
  int j = 15;
  #pragma unroll
  for (int q = 14; q >= 0; --q)
    if (bprev + c[q] > r) j = q;
  *lo = lprev + ((unsigned int)j << kprev);
  *base = (j == 0) ? bprev : bprev + c[j - 1];
}

__global__ __launch_bounds__(256) void k_medpass(int t,
                                                 const int* __restrict__ meta,
                                                 const float* __restrict__ Da_all,
                                                 const float* __restrict__ Db_all,
                                                 const float* __restrict__ Dab_all,
                                                 unsigned int* __restrict__ bufAll,  // [MPASSES][25][16]
                                                 unsigned int* __restrict__ loArr,   // [MPASSES][25]
                                                 unsigned int* __restrict__ baseArr, // [MPASSES][25]
                                                 unsigned int* __restrict__ zcArr) { // [25]
  int b = blockIdx.x;
  int p = b / MSHARDS, sh = b % MSHARDS;
  int kcl = p / 5, ccl = p % 5;
  int tid = threadIdx.x;
  int nsf = meta[kcl], nqf = meta[5 + ccl];
  if (nsf < 2 || nqf < 2) return;
  int na = meta[10 + kcl], nb = meta[15 + ccl];
  const float4* A4 = (const float4*)(Da_all + kcl * 65536);
  const float4* B4 = (const float4*)(Db_all + ccl * 65536);
  const float4* C4 = (const float4*)(Dab_all + p * 65536);

  __shared__ unsigned int sh_lo[1], sh_base[1];
  __shared__ unsigned int wred[4][16];
  __shared__ unsigned int wzc[4];

  int ks = c_kshift[t];
  unsigned int N = (unsigned int)(na + nb) * (unsigned int)(na + nb);

  if (tid == 0) {
    unsigned int lo = 0, base = 0;
    if (t > 0) {
      unsigned int nz = zcArr[p];
      if (nz < N) {
        unsigned int r = nz + (N - nz - 1u) / 2u;
        unsigned int cprev[15];
        const unsigned int* cp = bufAll + ((size_t)(t - 1) * 25 + p) * 16;
        #pragma unroll
        for (int q = 0; q < 15; ++q) cprev[q] = cp[q];
        med_select(cprev, loArr[(t - 1) * 25 + p], baseArr[(t - 1) * 25 + p],
                   r, c_kshift[t - 1], &lo, &base);
      }
    }
    sh_lo[0] = lo; sh_base[0] = base;
    if (sh == 0) { loArr[t * 25 + p] = lo; baseArr[t * 25 + p] = base; }
  }
  __syncthreads();
  unsigned int lo = sh_lo[0];

  unsigned int cnt[15];
  #pragma unroll
  for (int j = 0; j < 15; ++j) cnt[j] = 0;
  unsigned int zc = 0;
  unsigned int span = 16u << ks;   // ks<=27 -> fits u32 (16<<27 = 2^31)

  #define PROC_MAT(M4, nr, nc, W)                                             \
    for (int m = 0; m < 8; ++m) {                                             \
      int fidx = sh * 2048 + m * 256 + tid;                                   \
      float4 v = M4[fidx];                                                    \
      int row = fidx >> 6; int col0 = (fidx & 63) << 2;                       \
      unsigned int kb[4] = {__float_as_uint(v.x), __float_as_uint(v.y),       \
                            __float_as_uint(v.z), __float_as_uint(v.w)};      \
      _Pragma("unroll")                                                       \
      for (int cc = 0; cc < 4; ++cc) {                                        \
        bool valid = (row < (nr)) && (col0 + cc < (nc));                      \
        unsigned int key = kb[cc];                                            \
        if (t == 0) zc += (valid && key == 0u) ? (W) : 0u;                    \
        unsigned int d = key - lo;                                            \
        bool in = valid && (key >= lo) && (d < span);                         \
        _Pragma("unroll")                                                     \
        for (int j = 0; j < 15; ++j)                                          \
          cnt[j] += (in && d < ((unsigned int)(j + 1) << ks)) ? (W) : 0u;     \
      }                                                                       \
    }

  PROC_MAT(A4, na, na, 1u)
  PROC_MAT(B4, nb, nb, 1u)
  PROC_MAT(C4, na, nb, 2u)
  #undef PROC_MAT

  // wave-level reduce then cross-wave
  #pragma unroll
  for (int j = 0; j < 15; ++j)
    for (int o = 32; o > 0; o >>= 1) cnt[j] += __shfl_down(cnt[j], o);
  if (t == 0)
    for (int o = 32; o > 0; o >>= 1) zc += __shfl_down(zc, o);
  int w = tid >> 6, lane = tid & 63;
  if (lane == 0) {
    #pragma unroll
    for (int j = 0; j < 15; ++j) wred[w][j] = cnt[j];
    wzc[w] = zc;
  }
  __syncthreads();
  if (tid < 15) {
    unsigned int s = wred[0][tid] + wred[1][tid] + wred[2][tid] + wred[3][tid];
    atomicAdd(&bufAll[((size_t)t * 25 + p) * 16 + tid], s);
  }
  if (t == 0 && tid == 15) {
    unsigned int s = wzc[0] + wzc[1] + wzc[2] + wzc[3];
    atomicAdd(&zcArr[p], s);
  }
}

// ============================================================================
// K8b: RBF partial sums (200 blocks), sigma from final select
// ============================================================================
__global__ __launch_bounds__(256) void k_rbf(const int* __restrict__ meta,
                                             const float* __restrict__ Da_all,
                                             const float* __restrict__ Db_all,
                                             const float* __restrict__ Dab_all,
                                             const unsigned int* __restrict__ bufAll,
                                             const unsigned int* __restrict__ loArr,
                                             const unsigned int* __restrict__ baseArr,
                                             const unsigned int* __restrict__ zcArr,
                                             double* __restrict__ mmdsum) { // [25][3]
  int b = blockIdx.x;
  int p = b / MSHARDS, sh = b % MSHARDS;
  int kcl = p / 5, ccl = p % 5;
  int tid = threadIdx.x;
  int nsf = meta[kcl], nqf = meta[5 + ccl];
  if (nsf < 2 || nqf < 2) return;
  int na = meta[10 + kcl], nb = meta[15 + ccl];
  const float4* A4 = (const float4*)(Da_all + kcl * 65536);
  const float4* B4 = (const float4*)(Db_all + ccl * 65536);
  const float4* C4 = (const float4*)(Dab_all + p * 65536);

  unsigned int N = (unsigned int)(na + nb) * (unsigned int)(na + nb);
  unsigned int nz = zcArr[p];
  float base_s;
  if (nz >= N) base_s = 1.0f;
  else {
    unsigned int r = nz + (N - nz - 1u) / 2u;
    unsigned int cprev[15];
    const unsigned int* cp = bufAll + ((size_t)(MPASSES - 1) * 25 + p) * 16;
    #pragma unroll
    for (int q = 0; q < 15; ++q) cprev[q] = cp[q];
    unsigned int lo, bs;
    med_select(cprev, loArr[(MPASSES - 1) * 25 + p], baseArr[(MPASSES - 1) * 25 + p],
               r, 0, &lo, &bs);
    base_s = sqrtf(__uint_as_float(lo) + 1e-6f);
  }
  float g2 = base_s * base_s;
  float c0 = 1.0f / (2.0f * g2 * 0.25f);
  float c1 = 1.0f / (2.0f * g2 * 1.0f);
  float c2 = 1.0f / (2.0f * g2 * 4.0f);
  float c3 = 1.0f / (2.0f * g2 * 16.0f);

  double accA = 0.0, accB = 0.0, accAB = 0.0;
  #define RBF_MAT(M4, nr, nc, ACC)                                            \
    for (int m = 0; m < 8; ++m) {                                             \
      int fidx = sh * 2048 + m * 256 + tid;                                   \
      float4 v = M4[fidx];                                                    \
      int row = fidx >> 6; int col0 = (fidx & 63) << 2;                       \
      float vv[4] = {v.x, v.y, v.z, v.w};                                     \
      _Pragma("unroll")                                                       \
      for (int cc = 0; cc < 4; ++cc) {                                        \
        if ((row < (nr)) && (col0 + cc < (nc))) {                             \
          float d = vv[cc];                                                   \
          ACC += (double)(expf(-d * c0) + expf(-d * c1)                       \
                        + expf(-d * c2) + expf(-d * c3));                     \
        }                                                                     \
      }                                                                       \
    }
  RBF_MAT(A4, na, na, accA)
  RBF_MAT(B4, nb, nb, accB)
  RBF_MAT(C4, na, nb, accAB)
  #undef RBF_MAT

  for (int o = 32; o > 0; o >>= 1) {
    accA += __shfl_down(accA, o);
    accB += __shfl_down(accB, o);
    accAB += __shfl_down(accAB, o);
  }
  __shared__ double wsum[4][3];
  int w = tid >> 6, lane = tid & 63;
  if (lane == 0) { wsum[w][0] = accA; wsum[w][1] = accB; wsum[w][2] = accAB; }
  __syncthreads();
  if (tid == 0) {
    double sA = wsum[0][0] + wsum[1][0] + wsum[2][0] + wsum[3][0];
    double sB = wsum[0][1] + wsum[1][1] + wsum[2][1] + wsum[3][1];
    double sC = wsum[0][2] + wsum[1][2] + wsum[2][2] + wsum[3][2];
    atomicAdd(&mmdsum[p * 3 + 0], sA);
    atomicAdd(&mmdsum[p * 3 + 1], sB);
    atomicAdd(&mmdsum[p * 3 + 2], sC);
  }
}

// ============================================================================
// K9: final weighted loss (mmd assembled from sums)
// ============================================================================
__global__ void k_final(const int* __restrict__ meta, const double* __restrict__ mmdsum,
                        float* out) {
  if (threadIdx.x != 0 || blockIdx.x != 0) return;
  double total = 0.0, vw = 0.0;
  for (int c = 0; c < 5; ++c) {
    int nsf = meta[c], nqf = meta[5 + c];
    if (nsf < 2 || nqf < 2) continue;
    int nbq = meta[15 + c];
    double mm[5];
    for (int k = 0; k < 5; ++k) {
      if (meta[k] < 2) { mm[k] = 0.0; continue; }
      int naa = meta[10 + k];
      int pp = k * 5 + c;
      double meanA  = mmdsum[pp * 3 + 0] / ((double)naa * (double)naa);
      double meanB  = mmdsum[pp * 3 + 1] / ((double)nbq * (double)nbq);
      double meanAB = mmdsum[pp * 3 + 2] / ((double)naa * (double)nbq);
      double m = meanA + meanB - 2.0 * meanAB;
      mm[k] = m > 0.0 ? m : 0.0;
    }
    double pos = mm[c];
    bool any = false; double best = 0.0;
    for (int k = 0; k < 5; ++k) {
      if (k == c || meta[k] < 2) continue;
      if (!any || mm[k] < best) { best = mm[k]; any = true; }
    }
    double lc = any ? fmax(pos - best + 0.1, 0.0) : pos;
    double w = sqrt((double)nsf * (double)nqf);
    total += w * lc; vw += w;
  }
  out[0] = (float)(0.1 * total / fmax(vw, 1e-12));
}

// ============================================================================
// host launcher
// ============================================================================
extern "C" void kernel_launch(void* const* d_in, const int* in_sizes, int n_in,
                              void* d_out, int out_size, void* d_ws, size_t ws_size,
                              hipStream_t stream) {
  const float* f_s = (const float*)d_in[0];
  const int*   l_s = (const int*)d_in[1];
  const float* f_q = (const float*)d_in[2];
  const int*   l_q = (const int*)d_in[3];
  float* out = (float*)d_out;
  char* ws = (char*)d_ws;

  size_t off = 0;
  auto take = [&](size_t bytes) -> void* {
    void* p = ws + off;
    off = (off + bytes + 255) & ~(size_t)255;
    return p;
  };
  int*   meta     = (int*)take(32 * 4);
  int*   cnts     = (int*)take(NBLK_C * 4);
  int*   offs     = (int*)take(NBLK_C * 4);
  int*   sup_list = (int*)take((size_t)5 * S_LEN * 4);
  int*   qry_list = (int*)take((size_t)5 * Q_TOT * 4);
  int*   Jsup     = (int*)take((size_t)5 * S_LEN * 4);
  int*   Jqry     = (int*)take((size_t)5 * Q_TOT * 4);
  unsigned int* draws = (unsigned int*)take((10ull * CAPS64 + 10ull * CAPQ64) * 4);
  int*   sel      = (int*)take((size_t)10 * MAXS * 4);
  float* xa       = (float*)take((size_t)5 * 65536 * 4);
  float* xb       = (float*)take((size_t)5 * 65536 * 4);
  float* Ga       = (float*)take((size_t)5 * 65536 * 4);
  float* Gb       = (float*)take((size_t)5 * 65536 * 4);
  float* Gab      = (float*)take((size_t)25 * 65536 * 4);
  float* diagA    = (float*)take((size_t)5 * 256 * 4);
  float* diagB    = (float*)take((size_t)5 * 256 * 4);
  unsigned int* bufAll  = (unsigned int*)take((size_t)MPASSES * 25 * 16 * 4);
  unsigned int* loArr   = (unsigned int*)take((size_t)MPASSES * 25 * 4);
  unsigned int* baseArr = (unsigned int*)take((size_t)MPASSES * 25 * 4);
  unsigned int* zcArr   = (unsigned int*)take(25 * 4);
  double* mmdsum  = (double*)take(25 * 3 * 8);
  if (off > ws_size) return;

  // H (next-hitter) arrays alias the draws buffer — draws dead after k_consume.
  unsigned int* Hsup = draws;
  unsigned int* Hqry = draws + (size_t)5 * S_LEN;
  size_t hbytes = ((size_t)5 * S_LEN + (size_t)5 * Q_TOT) * 4;

  k_draws<<<10, 256, 0, stream>>>(draws);
  k_count<<<NBLK_C, 256, 0, stream>>>(l_s, l_q, cnts);
  k_scan<<<1, 64, 0, stream>>>(cnts, offs, meta);
  k_write<<<NBLK_C, 256, 0, stream>>>(l_s, l_q, offs, sup_list, qry_list);
  k_consume<<<10, 64, 0, stream>>>(meta, draws, Jsup, Jqry);
  hipMemsetAsync(Hsup, 0xFF, hbytes, stream);
  {
    int nblk = 5 * (S_LEN / 256) + 5 * (Q_TOT / 256);   // 320 + 6400
    k_hfill<<<nblk, 256, 0, stream>>>(meta, Jsup, Jqry, Hsup, Hqry);
  }
  k_chase<<<10, 256, 0, stream>>>(meta, sup_list, qry_list, Hsup, Hqry, sel);
  k_gather<<<80, 256, 0, stream>>>(f_s, f_q, meta, sel, xa, xb);
  k_gram<<<35, 1024, 0, stream>>>(xa, xb, Ga, Gb, Gab);
  k_diag<<<10, 256, 0, stream>>>(Ga, Gb, diagA, diagB);
  k_conv<<<280, 256, 0, stream>>>(Ga, Gb, Gab, diagA, diagB);

  hipMemsetAsync(bufAll, 0, (size_t)MPASSES * 25 * 16 * 4, stream);
  hipMemsetAsync(zcArr, 0, 25 * 4, stream);
  hipMemsetAsync(mmdsum, 0, 25 * 3 * 8, stream);
  for (int t = 0; t < MPASSES; ++t)
    k_medpass<<<25 * MSHARDS, 256, 0, stream>>>(t, meta, Ga, Gb, Gab,
                                                bufAll, loArr, baseArr, zcArr);
  k_rbf<<<25 * MSHARDS, 256, 0, stream>>>(meta, Ga, Gb, Gab,
                                          bufAll, loArr, baseArr, zcArr, mmdsum);
  k_final<<<1, 64, 0, stream>>>(meta, mmdsum, out);
}

// Round 8
// 1233.687 us; speedup vs baseline: 11.1014x; 1.0540x over previous
//
#include <hip/hip_runtime.h>

// ============================================================================
// numpy RNG replication: SeedSequence + PCG64 (XSL-RR 128/64), next32 buffering
// ============================================================================
struct U128 { unsigned long long hi, lo; };

__device__ __forceinline__ U128 u128_mul(U128 a, U128 b) {
  U128 r;
  r.lo = a.lo * b.lo;
  r.hi = __umul64hi(a.lo, b.lo) + a.hi * b.lo + a.lo * b.hi;
  return r;
}
__device__ __forceinline__ U128 u128_add(U128 a, U128 b) {
  U128 r; r.lo = a.lo + b.lo; r.hi = a.hi + b.hi + (r.lo < a.lo ? 1ull : 0ull); return r;
}

struct Pcg64 {
  U128 state, inc;
};

__device__ __forceinline__ void pcg_step(Pcg64* r) {
  const U128 M = {0x2360ed051fc65da4ull, 0x4385df649fccf645ull};
  r->state = u128_add(u128_mul(r->state, M), r->inc);
}
__device__ __forceinline__ unsigned long long pcg_next64(Pcg64* r) {
  pcg_step(r);
  unsigned int rot = (unsigned int)(r->state.hi >> 58);   // state >> 122
  unsigned long long x = r->state.hi ^ r->state.lo;       // XSL
  return (x >> rot) | (x << ((64u - rot) & 63u));         // RR
}

// SeedSequence constants (numpy bit_generator.pyx)
__device__ __forceinline__ unsigned int ss_hashmix(unsigned int v, unsigned int* hc) {
  v ^= *hc; *hc = *hc * 0x931e8875u; v *= *hc; v ^= v >> 16; return v;
}
__device__ __forceinline__ unsigned int ss_mix(unsigned int x, unsigned int y) {
  unsigned int r = x * 0xca01f9ddu ^ y * 0x4973f715u; r ^= r >> 16; return r;
}
__device__ void pcg_seed(Pcg64* rng, unsigned int seed) {
  unsigned int pool[4]; unsigned int hc = 0x43b0d7e5u;   // INIT_A
  pool[0] = ss_hashmix(seed, &hc);
  for (int i = 1; i < 4; ++i) pool[i] = ss_hashmix(0u, &hc);
  for (int s = 0; s < 4; ++s)
    for (int d = 0; d < 4; ++d)
      if (s != d) pool[d] = ss_mix(pool[d], ss_hashmix(pool[s], &hc));
  unsigned int hc2 = 0x8b51f9ddu;                        // INIT_B
  unsigned long long w64[4];
  for (int i = 0; i < 4; ++i) {
    unsigned int lo = pool[(2*i) & 3];
    lo ^= hc2; hc2 *= 0x58f38dedu; lo *= hc2; lo ^= lo >> 16;
    unsigned int hi = pool[(2*i+1) & 3];
    hi ^= hc2; hc2 *= 0x58f38dedu; hi *= hc2; hi ^= hi >> 16;
    w64[i] = (unsigned long long)lo | ((unsigned long long)hi << 32);
  }
  U128 initstate = {w64[0], w64[1]};   // PCG_128BIT_CONSTANT(seed[0], seed[1]): [0] is HIGH
  U128 initseq   = {w64[2], w64[3]};
  rng->inc.hi = (initseq.hi << 1) | (initseq.lo >> 63);
  rng->inc.lo = (initseq.lo << 1) | 1ull;
  rng->state.hi = 0; rng->state.lo = 0;
  pcg_step(rng);
  rng->state = u128_add(rng->state, initstate);
  pcg_step(rng);
}

// affine jump-ahead: state <- A^delta * state + (A^delta-1)/(A-1)*inc
__device__ void pcg_advance(Pcg64* r, unsigned long long delta) {
  U128 acc_mult = {0ull, 1ull}, acc_plus = {0ull, 0ull};
  U128 cur_mult = {0x2360ed051fc65da4ull, 0x4385df649fccf645ull};
  U128 cur_plus = r->inc;
  while (delta) {
    if (delta & 1ull) {
      acc_mult = u128_mul(acc_mult, cur_mult);
      acc_plus = u128_add(u128_mul(acc_plus, cur_mult), cur_plus);
    }
    U128 one = {0ull, 1ull};
    U128 cm1 = u128_add(cur_mult, one);
    cur_plus = u128_mul(cm1, cur_plus);
    cur_mult = u128_mul(cur_mult, cur_mult);
    delta >>= 1;
  }
  r->state = u128_add(u128_mul(r->state, acc_mult), acc_plus);
}

// ============================================================================
// Problem constants
// ============================================================================
#define S_LEN   16384
#define Q_LEN   65536
#define Q_TOT   327680     // 5*65536
#define DFEAT   256
#define MAXS    256
#define CAPS64  24576
#define CAPQ64  98304
#define TILE    4096
#define STILES  (S_LEN / TILE)    // 4
#define QTILES  (Q_TOT / TILE)    // 80
#define NBLK_C  (5 * STILES + 5 * QTILES)   // 420
#define MSHARDS 8
#define MPASSES 8

// meta layout: [0..4]=ns_full, [5..9]=nq_full, [10..14]=na, [15..19]=nb

__constant__ int c_kshift[MPASSES] = {27, 23, 19, 15, 11, 7, 3, 0};

// ============================================================================
// K0: parallel draw-stream generation (exact numpy next32 sequence, lo first)
// ============================================================================
__global__ __launch_bounds__(256) void k_draws(unsigned int* __restrict__ draws) {
  int t = blockIdx.x; int cls = t % 5; int isq = t / 5;
  unsigned int seed = (unsigned)(1000 + isq * 1000 + cls + 1);
  unsigned long long cap64 = isq ? CAPQ64 : CAPS64;
  unsigned int* dst = draws + (isq ? (10ull * CAPS64 + (unsigned long long)cls * 2 * CAPQ64)
                                   : ((unsigned long long)cls * 2 * CAPS64));
  Pcg64 rng; pcg_seed(&rng, seed);
  int tid = threadIdx.x;
  unsigned long long C = cap64 / 256ull;     // 96 or 384
  unsigned long long k0 = (unsigned long long)tid * C;
  pcg_advance(&rng, k0);
  uint2* d2 = (uint2*)dst;
  for (unsigned long long m = 0; m < C; ++m) {
    unsigned long long o = pcg_next64(&rng);
    d2[k0 + m] = make_uint2((unsigned int)o, (unsigned int)(o >> 32));
  }
}

// ============================================================================
// K1a: per-tile match counts
// ============================================================================
__global__ __launch_bounds__(256) void k_count(const int* __restrict__ ls,
                                               const int* __restrict__ lq,
                                               int* __restrict__ cnts) {
  int b = blockIdx.x;
  const int* src; int matchval;
  if (b < 5 * STILES) {
    int cls = b / STILES, tl = b % STILES;
    src = ls + cls * S_LEN + tl * TILE; matchval = 1;
  } else {
    int bb = b - 5 * STILES; int cls = bb / QTILES, tl = bb % QTILES;
    src = lq + tl * TILE; matchval = cls + 1;
  }
  int tid = threadIdx.x;
  int cnt = 0;
  for (int k = 0; k < TILE; k += 256) cnt += (src[k + tid] == matchval) ? 1 : 0;
  __shared__ int red[256];
  red[tid] = cnt; __syncthreads();
  for (int s = 128; s > 0; s >>= 1) { if (tid < s) red[tid] += red[tid + s]; __syncthreads(); }
  if (tid == 0) cnts[b] = red[0];
}

// ============================================================================
// K1b: tiny scan: exclusive offsets per class + meta totals
// ============================================================================
__global__ void k_scan(const int* __restrict__ cnts, int* __restrict__ offs,
                       int* __restrict__ meta) {
  int t = threadIdx.x;
  if (t < 5) {
    int base = 0;
    for (int k = 0; k < STILES; ++k) {
      offs[t * STILES + k] = base; base += cnts[t * STILES + k];
    }
    meta[t] = base;
    meta[10 + t] = base < MAXS ? base : MAXS;
  } else if (t < 10) {
    int c = t - 5; int base = 0;
    for (int k = 0; k < QTILES; ++k) {
      int idx = 5 * STILES + c * QTILES + k;
      offs[idx] = base; base += cnts[idx];
    }
    meta[5 + c] = base;
    meta[15 + c] = base < MAXS ? base : MAXS;
  }
}

// ============================================================================
// K1c: stable compaction write at per-tile offsets (4-wave ballot prefix)
// ============================================================================
__global__ __launch_bounds__(256) void k_write(const int* __restrict__ ls,
                                               const int* __restrict__ lq,
                                               const int* __restrict__ offs,
                                               int* __restrict__ sup_list,
                                               int* __restrict__ qry_list) {
  int b = blockIdx.x;
  const int* src; int matchval; int* out; int ibase;
  if (b < 5 * STILES) {
    int cls = b / STILES, tl = b % STILES;
    src = ls + cls * S_LEN + tl * TILE; matchval = 1;
    out = sup_list + cls * S_LEN; ibase = tl * TILE;
  } else {
    int bb = b - 5 * STILES; int cls = bb / QTILES, tl = bb % QTILES;
    src = lq + tl * TILE; matchval = cls + 1;
    out = qry_list + (size_t)cls * Q_TOT; ibase = tl * TILE;
  }
  int tid = threadIdx.x; int w = tid >> 6, lane = tid & 63;
  unsigned long long lmask = (1ull << lane) - 1ull;
  __shared__ int wcnt[4];
  int base = offs[b];
  for (int k = 0; k < TILE; k += 256) {
    int i = k + tid;
    bool p = (src[i] == matchval);
    unsigned long long m = __ballot(p);
    if (lane == 0) wcnt[w] = __popcll(m);
    __syncthreads();
    int prev = 0;
    #pragma unroll
    for (int ww = 0; ww < 4; ++ww) prev += (ww < w) ? wcnt[ww] : 0;
    int tot = wcnt[0] + wcnt[1] + wcnt[2] + wcnt[3];
    if (p) out[base + prev + __popcll(m & lmask)] = ibase + i;
    __syncthreads();
    base += tot;
  }
}

// ============================================================================
// K2: wave-parallel masked-rejection automaton, INTERVAL-COMMIT resolution.
//     Depth-3 register prefetch (consumption is exactly 64 draws/chunk, so
//     prefetch addresses are deterministic).  Fast path: one round with TWO
//     ballots — nr = ballot(def_rej), hd = ballot(hard); accepts commit as
//     unc & ~nr & ~hd (no accept ballot, no confirmation round).  Progress:
//     lowest hard lane has ubelow==0 next round -> exact resolve.
// ============================================================================
__global__ __launch_bounds__(64) void k_consume(const int* __restrict__ meta,
                                                const unsigned int* __restrict__ draws,
                                                int* Jsup, int* Jqry) {
  int t = blockIdx.x; int cls = t % 5; int isq = t / 5;
  int n = meta[isq * 5 + cls];
  if (n <= MAXS) return;
  const unsigned int* d = draws + (isq ? (10ull * CAPS64 + (unsigned long long)cls * 2 * CAPQ64)
                                       : ((unsigned long long)cls * 2 * CAPS64));
  int* J = isq ? (Jqry + (size_t)cls * Q_TOT) : (Jsup + cls * S_LEN);
  int lane = threadIdx.x;
  unsigned long long lmask = (1ull << lane) - 1ull;
  unsigned long long lbit  = (1ull << lane);
  int i = n - 1;
  size_t p = 0;
  unsigned int v   = d[lane];
  unsigned int vn1 = d[64 + lane];
  unsigned int vn2 = d[128 + lane];
  unsigned int vn3 = d[192 + lane];
  for (;;) {
    unsigned int vfar = d[p + 256 + lane];     // 3-deep prefetch, in flight
    unsigned long long rej = 0ull, acc = 0ull;
    for (;;) {
      unsigned long long unc = ~(rej | acc);
      int rbelow = __popcll(rej & lmask);
      int ubelow = __popcll(unc & lmask);
      int il_min = i - lane + rbelow;          // >= 193 always
      int il_max = il_min + ubelow;
      bool unres = (unc & lbit) != 0ull;
      unsigned int mlo = 0xFFFFFFFFu >> __clz(il_min);
      unsigned int mhi = 0xFFFFFFFFu >> __clz(il_max);
      unsigned int w = v & mlo;
      bool def_rej, hard;
      if (mlo == mhi) {
        def_rej = w > (unsigned int)il_max;
        hard = !def_rej && (w > (unsigned int)il_min);   // middle band
      } else if (ubelow == 0) {                // octave boundary: exact resolve
        def_rej = w > (unsigned int)il_min;
        hard = false;
      } else {
        def_rej = false;
        hard = true;                           // boundary-spanning, wait
      }
      def_rej = def_rej && unres;
      hard = hard && unres;
      unsigned long long nr = __ballot(def_rej);
      unsigned long long hd = __ballot(hard);
      rej |= nr;
      acc |= unc & ~nr & ~hd;
      if (!hd) break;
    }
    int rbelow = __popcll(rej & lmask);
    int il = i - lane + rbelow;
    int totAcc = 64 - __popcll(rej);
    if ((acc & lbit) && il >= MAXS)
      J[il] = (int)(v & (0xFFFFFFFFu >> __clz(il)));
    int needed = i - (MAXS - 1);
    if (totAcc >= needed) break;
    i -= totAcc; p += 64;
    v = vn1; vn1 = vn2; vn2 = vn3; vn3 = vfar;
  }
}

// ============================================================================
// K3a: next-hitter index fill.  H[v] = min{ i > v, i in [256,n) : J[i] == v }
// ============================================================================
__global__ __launch_bounds__(256) void k_hfill(const int* __restrict__ meta,
                                               const int* __restrict__ Jsup,
                                               const int* __restrict__ Jqry,
                                               unsigned int* __restrict__ Hsup,
                                               unsigned int* __restrict__ Hqry) {
  const int SB = 5 * (S_LEN / 256);
  int b = blockIdx.x;
  int cls, i; const int* J; unsigned int* H; int n;
  if (b < SB) {
    cls = b / (S_LEN / 256);
    i = (b % (S_LEN / 256)) * 256 + threadIdx.x;
    n = meta[cls];
    J = Jsup + cls * S_LEN; H = Hsup + cls * S_LEN;
  } else {
    b -= SB;
    cls = b / (Q_TOT / 256);
    i = (b % (Q_TOT / 256)) * 256 + threadIdx.x;
    n = meta[5 + cls];
    J = Jqry + (size_t)cls * Q_TOT; H = Hqry + (size_t)cls * Q_TOT;
  }
  if (i < MAXS || i >= n) return;
  int j = J[i];
  if (j != i) atomicMin(&H[j], (unsigned int)i);
}

// ============================================================================
// K3b: chase.  sel[t][s] = list[ c(s) ]
// ============================================================================
__global__ __launch_bounds__(256) void k_chase(const int* __restrict__ meta,
                                               const int* __restrict__ sup_list,
                                               const int* __restrict__ qry_list,
                                               const unsigned int* __restrict__ Hsup,
                                               const unsigned int* __restrict__ Hqry,
                                               int* sel) {
  int t = blockIdx.x; int tid = threadIdx.x;
  int cls = t % 5; int isq = t / 5;
  int n = meta[isq * 5 + cls];
  const int* list; const unsigned int* H;
  if (!isq) { list = sup_list + cls * S_LEN; H = Hsup + cls * S_LEN; }
  else      { list = qry_list + (size_t)cls * Q_TOT; H = Hqry + (size_t)cls * Q_TOT; }
  int* s = sel + t * MAXS;
  if (n <= MAXS) { if (tid < n) s[tid] = list[tid]; return; }
  unsigned int v = (unsigned int)tid;
  unsigned int h = H[v];
  while (h != 0xFFFFFFFFu) { v = h; h = H[v]; }
  s[tid] = list[v];
}

// ============================================================================
// K4: gather selected feature rows + fused row-norm (x / (||x|| + 1e-12)).
// ============================================================================
__global__ __launch_bounds__(256) void k_gather(const float* __restrict__ f_s,
                                                const float* __restrict__ f_q,
                                                const int* __restrict__ meta,
                                                const int* __restrict__ sel,
                                                float* xa, float* xb) {
  int blk = blockIdx.x;
  int t = blk >> 3;          // class-pair 0..9
  int slab = blk & 7;        // 8 slabs x 32 rows
  int cls = t % 5; int isq = t / 5;
  int n = meta[10 + isq * 5 + cls];
  int tid = threadIdx.x;
  int row = slab * 32 + (tid >> 3);
  int dg = tid & 7;          // 8 d-groups of 32
  if (row >= n) return;      // group-uniform (8 lanes share row)
  int id = sel[t * MAXS + row];
  const float* src; size_t stride; float* dst;
  if (!isq) {
    src = f_s + (size_t)cls * DFEAT * S_LEN + id; stride = S_LEN;
    dst = xa + cls * (MAXS * DFEAT) + row * DFEAT;
  } else {
    int m = id >> 16; int nn = id & 0xFFFF;
    src = f_q + (size_t)m * DFEAT * Q_LEN + nn; stride = Q_LEN;
    dst = xb + cls * (MAXS * DFEAT) + row * DFEAT;
  }
  float v[32];
  #pragma unroll
  for (int dd = 0; dd < 32; ++dd)
    v[dd] = src[(size_t)(dg * 32 + dd) * stride];
  float ss = 0.f;
  #pragma unroll
  for (int dd = 0; dd < 32; ++dd) ss += v[dd] * v[dd];
  ss += __shfl_xor(ss, 1);
  ss += __shfl_xor(ss, 2);
  ss += __shfl_xor(ss, 4);
  float inv = 1.0f / (sqrtf(ss) + 1e-12f);
  #pragma unroll
  for (int dd = 0; dd < 32; ++dd) dst[dg * 32 + dd] = v[dd] * inv;
}

// ============================================================================
// K5: 35 Gram matrices (256x256, K=256)
// ============================================================================
__global__ __launch_bounds__(1024) void k_gram(const float* __restrict__ xa,
                                               const float* __restrict__ xb,
                                               float* Ga, float* Gb, float* Gab) {
  int j = blockIdx.x;
  const float *A, *B; float* G;
  if (j < 5)       { A = xa + j * 65536; B = A; G = Ga + j * 65536; }
  else if (j < 10) { int c = j - 5; A = xb + c * 65536; B = A; G = Gb + c * 65536; }
  else             { int p = j - 10; int k = p / 5, c = p % 5;
                     A = xa + k * 65536; B = xb + c * 65536; G = Gab + p * 65536; }
  __shared__ float As[256][17];
  __shared__ float Bs[256][17];
  int tid = threadIdx.x;
  int ti = tid >> 5, tj = tid & 31;
  float acc[8][8];
  #pragma unroll
  for (int r = 0; r < 8; ++r)
    #pragma unroll
    for (int s = 0; s < 8; ++s) acc[r][s] = 0.f;
  for (int k0 = 0; k0 < 256; k0 += 16) {
    #pragma unroll
    for (int e = 0; e < 4; ++e) {
      int idx = tid + e * 1024;
      int i = idx >> 4, kk = idx & 15;
      As[i][kk] = A[i * 256 + k0 + kk];
      Bs[i][kk] = B[i * 256 + k0 + kk];
    }
    __syncthreads();
    #pragma unroll
    for (int kk = 0; kk < 16; ++kk) {
      float a[8], b[8];
      #pragma unroll
      for (int r = 0; r < 8; ++r) a[r] = As[ti * 8 + r][kk];
      #pragma unroll
      for (int s = 0; s < 8; ++s) b[s] = Bs[tj * 8 + s][kk];
      #pragma unroll
      for (int r = 0; r < 8; ++r)
        #pragma unroll
        for (int s = 0; s < 8; ++s) acc[r][s] += a[r] * b[s];
    }
    __syncthreads();
  }
  #pragma unroll
  for (int r = 0; r < 8; ++r)
    #pragma unroll
    for (int s = 0; s < 8; ++s)
      G[(ti * 8 + r) * 256 + tj * 8 + s] = acc[r][s];
}

// ============================================================================
// K6: extract Gram diagonals
// ============================================================================
__global__ __launch_bounds__(256) void k_diag(const float* __restrict__ Ga,
                                              const float* __restrict__ Gb,
                                              float* diagA, float* diagB) {
  int t = blockIdx.x; int i = threadIdx.x;
  if (t < 5) diagA[t * 256 + i] = Ga[t * 65536 + i * 257];
  else { int c = t - 5; diagB[c * 256 + i] = Gb[c * 65536 + i * 257]; }
}

// ============================================================================
// K7: G -> D in place (280 blocks: 35 matrices x 8 row-slabs)
// ============================================================================
__global__ __launch_bounds__(256) void k_conv(float* Ga, float* Gb, float* Gab,
                                              const float* __restrict__ diagA,
                                              const float* __restrict__ diagB) {
  int b = blockIdx.x; int j = b >> 3; int slab = b & 7; int tid = threadIdx.x;
  float* G; const float *dA, *dB;
  if (j < 5)       { G = Ga + j * 65536; dA = diagA + j * 256; dB = dA; }
  else if (j < 10) { int c = j - 5; G = Gb + c * 65536; dA = diagB + c * 256; dB = dA; }
  else             { int p = j - 10; int k = p / 5, c = p % 5;
                     G = Gab + p * 65536; dA = diagA + k * 256; dB = diagB + c * 256; }
  float db = dB[tid];
  for (int i = slab * 32; i < slab * 32 + 32; ++i) {
    float g = G[i * 256 + tid];
    float d = dA[i] + db - 2.0f * g;
    G[i * 256 + tid] = d > 0.f ? d : 0.f;
  }
}

// ============================================================================
// K8: grid-parallel 16-ary exact radix-select, one kernel per pass.
// ============================================================================
__device__ __forceinline__ void med_select(const unsigned int* __restrict__ c,
                                           unsigned int lprev, unsigned int bprev,
                                           unsigned int r, int kprev,
                                           unsigned int* lo, unsigned int* base) {
  int j = 15;
  #pragma unroll
  for (int q = 14; q >= 0; --q)
    if (bprev + c[q] > r) j = q;
  *lo = lprev + ((unsigned int)j << kprev);
  *base = (j == 0) ? bprev : bprev + c[j - 1];
}

__global__ __launch_bounds__(256) void k_medpass(int t,
                                                 const int* __restrict__ meta,
                                                 const float* __restrict__ Da_all,
                                                 const float* __restrict__ Db_all,
                                                 const float* __restrict__ Dab_all,
                                                 unsigned int* __restrict__ bufAll,  // [MPASSES][25][16]
                                                 unsigned int* __restrict__ loArr,   // [MPASSES][25]
                                                 unsigned int* __restrict__ baseArr, // [MPASSES][25]
                                                 unsigned int* __restrict__ zcArr) { // [25]
  int b = blockIdx.x;
  int p = b / MSHARDS, sh = b % MSHARDS;
  int kcl = p / 5, ccl = p % 5;
  int tid = threadIdx.x;
  int nsf = meta[kcl], nqf = meta[5 + ccl];
  if (nsf < 2 || nqf < 2) return;
  int na = meta[10 + kcl], nb = meta[15 + ccl];
  const float4* A4 = (const float4*)(Da_all + kcl * 65536);
  const float4* B4 = (const float4*)(Db_all + ccl * 65536);
  const float4* C4 = (const float4*)(Dab_all + p * 65536);

  __shared__ unsigned int sh_lo[1], sh_base[1];
  __shared__ unsigned int wred[4][16];
  __shared__ unsigned int wzc[4];

  int ks = c_kshift[t];
  unsigned int N = (unsigned int)(na + nb) * (unsigned int)(na + nb);

  if (tid == 0) {
    unsigned int lo = 0, base = 0;
    if (t > 0) {
      unsigned int nz = zcArr[p];
      if (nz < N) {
        unsigned int r = nz + (N - nz - 1u) / 2u;
        unsigned int cprev[15];
        const unsigned int* cp = bufAll + ((size_t)(t - 1) * 25 + p) * 16;
        #pragma unroll
        for (int q = 0; q < 15; ++q) cprev[q] = cp[q];
        med_select(cprev, loArr[(t - 1) * 25 + p], baseArr[(t - 1) * 25 + p],
                   r, c_kshift[t - 1], &lo, &base);
      }
    }
    sh_lo[0] = lo; sh_base[0] = base;
    if (sh == 0) { loArr[t * 25 + p] = lo; baseArr[t * 25 + p] = base; }
  }
  __syncthreads();
  unsigned int lo = sh_lo[0];

  unsigned int cnt[15];
  #pragma unroll
  for (int j = 0; j < 15; ++j) cnt[j] = 0;
  unsigned int zc = 0;
  unsigned int span = 16u << ks;   // ks<=27 -> fits u32 (16<<27 = 2^31)

  #define PROC_MAT(M4, nr, nc, W)                                             \
    for (int m = 0; m < 8; ++m) {                                             \
      int fidx = sh * 2048 + m * 256 + tid;                                   \
      float4 v = M4[fidx];                                                    \
      int row = fidx >> 6; int col0 = (fidx & 63) << 2;                       \
      unsigned int kb[4] = {__float_as_uint(v.x), __float_as_uint(v.y),       \
                            __float_as_uint(v.z), __float_as_uint(v.w)};      \
      _Pragma("unroll")                                                       \
      for (int cc = 0; cc < 4; ++cc) {                                        \
        bool valid = (row < (nr)) && (col0 + cc < (nc));                      \
        unsigned int key = kb[cc];                                            \
        if (t == 0) zc += (valid && key == 0u) ? (W) : 0u;                    \
        unsigned int d = key - lo;                                            \
        bool in = valid && (key >= lo) && (d < span);                         \
        _Pragma("unroll")                                                     \
        for (int j = 0; j < 15; ++j)                                          \
          cnt[j] += (in && d < ((unsigned int)(j + 1) << ks)) ? (W) : 0u;     \
      }                                                                       \
    }

  PROC_MAT(A4, na, na, 1u)
  PROC_MAT(B4, nb, nb, 1u)
  PROC_MAT(C4, na, nb, 2u)
  #undef PROC_MAT

  // wave-level reduce then cross-wave
  #pragma unroll
  for (int j = 0; j < 15; ++j)
    for (int o = 32; o > 0; o >>= 1) cnt[j] += __shfl_down(cnt[j], o);
  if (t == 0)
    for (int o = 32; o > 0; o >>= 1) zc += __shfl_down(zc, o);
  int w = tid >> 6, lane = tid & 63;
  if (lane == 0) {
    #pragma unroll
    for (int j = 0; j < 15; ++j) wred[w][j] = cnt[j];
    wzc[w] = zc;
  }
  __syncthreads();
  if (tid < 15) {
    unsigned int s = wred[0][tid] + wred[1][tid] + wred[2][tid] + wred[3][tid];
    atomicAdd(&bufAll[((size_t)t * 25 + p) * 16 + tid], s);
  }
  if (t == 0 && tid == 15) {
    unsigned int s = wzc[0] + wzc[1] + wzc[2] + wzc[3];
    atomicAdd(&zcArr[p], s);
  }
}

// ============================================================================
// K8b: RBF partial sums (200 blocks), sigma from final select
// ============================================================================
__global__ __launch_bounds__(256) void k_rbf(const int* __restrict__ meta,
                                             const float* __restrict__ Da_all,
                                             const float* __restrict__ Db_all,
                                             const float* __restrict__ Dab_all,
                                             const unsigned int* __restrict__ bufAll,
                                             const unsigned int* __restrict__ loArr,
                                             const unsigned int* __restrict__ baseArr,
                                             const unsigned int* __restrict__ zcArr,
                                             double* __restrict__ mmdsum) { // [25][3]
  int b = blockIdx.x;
  int p = b / MSHARDS, sh = b % MSHARDS;
  int kcl = p / 5, ccl = p % 5;
  int tid = threadIdx.x;
  int nsf = meta[kcl], nqf = meta[5 + ccl];
  if (nsf < 2 || nqf < 2) return;
  int na = meta[10 + kcl], nb = meta[15 + ccl];
  const float4* A4 = (const float4*)(Da_all + kcl * 65536);
  const float4* B4 = (const float4*)(Db_all + ccl * 65536);
  const float4* C4 = (const float4*)(Dab_all + p * 65536);

  unsigned int N = (unsigned int)(na + nb) * (unsigned int)(na + nb);
  unsigned int nz = zcArr[p];
  float base_s;
  if (nz >= N) base_s = 1.0f;
  else {
    unsigned int r = nz + (N - nz - 1u) / 2u;
    unsigned int cprev[15];
    const unsigned int* cp = bufAll + ((size_t)(MPASSES - 1) * 25 + p) * 16;
    #pragma unroll
    for (int q = 0; q < 15; ++q) cprev[q] = cp[q];
    unsigned int lo, bs;
    med_select(cprev, loArr[(MPASSES - 1) * 25 + p], baseArr[(MPASSES - 1) * 25 + p],
               r, 0, &lo, &bs);
    base_s = sqrtf(__uint_as_float(lo) + 1e-6f);
  }
  float g2 = base_s * base_s;
  float c0 = 1.0f / (2.0f * g2 * 0.25f);
  float c1 = 1.0f / (2.0f * g2 * 1.0f);
  float c2 = 1.0f / (2.0f * g2 * 4.0f);
  float c3 = 1.0f / (2.0f * g2 * 16.0f);

  double accA = 0.0, accB = 0.0, accAB = 0.0;
  #define RBF_MAT(M4, nr, nc, ACC)                                            \
    for (int m = 0; m < 8; ++m) {                                             \
      int fidx = sh * 2048 + m * 256 + tid;                                   \
      float4 v = M4[fidx];                                                    \
      int row = fidx >> 6; int col0 = (fidx & 63) << 2;                       \
      float vv[4] = {v.x, v.y, v.z, v.w};                                     \
      _Pragma("unroll")                                                       \
      for (int cc = 0; cc < 4; ++cc) {                                        \
        if ((row < (nr)) && (col0 + cc < (nc))) {                             \
          float d = vv[cc];                                                   \
          ACC += (double)(expf(-d * c0) + expf(-d * c1)                       \
                        + expf(-d * c2) + expf(-d * c3));                     \
        }                                                                     \
      }                                                                       \
    }
  RBF_MAT(A4, na, na, accA)
  RBF_MAT(B4, nb, nb, accB)
  RBF_MAT(C4, na, nb, accAB)
  #undef RBF_MAT

  for (int o = 32; o > 0; o >>= 1) {
    accA += __shfl_down(accA, o);
    accB += __shfl_down(accB, o);
    accAB += __shfl_down(accAB, o);
  }
  __shared__ double wsum[4][3];
  int w = tid >> 6, lane = tid & 63;
  if (lane == 0) { wsum[w][0] = accA; wsum[w][1] = accB; wsum[w][2] = accAB; }
  __syncthreads();
  if (tid == 0) {
    double sA = wsum[0][0] + wsum[1][0] + wsum[2][0] + wsum[3][0];
    double sB = wsum[0][1] + wsum[1][1] + wsum[2][1] + wsum[3][1];
    double sC = wsum[0][2] + wsum[1][2] + wsum[2][2] + wsum[3][2];
    atomicAdd(&mmdsum[p * 3 + 0], sA);
    atomicAdd(&mmdsum[p * 3 + 1], sB);
    atomicAdd(&mmdsum[p * 3 + 2], sC);
  }
}

// ============================================================================
// K9: final weighted loss (mmd assembled from sums)
// ============================================================================
__global__ void k_final(const int* __restrict__ meta, const double* __restrict__ mmdsum,
                        float* out) {
  if (threadIdx.x != 0 || blockIdx.x != 0) return;
  double total = 0.0, vw = 0.0;
  for (int c = 0; c < 5; ++c) {
    int nsf = meta[c], nqf = meta[5 + c];
    if (nsf < 2 || nqf < 2) continue;
    int nbq = meta[15 + c];
    double mm[5];
    for (int k = 0; k < 5; ++k) {
      if (meta[k] < 2) { mm[k] = 0.0; continue; }
      int naa = meta[10 + k];
      int pp = k * 5 + c;
      double meanA  = mmdsum[pp * 3 + 0] / ((double)naa * (double)naa);
      double meanB  = mmdsum[pp * 3 + 1] / ((double)nbq * (double)nbq);
      double meanAB = mmdsum[pp * 3 + 2] / ((double)naa * (double)nbq);
      double m = meanA + meanB - 2.0 * meanAB;
      mm[k] = m > 0.0 ? m : 0.0;
    }
    double pos = mm[c];
    bool any = false; double best = 0.0;
    for (int k = 0; k < 5; ++k) {
      if (k == c || meta[k] < 2) continue;
      if (!any || mm[k] < best) { best = mm[k]; any = true; }
    }
    double lc = any ? fmax(pos - best + 0.1, 0.0) : pos;
    double w = sqrt((double)nsf * (double)nqf);
    total += w * lc; vw += w;
  }
  out[0] = (float)(0.1 * total / fmax(vw, 1e-12));
}

// ============================================================================
// host launcher
// ============================================================================
extern "C" void kernel_launch(void* const* d_in, const int* in_sizes, int n_in,
                              void* d_out, int out_size, void* d_ws, size_t ws_size,
                              hipStream_t stream) {
  const float* f_s = (const float*)d_in[0];
  const int*   l_s = (const int*)d_in[1];
  const float* f_q = (const float*)d_in[2];
  const int*   l_q = (const int*)d_in[3];
  float* out = (float*)d_out;
  char* ws = (char*)d_ws;

  size_t off = 0;
  auto take = [&](size_t bytes) -> void* {
    void* p = ws + off;
    off = (off + bytes + 255) & ~(size_t)255;
    return p;
  };
  int*   meta     = (int*)take(32 * 4);
  int*   cnts     = (int*)take(NBLK_C * 4);
  int*   offs     = (int*)take(NBLK_C * 4);
  int*   sup_list = (int*)take((size_t)5 * S_LEN * 4);
  int*   qry_list = (int*)take((size_t)5 * Q_TOT * 4);
  int*   Jsup     = (int*)take((size_t)5 * S_LEN * 4);
  int*   Jqry     = (int*)take((size_t)5 * Q_TOT * 4);
  unsigned int* draws = (unsigned int*)take((10ull * CAPS64 + 10ull * CAPQ64) * 4);
  int*   sel      = (int*)take((size_t)10 * MAXS * 4);
  float* xa       = (float*)take((size_t)5 * 65536 * 4);
  float* xb       = (float*)take((size_t)5 * 65536 * 4);
  float* Ga       = (float*)take((size_t)5 * 65536 * 4);
  float* Gb       = (float*)take((size_t)5 * 65536 * 4);
  float* Gab      = (float*)take((size_t)25 * 65536 * 4);
  float* diagA    = (float*)take((size_t)5 * 256 * 4);
  float* diagB    = (float*)take((size_t)5 * 256 * 4);
  unsigned int* bufAll  = (unsigned int*)take((size_t)MPASSES * 25 * 16 * 4);
  unsigned int* loArr   = (unsigned int*)take((size_t)MPASSES * 25 * 4);
  unsigned int* baseArr = (unsigned int*)take((size_t)MPASSES * 25 * 4);
  unsigned int* zcArr   = (unsigned int*)take(25 * 4);
  double* mmdsum  = (double*)take(25 * 3 * 8);
  if (off > ws_size) return;

  // H (next-hitter) arrays alias the draws buffer — draws dead after k_consume.
  unsigned int* Hsup = draws;
  unsigned int* Hqry = draws + (size_t)5 * S_LEN;
  size_t hbytes = ((size_t)5 * S_LEN + (size_t)5 * Q_TOT) * 4;

  k_draws<<<10, 256, 0, stream>>>(draws);
  k_count<<<NBLK_C, 256, 0, stream>>>(l_s, l_q, cnts);
  k_scan<<<1, 64, 0, stream>>>(cnts, offs, meta);
  k_write<<<NBLK_C, 256, 0, stream>>>(l_s, l_q, offs, sup_list, qry_list);
  k_consume<<<10, 64, 0, stream>>>(meta, draws, Jsup, Jqry);
  hipMemsetAsync(Hsup, 0xFF, hbytes, stream);
  {
    int nblk = 5 * (S_LEN / 256) + 5 * (Q_TOT / 256);   // 320 + 6400
    k_hfill<<<nblk, 256, 0, stream>>>(meta, Jsup, Jqry, Hsup, Hqry);
  }
  k_chase<<<10, 256, 0, stream>>>(meta, sup_list, qry_list, Hsup, Hqry, sel);
  k_gather<<<80, 256, 0, stream>>>(f_s, f_q, meta, sel, xa, xb);
  k_gram<<<35, 1024, 0, stream>>>(xa, xb, Ga, Gb, Gab);
  k_diag<<<10, 256, 0, stream>>>(Ga, Gb, diagA, diagB);
  k_conv<<<280, 256, 0, stream>>>(Ga, Gb, Gab, diagA, diagB);

  hipMemsetAsync(bufAll, 0, (size_t)MPASSES * 25 * 16 * 4, stream);
  hipMemsetAsync(zcArr, 0, 25 * 4, stream);
  hipMemsetAsync(mmdsum, 0, 25 * 3 * 8, stream);
  for (int t = 0; t < MPASSES; ++t)
    k_medpass<<<25 * MSHARDS, 256, 0, stream>>>(t, meta, Ga, Gb, Gab,
                                                bufAll, loArr, baseArr, zcArr);
  k_rbf<<<25 * MSHARDS, 256, 0, stream>>>(meta, Ga, Gb, Gab,
                                          bufAll, loArr, baseArr, zcArr, mmdsum);
  k_final<<<1, 64, 0, stream>>>(meta, mmdsum, out);
}

// Round 9
// 835.018 us; speedup vs baseline: 16.4016x; 1.4774x over previous
//
#include <hip/hip_runtime.h>

// ============================================================================
// numpy RNG replication: SeedSequence + PCG64 (XSL-RR 128/64), next32 buffering
// ============================================================================
struct U128 { unsigned long long hi, lo; };

__device__ __forceinline__ U128 u128_mul(U128 a, U128 b) {
  U128 r;
  r.lo = a.lo * b.lo;
  r.hi = __umul64hi(a.lo, b.lo) + a.hi * b.lo + a.lo * b.hi;
  return r;
}
__device__ __forceinline__ U128 u128_add(U128 a, U128 b) {
  U128 r; r.lo = a.lo + b.lo; r.hi = a.hi + b.hi + (r.lo < a.lo ? 1ull : 0ull); return r;
}

struct Pcg64 {
  U128 state, inc;
};

__device__ __forceinline__ void pcg_step(Pcg64* r) {
  const U128 M = {0x2360ed051fc65da4ull, 0x4385df649fccf645ull};
  r->state = u128_add(u128_mul(r->state, M), r->inc);
}
__device__ __forceinline__ unsigned long long pcg_next64(Pcg64* r) {
  pcg_step(r);
  unsigned int rot = (unsigned int)(r->state.hi >> 58);   // state >> 122
  unsigned long long x = r->state.hi ^ r->state.lo;       // XSL
  return (x >> rot) | (x << ((64u - rot) & 63u));         // RR
}

// SeedSequence constants (numpy bit_generator.pyx)
__device__ __forceinline__ unsigned int ss_hashmix(unsigned int v, unsigned int* hc) {
  v ^= *hc; *hc = *hc * 0x931e8875u; v *= *hc; v ^= v >> 16; return v;
}
__device__ __forceinline__ unsigned int ss_mix(unsigned int x, unsigned int y) {
  unsigned int r = x * 0xca01f9ddu ^ y * 0x4973f715u; r ^= r >> 16; return r;
}
__device__ void pcg_seed(Pcg64* rng, unsigned int seed) {
  unsigned int pool[4]; unsigned int hc = 0x43b0d7e5u;   // INIT_A
  pool[0] = ss_hashmix(seed, &hc);
  for (int i = 1; i < 4; ++i) pool[i] = ss_hashmix(0u, &hc);
  for (int s = 0; s < 4; ++s)
    for (int d = 0; d < 4; ++d)
      if (s != d) pool[d] = ss_mix(pool[d], ss_hashmix(pool[s], &hc));
  unsigned int hc2 = 0x8b51f9ddu;                        // INIT_B
  unsigned long long w64[4];
  for (int i = 0; i < 4; ++i) {
    unsigned int lo = pool[(2*i) & 3];
    lo ^= hc2; hc2 *= 0x58f38dedu; lo *= hc2; lo ^= lo >> 16;
    unsigned int hi = pool[(2*i+1) & 3];
    hi ^= hc2; hc2 *= 0x58f38dedu; hi *= hc2; hi ^= hi >> 16;
    w64[i] = (unsigned long long)lo | ((unsigned long long)hi << 32);
  }
  U128 initstate = {w64[0], w64[1]};   // PCG_128BIT_CONSTANT(seed[0], seed[1]): [0] is HIGH
  U128 initseq   = {w64[2], w64[3]};
  rng->inc.hi = (initseq.hi << 1) | (initseq.lo >> 63);
  rng->inc.lo = (initseq.lo << 1) | 1ull;
  rng->state.hi = 0; rng->state.lo = 0;
  pcg_step(rng);
  rng->state = u128_add(rng->state, initstate);
  pcg_step(rng);
}

// affine jump-ahead: state <- A^delta * state + (A^delta-1)/(A-1)*inc
__device__ void pcg_advance(Pcg64* r, unsigned long long delta) {
  U128 acc_mult = {0ull, 1ull}, acc_plus = {0ull, 0ull};
  U128 cur_mult = {0x2360ed051fc65da4ull, 0x4385df649fccf645ull};
  U128 cur_plus = r->inc;
  while (delta) {
    if (delta & 1ull) {
      acc_mult = u128_mul(acc_mult, cur_mult);
      acc_plus = u128_add(u128_mul(acc_plus, cur_mult), cur_plus);
    }
    U128 one = {0ull, 1ull};
    U128 cm1 = u128_add(cur_mult, one);
    cur_plus = u128_mul(cm1, cur_plus);
    cur_mult = u128_mul(cur_mult, cur_mult);
    delta >>= 1;
  }
  r->state = u128_add(u128_mul(r->state, acc_mult), acc_plus);
}

// ============================================================================
// Problem constants
// ============================================================================
#define S_LEN   16384
#define Q_LEN   65536
#define Q_TOT   327680     // 5*65536
#define DFEAT   256
#define MAXS    256
#define CAPS64  24576
#define CAPQ64  98304
#define TILE    4096
#define STILES  (S_LEN / TILE)    // 4
#define QTILES  (Q_TOT / TILE)    // 80
#define NBLK_C  (5 * STILES + 5 * QTILES)   // 420
#define MSHARDS 8
#define MPASSES 8

// meta layout: [0..4]=ns_full, [5..9]=nq_full, [10..14]=na, [15..19]=nb

__constant__ int c_kshift[MPASSES] = {27, 23, 19, 15, 11, 7, 3, 0};

// ============================================================================
// K0: parallel draw-stream generation (exact numpy next32 sequence, lo first)
// ============================================================================
__global__ __launch_bounds__(256) void k_draws(unsigned int* __restrict__ draws) {
  int t = blockIdx.x; int cls = t % 5; int isq = t / 5;
  unsigned int seed = (unsigned)(1000 + isq * 1000 + cls + 1);
  unsigned long long cap64 = isq ? CAPQ64 : CAPS64;
  unsigned int* dst = draws + (isq ? (10ull * CAPS64 + (unsigned long long)cls * 2 * CAPQ64)
                                   : ((unsigned long long)cls * 2 * CAPS64));
  Pcg64 rng; pcg_seed(&rng, seed);
  int tid = threadIdx.x;
  unsigned long long C = cap64 / 256ull;     // 96 or 384
  unsigned long long k0 = (unsigned long long)tid * C;
  pcg_advance(&rng, k0);
  uint2* d2 = (uint2*)dst;
  for (unsigned long long m = 0; m < C; ++m) {
    unsigned long long o = pcg_next64(&rng);
    d2[k0 + m] = make_uint2((unsigned int)o, (unsigned int)(o >> 32));
  }
}

// ============================================================================
// K1a: per-tile match counts
// ============================================================================
__global__ __launch_bounds__(256) void k_count(const int* __restrict__ ls,
                                               const int* __restrict__ lq,
                                               int* __restrict__ cnts) {
  int b = blockIdx.x;
  const int* src; int matchval;
  if (b < 5 * STILES) {
    int cls = b / STILES, tl = b % STILES;
    src = ls + cls * S_LEN + tl * TILE; matchval = 1;
  } else {
    int bb = b - 5 * STILES; int cls = bb / QTILES, tl = bb % QTILES;
    src = lq + tl * TILE; matchval = cls + 1;
  }
  int tid = threadIdx.x;
  int cnt = 0;
  for (int k = 0; k < TILE; k += 256) cnt += (src[k + tid] == matchval) ? 1 : 0;
  __shared__ int red[256];
  red[tid] = cnt; __syncthreads();
  for (int s = 128; s > 0; s >>= 1) { if (tid < s) red[tid] += red[tid + s]; __syncthreads(); }
  if (tid == 0) cnts[b] = red[0];
}

// ============================================================================
// K1b: tiny scan: exclusive offsets per class + meta totals
// ============================================================================
__global__ void k_scan(const int* __restrict__ cnts, int* __restrict__ offs,
                       int* __restrict__ meta) {
  int t = threadIdx.x;
  if (t < 5) {
    int base = 0;
    for (int k = 0; k < STILES; ++k) {
      offs[t * STILES + k] = base; base += cnts[t * STILES + k];
    }
    meta[t] = base;
    meta[10 + t] = base < MAXS ? base : MAXS;
  } else if (t < 10) {
    int c = t - 5; int base = 0;
    for (int k = 0; k < QTILES; ++k) {
      int idx = 5 * STILES + c * QTILES + k;
      offs[idx] = base; base += cnts[idx];
    }
    meta[5 + c] = base;
    meta[15 + c] = base < MAXS ? base : MAXS;
  }
}

// ============================================================================
// K1c: stable compaction write at per-tile offsets (4-wave ballot prefix)
// ============================================================================
__global__ __launch_bounds__(256) void k_write(const int* __restrict__ ls,
                                               const int* __restrict__ lq,
                                               const int* __restrict__ offs,
                                               int* __restrict__ sup_list,
                                               int* __restrict__ qry_list) {
  int b = blockIdx.x;
  const int* src; int matchval; int* out; int ibase;
  if (b < 5 * STILES) {
    int cls = b / STILES, tl = b % STILES;
    src = ls + cls * S_LEN + tl * TILE; matchval = 1;
    out = sup_list + cls * S_LEN; ibase = tl * TILE;
  } else {
    int bb = b - 5 * STILES; int cls = bb / QTILES, tl = bb % QTILES;
    src = lq + tl * TILE; matchval = cls + 1;
    out = qry_list + (size_t)cls * Q_TOT; ibase = tl * TILE;
  }
  int tid = threadIdx.x; int w = tid >> 6, lane = tid & 63;
  unsigned long long lmask = (1ull << lane) - 1ull;
  __shared__ int wcnt[4];
  int base = offs[b];
  for (int k = 0; k < TILE; k += 256) {
    int i = k + tid;
    bool p = (src[i] == matchval);
    unsigned long long m = __ballot(p);
    if (lane == 0) wcnt[w] = __popcll(m);
    __syncthreads();
    int prev = 0;
    #pragma unroll
    for (int ww = 0; ww < 4; ++ww) prev += (ww < w) ? wcnt[ww] : 0;
    int tot = wcnt[0] + wcnt[1] + wcnt[2] + wcnt[3];
    if (p) out[base + prev + __popcll(m & lmask)] = ibase + i;
    __syncthreads();
    base += tot;
  }
}

// ============================================================================
// K2: wave-parallel masked-rejection automaton, INTERVAL-COMMIT resolution,
//     depth-3 register prefetch, two-ballot fast path.
// ============================================================================
__global__ __launch_bounds__(64) void k_consume(const int* __restrict__ meta,
                                                const unsigned int* __restrict__ draws,
                                                int* Jsup, int* Jqry) {
  int t = blockIdx.x; int cls = t % 5; int isq = t / 5;
  int n = meta[isq * 5 + cls];
  if (n <= MAXS) return;
  const unsigned int* d = draws + (isq ? (10ull * CAPS64 + (unsigned long long)cls * 2 * CAPQ64)
                                       : ((unsigned long long)cls * 2 * CAPS64));
  int* J = isq ? (Jqry + (size_t)cls * Q_TOT) : (Jsup + cls * S_LEN);
  int lane = threadIdx.x;
  unsigned long long lmask = (1ull << lane) - 1ull;
  unsigned long long lbit  = (1ull << lane);
  int i = n - 1;
  size_t p = 0;
  unsigned int v   = d[lane];
  unsigned int vn1 = d[64 + lane];
  unsigned int vn2 = d[128 + lane];
  unsigned int vn3 = d[192 + lane];
  for (;;) {
    unsigned int vfar = d[p + 256 + lane];     // 3-deep prefetch, in flight
    unsigned long long rej = 0ull, acc = 0ull;
    for (;;) {
      unsigned long long unc = ~(rej | acc);
      int rbelow = __popcll(rej & lmask);
      int ubelow = __popcll(unc & lmask);
      int il_min = i - lane + rbelow;          // >= 193 always
      int il_max = il_min + ubelow;
      bool unres = (unc & lbit) != 0ull;
      unsigned int mlo = 0xFFFFFFFFu >> __clz(il_min);
      unsigned int mhi = 0xFFFFFFFFu >> __clz(il_max);
      unsigned int w = v & mlo;
      bool def_rej, hard;
      if (mlo == mhi) {
        def_rej = w > (unsigned int)il_max;
        hard = !def_rej && (w > (unsigned int)il_min);   // middle band
      } else if (ubelow == 0) {                // octave boundary: exact resolve
        def_rej = w > (unsigned int)il_min;
        hard = false;
      } else {
        def_rej = false;
        hard = true;                           // boundary-spanning, wait
      }
      def_rej = def_rej && unres;
      hard = hard && unres;
      unsigned long long nr = __ballot(def_rej);
      unsigned long long hd = __ballot(hard);
      rej |= nr;
      acc |= unc & ~nr & ~hd;
      if (!hd) break;
    }
    int rbelow = __popcll(rej & lmask);
    int il = i - lane + rbelow;
    int totAcc = 64 - __popcll(rej);
    if ((acc & lbit) && il >= MAXS)
      J[il] = (int)(v & (0xFFFFFFFFu >> __clz(il)));
    int needed = i - (MAXS - 1);
    if (totAcc >= needed) break;
    i -= totAcc; p += 64;
    v = vn1; vn1 = vn2; vn2 = vn3; vn3 = vfar;
  }
}

// ============================================================================
// K3a: next-hitter index fill.  H[v] = min{ i > v, i in [256,n) : J[i] == v }
// ============================================================================
__global__ __launch_bounds__(256) void k_hfill(const int* __restrict__ meta,
                                               const int* __restrict__ Jsup,
                                               const int* __restrict__ Jqry,
                                               unsigned int* __restrict__ Hsup,
                                               unsigned int* __restrict__ Hqry) {
  const int SB = 5 * (S_LEN / 256);
  int b = blockIdx.x;
  int cls, i; const int* J; unsigned int* H; int n;
  if (b < SB) {
    cls = b / (S_LEN / 256);
    i = (b % (S_LEN / 256)) * 256 + threadIdx.x;
    n = meta[cls];
    J = Jsup + cls * S_LEN; H = Hsup + cls * S_LEN;
  } else {
    b -= SB;
    cls = b / (Q_TOT / 256);
    i = (b % (Q_TOT / 256)) * 256 + threadIdx.x;
    n = meta[5 + cls];
    J = Jqry + (size_t)cls * Q_TOT; H = Hqry + (size_t)cls * Q_TOT;
  }
  if (i < MAXS || i >= n) return;
  int j = J[i];
  if (j != i) atomicMin(&H[j], (unsigned int)i);
}

// ============================================================================
// K3b: chase.  sel[t][s] = list[ c(s) ]
// ============================================================================
__global__ __launch_bounds__(256) void k_chase(const int* __restrict__ meta,
                                               const int* __restrict__ sup_list,
                                               const int* __restrict__ qry_list,
                                               const unsigned int* __restrict__ Hsup,
                                               const unsigned int* __restrict__ Hqry,
                                               int* sel) {
  int t = blockIdx.x; int tid = threadIdx.x;
  int cls = t % 5; int isq = t / 5;
  int n = meta[isq * 5 + cls];
  const int* list; const unsigned int* H;
  if (!isq) { list = sup_list + cls * S_LEN; H = Hsup + cls * S_LEN; }
  else      { list = qry_list + (size_t)cls * Q_TOT; H = Hqry + (size_t)cls * Q_TOT; }
  int* s = sel + t * MAXS;
  if (n <= MAXS) { if (tid < n) s[tid] = list[tid]; return; }
  unsigned int v = (unsigned int)tid;
  unsigned int h = H[v];
  while (h != 0xFFFFFFFFu) { v = h; h = H[v]; }
  s[tid] = list[v];
}

// ============================================================================
// K4: gather selected feature rows + fused row-norm (x / (||x|| + 1e-12)).
// ============================================================================
__global__ __launch_bounds__(256) void k_gather(const float* __restrict__ f_s,
                                                const float* __restrict__ f_q,
                                                const int* __restrict__ meta,
                                                const int* __restrict__ sel,
                                                float* xa, float* xb) {
  int blk = blockIdx.x;
  int t = blk >> 3;          // class-pair 0..9
  int slab = blk & 7;        // 8 slabs x 32 rows
  int cls = t % 5; int isq = t / 5;
  int n = meta[10 + isq * 5 + cls];
  int tid = threadIdx.x;
  int row = slab * 32 + (tid >> 3);
  int dg = tid & 7;          // 8 d-groups of 32
  if (row >= n) return;      // group-uniform (8 lanes share row)
  int id = sel[t * MAXS + row];
  const float* src; size_t stride; float* dst;
  if (!isq) {
    src = f_s + (size_t)cls * DFEAT * S_LEN + id; stride = S_LEN;
    dst = xa + cls * (MAXS * DFEAT) + row * DFEAT;
  } else {
    int m = id >> 16; int nn = id & 0xFFFF;
    src = f_q + (size_t)m * DFEAT * Q_LEN + nn; stride = Q_LEN;
    dst = xb + cls * (MAXS * DFEAT) + row * DFEAT;
  }
  float v[32];
  #pragma unroll
  for (int dd = 0; dd < 32; ++dd)
    v[dd] = src[(size_t)(dg * 32 + dd) * stride];
  float ss = 0.f;
  #pragma unroll
  for (int dd = 0; dd < 32; ++dd) ss += v[dd] * v[dd];
  ss += __shfl_xor(ss, 1);
  ss += __shfl_xor(ss, 2);
  ss += __shfl_xor(ss, 4);
  float inv = 1.0f / (sqrtf(ss) + 1e-12f);
  #pragma unroll
  for (int dd = 0; dd < 32; ++dd) dst[dg * 32 + dd] = v[dd] * inv;
}

// ============================================================================
// K5: 35 Gram matrices (256x256, K=256), 128x128 tiles -> 140 blocks.
//     256 threads: 2x2 waves of 8x8 lanes, 8x8 outputs each.
//     LDS [128][33] odd stride: a/b reads are 8 lanes over 4 banks = 2-way
//     aliasing (free, m136).  Per-output FMA chain ascending k -> bit-identical
//     to the previous kernel.
// ============================================================================
__global__ __launch_bounds__(256) void k_gram(const float* __restrict__ xa,
                                              const float* __restrict__ xb,
                                              float* Ga, float* Gb, float* Gab) {
  int b = blockIdx.x;
  int j = b >> 2; int tile = b & 3;
  int tr = (tile >> 1) * 128, tc = (tile & 1) * 128;
  const float *A, *B; float* G;
  if (j < 5)       { A = xa + j * 65536; B = A; G = Ga + j * 65536; }
  else if (j < 10) { int c = j - 5; A = xb + c * 65536; B = A; G = Gb + c * 65536; }
  else             { int p = j - 10; int k = p / 5, c = p % 5;
                     A = xa + k * 65536; B = xb + c * 65536; G = Gab + p * 65536; }
  __shared__ float As[128][33];
  __shared__ float Bs[128][33];
  int tid = threadIdx.x;
  int w = tid >> 6, lane = tid & 63;
  int wr = w >> 1, wc = w & 1;
  int lr = lane >> 3, lc = lane & 7;
  int orow = wr * 64 + lr * 8;     // within-tile output row base
  int ocol = wc * 64 + lc * 8;     // within-tile output col base
  float acc[8][8];
  #pragma unroll
  for (int r = 0; r < 8; ++r)
    #pragma unroll
    for (int s = 0; s < 8; ++s) acc[r][s] = 0.f;

  for (int k0 = 0; k0 < 256; k0 += 32) {
    #pragma unroll
    for (int e = 0; e < 4; ++e) {
      int idx = tid + e * 256;          // 0..1023
      int row = idx >> 3;               // 0..127
      int c4  = idx & 7;                // float4 slot in 32-k chunk
      float4 va = *(const float4*)(A + (size_t)(tr + row) * 256 + k0 + c4 * 4);
      As[row][c4 * 4 + 0] = va.x; As[row][c4 * 4 + 1] = va.y;
      As[row][c4 * 4 + 2] = va.z; As[row][c4 * 4 + 3] = va.w;
      float4 vb = *(const float4*)(B + (size_t)(tc + row) * 256 + k0 + c4 * 4);
      Bs[row][c4 * 4 + 0] = vb.x; Bs[row][c4 * 4 + 1] = vb.y;
      Bs[row][c4 * 4 + 2] = vb.z; Bs[row][c4 * 4 + 3] = vb.w;
    }
    __syncthreads();
    #pragma unroll 4
    for (int kk = 0; kk < 32; ++kk) {
      float a[8], bv[8];
      #pragma unroll
      for (int r = 0; r < 8; ++r) a[r] = As[orow + r][kk];
      #pragma unroll
      for (int s = 0; s < 8; ++s) bv[s] = Bs[ocol + s][kk];
      #pragma unroll
      for (int r = 0; r < 8; ++r)
        #pragma unroll
        for (int s = 0; s < 8; ++s) acc[r][s] += a[r] * bv[s];
    }
    __syncthreads();
  }
  #pragma unroll
  for (int r = 0; r < 8; ++r) {
    float* grow = G + (size_t)(tr + orow + r) * 256 + tc + ocol;
    *(float4*)(grow + 0) = make_float4(acc[r][0], acc[r][1], acc[r][2], acc[r][3]);
    *(float4*)(grow + 4) = make_float4(acc[r][4], acc[r][5], acc[r][6], acc[r][7]);
  }
}

// ============================================================================
// K6: extract Gram diagonals
// ============================================================================
__global__ __launch_bounds__(256) void k_diag(const float* __restrict__ Ga,
                                              const float* __restrict__ Gb,
                                              float* diagA, float* diagB) {
  int t = blockIdx.x; int i = threadIdx.x;
  if (t < 5) diagA[t * 256 + i] = Ga[t * 65536 + i * 257];
  else { int c = t - 5; diagB[c * 256 + i] = Gb[c * 65536 + i * 257]; }
}

// ============================================================================
// K7: G -> D in place (280 blocks: 35 matrices x 8 row-slabs)
// ============================================================================
__global__ __launch_bounds__(256) void k_conv(float* Ga, float* Gb, float* Gab,
                                              const float* __restrict__ diagA,
                                              const float* __restrict__ diagB) {
  int b = blockIdx.x; int j = b >> 3; int slab = b & 7; int tid = threadIdx.x;
  float* G; const float *dA, *dB;
  if (j < 5)       { G = Ga + j * 65536; dA = diagA + j * 256; dB = dA; }
  else if (j < 10) { int c = j - 5; G = Gb + c * 65536; dA = diagB + c * 256; dB = dA; }
  else             { int p = j - 10; int k = p / 5, c = p % 5;
                     G = Gab + p * 65536; dA = diagA + k * 256; dB = diagB + c * 256; }
  float db = dB[tid];
  for (int i = slab * 32; i < slab * 32 + 32; ++i) {
    float g = G[i * 256 + tid];
    float d = dA[i] + db - 2.0f * g;
    G[i * 256 + tid] = d > 0.f ? d : 0.f;
  }
}

// ============================================================================
// K8: grid-parallel 16-ary exact radix-select, one kernel per pass.
// ============================================================================
__device__ __forceinline__ void med_select(const unsigned int* __restrict__ c,
                                           unsigned int lprev, unsigned int bprev,
                                           unsigned int r, int kprev,
                                           unsigned int* lo, unsigned int* base) {
  int j = 15;
  #pragma unroll
  for (int q = 14; q >= 0; --q)
    if (bprev + c[q] > r) j = q;
  *lo = lprev + ((unsigned int)j << kprev);
  *base = (j == 0) ? bprev : bprev + c[j - 1];
}

__global__ __launch_bounds__(256) void k_medpass(int t,
                                                 const int* __restrict__ meta,
                                                 const float* __restrict__ Da_all,
                                                 const float* __restrict__ Db_all,
                                                 const float* __restrict__ Dab_all,
                                                 unsigned int* __restrict__ bufAll,  // [MPASSES][25][16]
                                                 unsigned int* __restrict__ loArr,   // [MPASSES][25]
                                                 unsigned int* __restrict__ baseArr, // [MPASSES][25]
                                                 unsigned int* __restrict__ zcArr) { // [25]
  int b = blockIdx.x;
  int p = b / MSHARDS, sh = b % MSHARDS;
  int kcl = p / 5, ccl = p % 5;
  int tid = threadIdx.x;
  int nsf = meta[kcl], nqf = meta[5 + ccl];
  if (nsf < 2 || nqf < 2) return;
  int na = meta[10 + kcl], nb = meta[15 + ccl];
  const float4* A4 = (const float4*)(Da_all + kcl * 65536);
  const float4* B4 = (const float4*)(Db_all + ccl * 65536);
  const float4* C4 = (const float4*)(Dab_all + p * 65536);

  __shared__ unsigned int sh_lo[1], sh_base[1];
  __shared__ unsigned int wred[4][16];
  __shared__ unsigned int wzc[4];

  int ks = c_kshift[t];
  unsigned int N = (unsigned int)(na + nb) * (unsigned int)(na + nb);

  if (tid == 0) {
    unsigned int lo = 0, base = 0;
    if (t > 0) {
      unsigned int nz = zcArr[p];
      if (nz < N) {
        unsigned int r = nz + (N - nz - 1u) / 2u;
        unsigned int cprev[15];
        const unsigned int* cp = bufAll + ((size_t)(t - 1) * 25 + p) * 16;
        #pragma unroll
        for (int q = 0; q < 15; ++q) cprev[q] = cp[q];
        med_select(cprev, loArr[(t - 1) * 25 + p], baseArr[(t - 1) * 25 + p],
                   r, c_kshift[t - 1], &lo, &base);
      }
    }
    sh_lo[0] = lo; sh_base[0] = base;
    if (sh == 0) { loArr[t * 25 + p] = lo; baseArr[t * 25 + p] = base; }
  }
  __syncthreads();
  unsigned int lo = sh_lo[0];

  unsigned int cnt[15];
  #pragma unroll
  for (int j = 0; j < 15; ++j) cnt[j] = 0;
  unsigned int zc = 0;
  unsigned int span = 16u << ks;   // ks<=27 -> fits u32 (16<<27 = 2^31)

  #define PROC_MAT(M4, nr, nc, W)                                             \
    for (int m = 0; m < 8; ++m) {                                             \
      int fidx = sh * 2048 + m * 256 + tid;                                   \
      float4 v = M4[fidx];                                                    \
      int row = fidx >> 6; int col0 = (fidx & 63) << 2;                       \
      unsigned int kb[4] = {__float_as_uint(v.x), __float_as_uint(v.y),       \
                            __float_as_uint(v.z), __float_as_uint(v.w)};      \
      _Pragma("unroll")                                                       \
      for (int cc = 0; cc < 4; ++cc) {                                        \
        bool valid = (row < (nr)) && (col0 + cc < (nc));                      \
        unsigned int key = kb[cc];                                            \
        if (t == 0) zc += (valid && key == 0u) ? (W) : 0u;                    \
        unsigned int d = key - lo;                                            \
        bool in = valid && (key >= lo) && (d < span);                         \
        _Pragma("unroll")                                                     \
        for (int j = 0; j < 15; ++j)                                          \
          cnt[j] += (in && d < ((unsigned int)(j + 1) << ks)) ? (W) : 0u;     \
      }                                                                       \
    }

  PROC_MAT(A4, na, na, 1u)
  PROC_MAT(B4, nb, nb, 1u)
  PROC_MAT(C4, na, nb, 2u)
  #undef PROC_MAT

  // wave-level reduce then cross-wave
  #pragma unroll
  for (int j = 0; j < 15; ++j)
    for (int o = 32; o > 0; o >>= 1) cnt[j] += __shfl_down(cnt[j], o);
  if (t == 0)
    for (int o = 32; o > 0; o >>= 1) zc += __shfl_down(zc, o);
  int w = tid >> 6, lane = tid & 63;
  if (lane == 0) {
    #pragma unroll
    for (int j = 0; j < 15; ++j) wred[w][j] = cnt[j];
    wzc[w] = zc;
  }
  __syncthreads();
  if (tid < 15) {
    unsigned int s = wred[0][tid] + wred[1][tid] + wred[2][tid] + wred[3][tid];
    atomicAdd(&bufAll[((size_t)t * 25 + p) * 16 + tid], s);
  }
  if (t == 0 && tid == 15) {
    unsigned int s = wzc[0] + wzc[1] + wzc[2] + wzc[3];
    atomicAdd(&zcArr[p], s);
  }
}

// ============================================================================
// K8b: RBF partial sums (200 blocks), sigma from final select
// ============================================================================
__global__ __launch_bounds__(256) void k_rbf(const int* __restrict__ meta,
                                             const float* __restrict__ Da_all,
                                             const float* __restrict__ Db_all,
                                             const float* __restrict__ Dab_all,
                                             const unsigned int* __restrict__ bufAll,
                                             const unsigned int* __restrict__ loArr,
                                             const unsigned int* __restrict__ baseArr,
                                             const unsigned int* __restrict__ zcArr,
                                             double* __restrict__ mmdsum) { // [25][3]
  int b = blockIdx.x;
  int p = b / MSHARDS, sh = b % MSHARDS;
  int kcl = p / 5, ccl = p % 5;
  int tid = threadIdx.x;
  int nsf = meta[kcl], nqf = meta[5 + ccl];
  if (nsf < 2 || nqf < 2) return;
  int na = meta[10 + kcl], nb = meta[15 + ccl];
  const float4* A4 = (const float4*)(Da_all + kcl * 65536);
  const float4* B4 = (const float4*)(Db_all + ccl * 65536);
  const float4* C4 = (const float4*)(Dab_all + p * 65536);

  unsigned int N = (unsigned int)(na + nb) * (unsigned int)(na + nb);
  unsigned int nz = zcArr[p];
  float base_s;
  if (nz >= N) base_s = 1.0f;
  else {
    unsigned int r = nz + (N - nz - 1u) / 2u;
    unsigned int cprev[15];
    const unsigned int* cp = bufAll + ((size_t)(MPASSES - 1) * 25 + p) * 16;
    #pragma unroll
    for (int q = 0; q < 15; ++q) cprev[q] = cp[q];
    unsigned int lo, bs;
    med_select(cprev, loArr[(MPASSES - 1) * 25 + p], baseArr[(MPASSES - 1) * 25 + p],
               r, 0, &lo, &bs);
    base_s = sqrtf(__uint_as_float(lo) + 1e-6f);
  }
  float g2 = base_s * base_s;
  float c0 = 1.0f / (2.0f * g2 * 0.25f);
  float c1 = 1.0f / (2.0f * g2 * 1.0f);
  float c2 = 1.0f / (2.0f * g2 * 4.0f);
  float c3 = 1.0f / (2.0f * g2 * 16.0f);

  double accA = 0.0, accB = 0.0, accAB = 0.0;
  #define RBF_MAT(M4, nr, nc, ACC)                                            \
    for (int m = 0; m < 8; ++m) {                                             \
      int fidx = sh * 2048 + m * 256 + tid;                                   \
      float4 v = M4[fidx];                                                    \
      int row = fidx >> 6; int col0 = (fidx & 63) << 2;                       \
      float vv[4] = {v.x, v.y, v.z, v.w};                                     \
      _Pragma("unroll")                                                       \
      for (int cc = 0; cc < 4; ++cc) {                                        \
        if ((row < (nr)) && (col0 + cc < (nc))) {                             \
          float d = vv[cc];                                                   \
          ACC += (double)(expf(-d * c0) + expf(-d * c1)                       \
                        + expf(-d * c2) + expf(-d * c3));                     \
        }                                                                     \
      }                                                                       \
    }
  RBF_MAT(A4, na, na, accA)
  RBF_MAT(B4, nb, nb, accB)
  RBF_MAT(C4, na, nb, accAB)
  #undef RBF_MAT

  for (int o = 32; o > 0; o >>= 1) {
    accA += __shfl_down(accA, o);
    accB += __shfl_down(accB, o);
    accAB += __shfl_down(accAB, o);
  }
  __shared__ double wsum[4][3];
  int w = tid >> 6, lane = tid & 63;
  if (lane == 0) { wsum[w][0] = accA; wsum[w][1] = accB; wsum[w][2] = accAB; }
  __syncthreads();
  if (tid == 0) {
    double sA = wsum[0][0] + wsum[1][0] + wsum[2][0] + wsum[3][0];
    double sB = wsum[0][1] + wsum[1][1] + wsum[2][1] + wsum[3][1];
    double sC = wsum[0][2] + wsum[1][2] + wsum[2][2] + wsum[3][2];
    atomicAdd(&mmdsum[p * 3 + 0], sA);
    atomicAdd(&mmdsum[p * 3 + 1], sB);
    atomicAdd(&mmdsum[p * 3 + 2], sC);
  }
}

// ============================================================================
// K9: final weighted loss (mmd assembled from sums)
// ============================================================================
__global__ void k_final(const int* __restrict__ meta, const double* __restrict__ mmdsum,
                        float* out) {
  if (threadIdx.x != 0 || blockIdx.x != 0) return;
  double total = 0.0, vw = 0.0;
  for (int c = 0; c < 5; ++c) {
    int nsf = meta[c], nqf = meta[5 + c];
    if (nsf < 2 || nqf < 2) continue;
    int nbq = meta[15 + c];
    double mm[5];
    for (int k = 0; k < 5; ++k) {
      if (meta[k] < 2) { mm[k] = 0.0; continue; }
      int naa = meta[10 + k];
      int pp = k * 5 + c;
      double meanA  = mmdsum[pp * 3 + 0] / ((double)naa * (double)naa);
      double meanB  = mmdsum[pp * 3 + 1] / ((double)nbq * (double)nbq);
      double meanAB = mmdsum[pp * 3 + 2] / ((double)naa * (double)nbq);
      double m = meanA + meanB - 2.0 * meanAB;
      mm[k] = m > 0.0 ? m : 0.0;
    }
    double pos = mm[c];
    bool any = false; double best = 0.0;
    for (int k = 0; k < 5; ++k) {
      if (k == c || meta[k] < 2) continue;
      if (!any || mm[k] < best) { best = mm[k]; any = true; }
    }
    double lc = any ? fmax(pos - best + 0.1, 0.0) : pos;
    double w = sqrt((double)nsf * (double)nqf);
    total += w * lc; vw += w;
  }
  out[0] = (float)(0.1 * total / fmax(vw, 1e-12));
}

// ============================================================================
// host launcher
// ============================================================================
extern "C" void kernel_launch(void* const* d_in, const int* in_sizes, int n_in,
                              void* d_out, int out_size, void* d_ws, size_t ws_size,
                              hipStream_t stream) {
  const float* f_s = (const float*)d_in[0];
  const int*   l_s = (const int*)d_in[1];
  const float* f_q = (const float*)d_in[2];
  const int*   l_q = (const int*)d_in[3];
  float* out = (float*)d_out;
  char* ws = (char*)d_ws;

  size_t off = 0;
  auto take = [&](size_t bytes) -> void* {
    void* p = ws + off;
    off = (off + bytes + 255) & ~(size_t)255;
    return p;
  };
  int*   meta     = (int*)take(32 * 4);
  int*   cnts     = (int*)take(NBLK_C * 4);
  int*   offs     = (int*)take(NBLK_C * 4);
  int*   sup_list = (int*)take((size_t)5 * S_LEN * 4);
  int*   qry_list = (int*)take((size_t)5 * Q_TOT * 4);
  int*   Jsup     = (int*)take((size_t)5 * S_LEN * 4);
  int*   Jqry     = (int*)take((size_t)5 * Q_TOT * 4);
  unsigned int* draws = (unsigned int*)take((10ull * CAPS64 + 10ull * CAPQ64) * 4);
  int*   sel      = (int*)take((size_t)10 * MAXS * 4);
  float* xa       = (float*)take((size_t)5 * 65536 * 4);
  float* xb       = (float*)take((size_t)5 * 65536 * 4);
  float* Ga       = (float*)take((size_t)5 * 65536 * 4);
  float* Gb       = (float*)take((size_t)5 * 65536 * 4);
  float* Gab      = (float*)take((size_t)25 * 65536 * 4);
  float* diagA    = (float*)take((size_t)5 * 256 * 4);
  float* diagB    = (float*)take((size_t)5 * 256 * 4);
  unsigned int* bufAll  = (unsigned int*)take((size_t)MPASSES * 25 * 16 * 4);
  unsigned int* loArr   = (unsigned int*)take((size_t)MPASSES * 25 * 4);
  unsigned int* baseArr = (unsigned int*)take((size_t)MPASSES * 25 * 4);
  unsigned int* zcArr   = (unsigned int*)take(25 * 4);
  double* mmdsum  = (double*)take(25 * 3 * 8);
  if (off > ws_size) return;

  // H (next-hitter) arrays alias the draws buffer — draws dead after k_consume.
  unsigned int* Hsup = draws;
  unsigned int* Hqry = draws + (size_t)5 * S_LEN;
  size_t hbytes = ((size_t)5 * S_LEN + (size_t)5 * Q_TOT) * 4;

  k_draws<<<10, 256, 0, stream>>>(draws);
  k_count<<<NBLK_C, 256, 0, stream>>>(l_s, l_q, cnts);
  k_scan<<<1, 64, 0, stream>>>(cnts, offs, meta);
  k_write<<<NBLK_C, 256, 0, stream>>>(l_s, l_q, offs, sup_list, qry_list);
  k_consume<<<10, 64, 0, stream>>>(meta, draws, Jsup, Jqry);
  hipMemsetAsync(Hsup, 0xFF, hbytes, stream);
  {
    int nblk = 5 * (S_LEN / 256) + 5 * (Q_TOT / 256);   // 320 + 6400
    k_hfill<<<nblk, 256, 0, stream>>>(meta, Jsup, Jqry, Hsup, Hqry);
  }
  k_chase<<<10, 256, 0, stream>>>(meta, sup_list, qry_list, Hsup, Hqry, sel);
  k_gather<<<80, 256, 0, stream>>>(f_s, f_q, meta, sel, xa, xb);
  k_gram<<<140, 256, 0, stream>>>(xa, xb, Ga, Gb, Gab);
  k_diag<<<10, 256, 0, stream>>>(Ga, Gb, diagA, diagB);
  k_conv<<<280, 256, 0, stream>>>(Ga, Gb, Gab, diagA, diagB);

  hipMemsetAsync(bufAll, 0, (size_t)MPASSES * 25 * 16 * 4, stream);
  hipMemsetAsync(zcArr, 0, 25 * 4, stream);
  hipMemsetAsync(mmdsum, 0, 25 * 3 * 8, stream);
  for (int t = 0; t < MPASSES; ++t)
    k_medpass<<<25 * MSHARDS, 256, 0, stream>>>(t, meta, Ga, Gb, Gab,
                                                bufAll, loArr, baseArr, zcArr);
  k_rbf<<<25 * MSHARDS, 256, 0, stream>>>(meta, Ga, Gb, Gab,
                                          bufAll, loArr, baseArr, zcArr, mmdsum);
  k_final<<<1, 64, 0, stream>>>(meta, mmdsum, out);
}

// Round 10
// 751.712 us; speedup vs baseline: 18.2193x; 1.1108x over previous
//
#include <hip/hip_runtime.h>

// ============================================================================
// numpy RNG replication: SeedSequence + PCG64 (XSL-RR 128/64), next32 buffering
// ============================================================================
struct U128 { unsigned long long hi, lo; };

__device__ __forceinline__ U128 u128_mul(U128 a, U128 b) {
  U128 r;
  r.lo = a.lo * b.lo;
  r.hi = __umul64hi(a.lo, b.lo) + a.hi * b.lo + a.lo * b.hi;
  return r;
}
__device__ __forceinline__ U128 u128_add(U128 a, U128 b) {
  U128 r; r.lo = a.lo + b.lo; r.hi = a.hi + b.hi + (r.lo < a.lo ? 1ull : 0ull); return r;
}

struct Pcg64 {
  U128 state, inc;
};

__device__ __forceinline__ void pcg_step(Pcg64* r) {
  const U128 M = {0x2360ed051fc65da4ull, 0x4385df649fccf645ull};
  r->state = u128_add(u128_mul(r->state, M), r->inc);
}
__device__ __forceinline__ unsigned long long pcg_next64(Pcg64* r) {
  pcg_step(r);
  unsigned int rot = (unsigned int)(r->state.hi >> 58);   // state >> 122
  unsigned long long x = r->state.hi ^ r->state.lo;       // XSL
  return (x >> rot) | (x << ((64u - rot) & 63u));         // RR
}

// SeedSequence constants (numpy bit_generator.pyx)
__device__ __forceinline__ unsigned int ss_hashmix(unsigned int v, unsigned int* hc) {
  v ^= *hc; *hc = *hc * 0x931e8875u; v *= *hc; v ^= v >> 16; return v;
}
__device__ __forceinline__ unsigned int ss_mix(unsigned int x, unsigned int y) {
  unsigned int r = x * 0xca01f9ddu ^ y * 0x4973f715u; r ^= r >> 16; return r;
}
__device__ void pcg_seed(Pcg64* rng, unsigned int seed) {
  unsigned int pool[4]; unsigned int hc = 0x43b0d7e5u;   // INIT_A
  pool[0] = ss_hashmix(seed, &hc);
  for (int i = 1; i < 4; ++i) pool[i] = ss_hashmix(0u, &hc);
  for (int s = 0; s < 4; ++s)
    for (int d = 0; d < 4; ++d)
      if (s != d) pool[d] = ss_mix(pool[d], ss_hashmix(pool[s], &hc));
  unsigned int hc2 = 0x8b51f9ddu;                        // INIT_B
  unsigned long long w64[4];
  for (int i = 0; i < 4; ++i) {
    unsigned int lo = pool[(2*i) & 3];
    lo ^= hc2; hc2 *= 0x58f38dedu; lo *= hc2; lo ^= lo >> 16;
    unsigned int hi = pool[(2*i+1) & 3];
    hi ^= hc2; hc2 *= 0x58f38dedu; hi *= hc2; hi ^= hi >> 16;
    w64[i] = (unsigned long long)lo | ((unsigned long long)hi << 32);
  }
  U128 initstate = {w64[0], w64[1]};   // PCG_128BIT_CONSTANT(seed[0], seed[1]): [0] is HIGH
  U128 initseq   = {w64[2], w64[3]};
  rng->inc.hi = (initseq.hi << 1) | (initseq.lo >> 63);
  rng->inc.lo = (initseq.lo << 1) | 1ull;
  rng->state.hi = 0; rng->state.lo = 0;
  pcg_step(rng);
  rng->state = u128_add(rng->state, initstate);
  pcg_step(rng);
}

// affine jump-ahead: state <- A^delta * state + (A^delta-1)/(A-1)*inc
__device__ void pcg_advance(Pcg64* r, unsigned long long delta) {
  U128 acc_mult = {0ull, 1ull}, acc_plus = {0ull, 0ull};
  U128 cur_mult = {0x2360ed051fc65da4ull, 0x4385df649fccf645ull};
  U128 cur_plus = r->inc;
  while (delta) {
    if (delta & 1ull) {
      acc_mult = u128_mul(acc_mult, cur_mult);
      acc_plus = u128_add(u128_mul(acc_plus, cur_mult), cur_plus);
    }
    U128 one = {0ull, 1ull};
    U128 cm1 = u128_add(cur_mult, one);
    cur_plus = u128_mul(cm1, cur_plus);
    cur_mult = u128_mul(cur_mult, cur_mult);
    delta >>= 1;
  }
  r->state = u128_add(u128_mul(r->state, acc_mult), acc_plus);
}

// ============================================================================
// Problem constants
// ============================================================================
#define S_LEN   16384
#define Q_LEN   65536
#define Q_TOT   327680     // 5*65536
#define DFEAT   256
#define MAXS    256
#define CAPS64  24576
#define CAPQ64  98304
#define TILE    4096
#define STILES  (S_LEN / TILE)    // 4
#define QTILES  (Q_TOT / TILE)    // 80
#define NBLK_C  (5 * STILES + 5 * QTILES)   // 420
#define MSHARDS 8
#define MPASSES 8

// meta layout: [0..4]=ns_full, [5..9]=nq_full, [10..14]=na, [15..19]=nb

__constant__ int c_kshift[MPASSES] = {27, 23, 19, 15, 11, 7, 3, 0};

// ============================================================================
// K0: parallel draw-stream generation (exact numpy next32 sequence, lo first)
// ============================================================================
__global__ __launch_bounds__(256) void k_draws(unsigned int* __restrict__ draws) {
  int t = blockIdx.x; int cls = t % 5; int isq = t / 5;
  unsigned int seed = (unsigned)(1000 + isq * 1000 + cls + 1);
  unsigned long long cap64 = isq ? CAPQ64 : CAPS64;
  unsigned int* dst = draws + (isq ? (10ull * CAPS64 + (unsigned long long)cls * 2 * CAPQ64)
                                   : ((unsigned long long)cls * 2 * CAPS64));
  Pcg64 rng; pcg_seed(&rng, seed);
  int tid = threadIdx.x;
  unsigned long long C = cap64 / 256ull;     // 96 or 384
  unsigned long long k0 = (unsigned long long)tid * C;
  pcg_advance(&rng, k0);
  uint2* d2 = (uint2*)dst;
  for (unsigned long long m = 0; m < C; ++m) {
    unsigned long long o = pcg_next64(&rng);
    d2[k0 + m] = make_uint2((unsigned int)o, (unsigned int)(o >> 32));
  }
}

// ============================================================================
// K1a: per-tile match counts
// ============================================================================
__global__ __launch_bounds__(256) void k_count(const int* __restrict__ ls,
                                               const int* __restrict__ lq,
                                               int* __restrict__ cnts) {
  int b = blockIdx.x;
  const int* src; int matchval;
  if (b < 5 * STILES) {
    int cls = b / STILES, tl = b % STILES;
    src = ls + cls * S_LEN + tl * TILE; matchval = 1;
  } else {
    int bb = b - 5 * STILES; int cls = bb / QTILES, tl = bb % QTILES;
    src = lq + tl * TILE; matchval = cls + 1;
  }
  int tid = threadIdx.x;
  int cnt = 0;
  for (int k = 0; k < TILE; k += 256) cnt += (src[k + tid] == matchval) ? 1 : 0;
  __shared__ int red[256];
  red[tid] = cnt; __syncthreads();
  for (int s = 128; s > 0; s >>= 1) { if (tid < s) red[tid] += red[tid + s]; __syncthreads(); }
  if (tid == 0) cnts[b] = red[0];
}

// ============================================================================
// K1b: tiny scan: exclusive offsets per class + meta totals
// ============================================================================
__global__ void k_scan(const int* __restrict__ cnts, int* __restrict__ offs,
                       int* __restrict__ meta) {
  int t = threadIdx.x;
  if (t < 5) {
    int base = 0;
    for (int k = 0; k < STILES; ++k) {
      offs[t * STILES + k] = base; base += cnts[t * STILES + k];
    }
    meta[t] = base;
    meta[10 + t] = base < MAXS ? base : MAXS;
  } else if (t < 10) {
    int c = t - 5; int base = 0;
    for (int k = 0; k < QTILES; ++k) {
      int idx = 5 * STILES + c * QTILES + k;
      offs[idx] = base; base += cnts[idx];
    }
    meta[5 + c] = base;
    meta[15 + c] = base < MAXS ? base : MAXS;
  }
}

// ============================================================================
// K1c: stable compaction write at per-tile offsets (4-wave ballot prefix)
// ============================================================================
__global__ __launch_bounds__(256) void k_write(const int* __restrict__ ls,
                                               const int* __restrict__ lq,
                                               const int* __restrict__ offs,
                                               int* __restrict__ sup_list,
                                               int* __restrict__ qry_list) {
  int b = blockIdx.x;
  const int* src; int matchval; int* out; int ibase;
  if (b < 5 * STILES) {
    int cls = b / STILES, tl = b % STILES;
    src = ls + cls * S_LEN + tl * TILE; matchval = 1;
    out = sup_list + cls * S_LEN; ibase = tl * TILE;
  } else {
    int bb = b - 5 * STILES; int cls = bb / QTILES, tl = bb % QTILES;
    src = lq + tl * TILE; matchval = cls + 1;
    out = qry_list + (size_t)cls * Q_TOT; ibase = tl * TILE;
  }
  int tid = threadIdx.x; int w = tid >> 6, lane = tid & 63;
  unsigned long long lmask = (1ull << lane) - 1ull;
  __shared__ int wcnt[4];
  int base = offs[b];
  for (int k = 0; k < TILE; k += 256) {
    int i = k + tid;
    bool p = (src[i] == matchval);
    unsigned long long m = __ballot(p);
    if (lane == 0) wcnt[w] = __popcll(m);
    __syncthreads();
    int prev = 0;
    #pragma unroll
    for (int ww = 0; ww < 4; ++ww) prev += (ww < w) ? wcnt[ww] : 0;
    int tot = wcnt[0] + wcnt[1] + wcnt[2] + wcnt[3];
    if (p) out[base + prev + __popcll(m & lmask)] = ibase + i;
    __syncthreads();
    base += tot;
  }
}

// ============================================================================
// K2: wave-parallel masked-rejection automaton, INTERVAL-COMMIT resolution.
//     4-chunk software pipeline: all 4 next-super-chunk loads issue at the
//     top (named registers v0..v3), 4 chunk bodies (~600 cy) hide the load
//     latency, rotation waits on a load issued a full super-chunk earlier.
// ============================================================================
__device__ __forceinline__ bool consume_chunk(unsigned int v, int& i, int lane,
                                              unsigned long long lmask,
                                              unsigned long long lbit,
                                              int* __restrict__ J) {
  unsigned long long rej = 0ull, acc = 0ull;
  for (;;) {
    unsigned long long unc = ~(rej | acc);
    int rbelow = __popcll(rej & lmask);
    int ubelow = __popcll(unc & lmask);
    int il_min = i - lane + rbelow;          // >= 193 always
    int il_max = il_min + ubelow;
    bool unres = (unc & lbit) != 0ull;
    unsigned int mlo = 0xFFFFFFFFu >> __clz(il_min);
    unsigned int mhi = 0xFFFFFFFFu >> __clz(il_max);
    unsigned int w = v & mlo;
    bool def_rej, hard;
    if (mlo == mhi) {
      def_rej = w > (unsigned int)il_max;
      hard = !def_rej && (w > (unsigned int)il_min);   // middle band
    } else if (ubelow == 0) {                // octave boundary: exact resolve
      def_rej = w > (unsigned int)il_min;
      hard = false;
    } else {
      def_rej = false;
      hard = true;                           // boundary-spanning, wait
    }
    def_rej = def_rej && unres;
    hard = hard && unres;
    unsigned long long nr = __ballot(def_rej);
    unsigned long long hd = __ballot(hard);
    rej |= nr;
    acc |= unc & ~nr & ~hd;
    if (!hd) break;
  }
  int rbelow = __popcll(rej & lmask);
  int il = i - lane + rbelow;
  int totAcc = 64 - __popcll(rej);
  if ((acc & lbit) && il >= MAXS)
    J[il] = (int)(v & (0xFFFFFFFFu >> __clz(il)));
  int needed = i - (MAXS - 1);
  if (totAcc >= needed) return true;
  i -= totAcc;
  return false;
}

__global__ __launch_bounds__(64) void k_consume(const int* __restrict__ meta,
                                                const unsigned int* __restrict__ draws,
                                                int* Jsup, int* Jqry) {
  int t = blockIdx.x; int cls = t % 5; int isq = t / 5;
  int n = meta[isq * 5 + cls];
  if (n <= MAXS) return;
  const unsigned int* d = draws + (isq ? (10ull * CAPS64 + (unsigned long long)cls * 2 * CAPQ64)
                                       : ((unsigned long long)cls * 2 * CAPS64));
  int* J = isq ? (Jqry + (size_t)cls * Q_TOT) : (Jsup + cls * S_LEN);
  int lane = threadIdx.x;
  unsigned long long lmask = (1ull << lane) - 1ull;
  unsigned long long lbit  = (1ull << lane);
  int i = n - 1;
  size_t p = 0;
  unsigned int v0 = d[lane];
  unsigned int v1 = d[64 + lane];
  unsigned int v2 = d[128 + lane];
  unsigned int v3 = d[192 + lane];
  for (;;) {
    unsigned int nv0 = d[p + 256 + lane];
    unsigned int nv1 = d[p + 320 + lane];
    unsigned int nv2 = d[p + 384 + lane];
    unsigned int nv3 = d[p + 448 + lane];
    if (consume_chunk(v0, i, lane, lmask, lbit, J)) break;
    if (consume_chunk(v1, i, lane, lmask, lbit, J)) break;
    if (consume_chunk(v2, i, lane, lmask, lbit, J)) break;
    if (consume_chunk(v3, i, lane, lmask, lbit, J)) break;
    p += 256;
    v0 = nv0; v1 = nv1; v2 = nv2; v3 = nv3;
  }
}

// ============================================================================
// K3a: next-hitter index fill.  H[v] = min{ i > v, i in [256,n) : J[i] == v }
// ============================================================================
__global__ __launch_bounds__(256) void k_hfill(const int* __restrict__ meta,
                                               const int* __restrict__ Jsup,
                                               const int* __restrict__ Jqry,
                                               unsigned int* __restrict__ Hsup,
                                               unsigned int* __restrict__ Hqry) {
  const int SB = 5 * (S_LEN / 256);
  int b = blockIdx.x;
  int cls, i; const int* J; unsigned int* H; int n;
  if (b < SB) {
    cls = b / (S_LEN / 256);
    i = (b % (S_LEN / 256)) * 256 + threadIdx.x;
    n = meta[cls];
    J = Jsup + cls * S_LEN; H = Hsup + cls * S_LEN;
  } else {
    b -= SB;
    cls = b / (Q_TOT / 256);
    i = (b % (Q_TOT / 256)) * 256 + threadIdx.x;
    n = meta[5 + cls];
    J = Jqry + (size_t)cls * Q_TOT; H = Hqry + (size_t)cls * Q_TOT;
  }
  if (i < MAXS || i >= n) return;
  int j = J[i];
  if (j != i) atomicMin(&H[j], (unsigned int)i);
}

// ============================================================================
// K3b: chase.  sel[t][s] = list[ c(s) ]
// ============================================================================
__global__ __launch_bounds__(256) void k_chase(const int* __restrict__ meta,
                                               const int* __restrict__ sup_list,
                                               const int* __restrict__ qry_list,
                                               const unsigned int* __restrict__ Hsup,
                                               const unsigned int* __restrict__ Hqry,
                                               int* sel) {
  int t = blockIdx.x; int tid = threadIdx.x;
  int cls = t % 5; int isq = t / 5;
  int n = meta[isq * 5 + cls];
  const int* list; const unsigned int* H;
  if (!isq) { list = sup_list + cls * S_LEN; H = Hsup + cls * S_LEN; }
  else      { list = qry_list + (size_t)cls * Q_TOT; H = Hqry + (size_t)cls * Q_TOT; }
  int* s = sel + t * MAXS;
  if (n <= MAXS) { if (tid < n) s[tid] = list[tid]; return; }
  unsigned int v = (unsigned int)tid;
  unsigned int h = H[v];
  while (h != 0xFFFFFFFFu) { v = h; h = H[v]; }
  s[tid] = list[v];
}

// ============================================================================
// K4: gather selected feature rows + fused row-norm (x / (||x|| + 1e-12)).
// ============================================================================
__global__ __launch_bounds__(256) void k_gather(const float* __restrict__ f_s,
                                                const float* __restrict__ f_q,
                                                const int* __restrict__ meta,
                                                const int* __restrict__ sel,
                                                float* xa, float* xb) {
  int blk = blockIdx.x;
  int t = blk >> 3;          // class-pair 0..9
  int slab = blk & 7;        // 8 slabs x 32 rows
  int cls = t % 5; int isq = t / 5;
  int n = meta[10 + isq * 5 + cls];
  int tid = threadIdx.x;
  int row = slab * 32 + (tid >> 3);
  int dg = tid & 7;          // 8 d-groups of 32
  if (row >= n) return;      // group-uniform (8 lanes share row)
  int id = sel[t * MAXS + row];
  const float* src; size_t stride; float* dst;
  if (!isq) {
    src = f_s + (size_t)cls * DFEAT * S_LEN + id; stride = S_LEN;
    dst = xa + cls * (MAXS * DFEAT) + row * DFEAT;
  } else {
    int m = id >> 16; int nn = id & 0xFFFF;
    src = f_q + (size_t)m * DFEAT * Q_LEN + nn; stride = Q_LEN;
    dst = xb + cls * (MAXS * DFEAT) + row * DFEAT;
  }
  float v[32];
  #pragma unroll
  for (int dd = 0; dd < 32; ++dd)
    v[dd] = src[(size_t)(dg * 32 + dd) * stride];
  float ss = 0.f;
  #pragma unroll
  for (int dd = 0; dd < 32; ++dd) ss += v[dd] * v[dd];
  ss += __shfl_xor(ss, 1);
  ss += __shfl_xor(ss, 2);
  ss += __shfl_xor(ss, 4);
  float inv = 1.0f / (sqrtf(ss) + 1e-12f);
  #pragma unroll
  for (int dd = 0; dd < 32; ++dd) dst[dg * 32 + dd] = v[dd] * inv;
}

// ============================================================================
// K5: 35 Gram matrices (256x256, K=256), 128x128 tiles -> 140 blocks.
// ============================================================================
__global__ __launch_bounds__(256) void k_gram(const float* __restrict__ xa,
                                              const float* __restrict__ xb,
                                              float* Ga, float* Gb, float* Gab) {
  int b = blockIdx.x;
  int j = b >> 2; int tile = b & 3;
  int tr = (tile >> 1) * 128, tc = (tile & 1) * 128;
  const float *A, *B; float* G;
  if (j < 5)       { A = xa + j * 65536; B = A; G = Ga + j * 65536; }
  else if (j < 10) { int c = j - 5; A = xb + c * 65536; B = A; G = Gb + c * 65536; }
  else             { int p = j - 10; int k = p / 5, c = p % 5;
                     A = xa + k * 65536; B = xb + c * 65536; G = Gab + p * 65536; }
  __shared__ float As[128][33];
  __shared__ float Bs[128][33];
  int tid = threadIdx.x;
  int w = tid >> 6, lane = tid & 63;
  int wr = w >> 1, wc = w & 1;
  int lr = lane >> 3, lc = lane & 7;
  int orow = wr * 64 + lr * 8;     // within-tile output row base
  int ocol = wc * 64 + lc * 8;     // within-tile output col base
  float acc[8][8];
  #pragma unroll
  for (int r = 0; r < 8; ++r)
    #pragma unroll
    for (int s = 0; s < 8; ++s) acc[r][s] = 0.f;

  for (int k0 = 0; k0 < 256; k0 += 32) {
    #pragma unroll
    for (int e = 0; e < 4; ++e) {
      int idx = tid + e * 256;          // 0..1023
      int row = idx >> 3;               // 0..127
      int c4  = idx & 7;                // float4 slot in 32-k chunk
      float4 va = *(const float4*)(A + (size_t)(tr + row) * 256 + k0 + c4 * 4);
      As[row][c4 * 4 + 0] = va.x; As[row][c4 * 4 + 1] = va.y;
      As[row][c4 * 4 + 2] = va.z; As[row][c4 * 4 + 3] = va.w;
      float4 vb = *(const float4*)(B + (size_t)(tc + row) * 256 + k0 + c4 * 4);
      Bs[row][c4 * 4 + 0] = vb.x; Bs[row][c4 * 4 + 1] = vb.y;
      Bs[row][c4 * 4 + 2] = vb.z; Bs[row][c4 * 4 + 3] = vb.w;
    }
    __syncthreads();
    #pragma unroll 4
    for (int kk = 0; kk < 32; ++kk) {
      float a[8], bv[8];
      #pragma unroll
      for (int r = 0; r < 8; ++r) a[r] = As[orow + r][kk];
      #pragma unroll
      for (int s = 0; s < 8; ++s) bv[s] = Bs[ocol + s][kk];
      #pragma unroll
      for (int r = 0; r < 8; ++r)
        #pragma unroll
        for (int s = 0; s < 8; ++s) acc[r][s] += a[r] * bv[s];
    }
    __syncthreads();
  }
  #pragma unroll
  for (int r = 0; r < 8; ++r) {
    float* grow = G + (size_t)(tr + orow + r) * 256 + tc + ocol;
    *(float4*)(grow + 0) = make_float4(acc[r][0], acc[r][1], acc[r][2], acc[r][3]);
    *(float4*)(grow + 4) = make_float4(acc[r][4], acc[r][5], acc[r][6], acc[r][7]);
  }
}

// ============================================================================
// K6: extract Gram diagonals
// ============================================================================
__global__ __launch_bounds__(256) void k_diag(const float* __restrict__ Ga,
                                              const float* __restrict__ Gb,
                                              float* diagA, float* diagB) {
  int t = blockIdx.x; int i = threadIdx.x;
  if (t < 5) diagA[t * 256 + i] = Ga[t * 65536 + i * 257];
  else { int c = t - 5; diagB[c * 256 + i] = Gb[c * 65536 + i * 257]; }
}

// ============================================================================
// K7: G -> D in place (280 blocks: 35 matrices x 8 row-slabs)
// ============================================================================
__global__ __launch_bounds__(256) void k_conv(float* Ga, float* Gb, float* Gab,
                                              const float* __restrict__ diagA,
                                              const float* __restrict__ diagB) {
  int b = blockIdx.x; int j = b >> 3; int slab = b & 7; int tid = threadIdx.x;
  float* G; const float *dA, *dB;
  if (j < 5)       { G = Ga + j * 65536; dA = diagA + j * 256; dB = dA; }
  else if (j < 10) { int c = j - 5; G = Gb + c * 65536; dA = diagB + c * 256; dB = dA; }
  else             { int p = j - 10; int k = p / 5, c = p % 5;
                     G = Gab + p * 65536; dA = diagA + k * 256; dB = diagB + c * 256; }
  float db = dB[tid];
  for (int i = slab * 32; i < slab * 32 + 32; ++i) {
    float g = G[i * 256 + tid];
    float d = dA[i] + db - 2.0f * g;
    G[i * 256 + tid] = d > 0.f ? d : 0.f;
  }
}

// ============================================================================
// K8: grid-parallel 16-ary exact radix-select, one kernel per pass.
// ============================================================================
__device__ __forceinline__ void med_select(const unsigned int* __restrict__ c,
                                           unsigned int lprev, unsigned int bprev,
                                           unsigned int r, int kprev,
                                           unsigned int* lo, unsigned int* base) {
  int j = 15;
  #pragma unroll
  for (int q = 14; q >= 0; --q)
    if (bprev + c[q] > r) j = q;
  *lo = lprev + ((unsigned int)j << kprev);
  *base = (j == 0) ? bprev : bprev + c[j - 1];
}

__global__ __launch_bounds__(256) void k_medpass(int t,
                                                 const int* __restrict__ meta,
                                                 const float* __restrict__ Da_all,
                                                 const float* __restrict__ Db_all,
                                                 const float* __restrict__ Dab_all,
                                                 unsigned int* __restrict__ bufAll,  // [MPASSES][25][16]
                                                 unsigned int* __restrict__ loArr,   // [MPASSES][25]
                                                 unsigned int* __restrict__ baseArr, // [MPASSES][25]
                                                 unsigned int* __restrict__ zcArr) { // [25]
  int b = blockIdx.x;
  int p = b / MSHARDS, sh = b % MSHARDS;
  int kcl = p / 5, ccl = p % 5;
  int tid = threadIdx.x;
  int nsf = meta[kcl], nqf = meta[5 + ccl];
  if (nsf < 2 || nqf < 2) return;
  int na = meta[10 + kcl], nb = meta[15 + ccl];
  const float4* A4 = (const float4*)(Da_all + kcl * 65536);
  const float4* B4 = (const float4*)(Db_all + ccl * 65536);
  const float4* C4 = (const float4*)(Dab_all + p * 65536);

  __shared__ unsigned int sh_lo[1], sh_base[1];
  __shared__ unsigned int wred[4][16];
  __shared__ unsigned int wzc[4];

  int ks = c_kshift[t];
  unsigned int N = (unsigned int)(na + nb) * (unsigned int)(na + nb);

  if (tid == 0) {
    unsigned int lo = 0, base = 0;
    if (t > 0) {
      unsigned int nz = zcArr[p];
      if (nz < N) {
        unsigned int r = nz + (N - nz - 1u) / 2u;
        unsigned int cprev[15];
        const unsigned int* cp = bufAll + ((size_t)(t - 1) * 25 + p) * 16;
        #pragma unroll
        for (int q = 0; q < 15; ++q) cprev[q] = cp[q];
        med_select(cprev, loArr[(t - 1) * 25 + p], baseArr[(t - 1) * 25 + p],
                   r, c_kshift[t - 1], &lo, &base);
      }
    }
    sh_lo[0] = lo; sh_base[0] = base;
    if (sh == 0) { loArr[t * 25 + p] = lo; baseArr[t * 25 + p] = base; }
  }
  __syncthreads();
  unsigned int lo = sh_lo[0];

  unsigned int cnt[15];
  #pragma unroll
  for (int j = 0; j < 15; ++j) cnt[j] = 0;
  unsigned int zc = 0;
  unsigned int span = 16u << ks;   // ks<=27 -> fits u32 (16<<27 = 2^31)

  #define PROC_MAT(M4, nr, nc, W)                                             \
    for (int m = 0; m < 8; ++m) {                                             \
      int fidx = sh * 2048 + m * 256 + tid;                                   \
      float4 v = M4[fidx];                                                    \
      int row = fidx >> 6; int col0 = (fidx & 63) << 2;                       \
      unsigned int kb[4] = {__float_as_uint(v.x), __float_as_uint(v.y),       \
                            __float_as_uint(v.z), __float_as_uint(v.w)};      \
      _Pragma("unroll")                                                       \
      for (int cc = 0; cc < 4; ++cc) {                                        \
        bool valid = (row < (nr)) && (col0 + cc < (nc));                      \
        unsigned int key = kb[cc];                                            \
        if (t == 0) zc += (valid && key == 0u) ? (W) : 0u;                    \
        unsigned int d = key - lo;                                            \
        bool in = valid && (key >= lo) && (d < span);                         \
        _Pragma("unroll")                                                     \
        for (int j = 0; j < 15; ++j)                                          \
          cnt[j] += (in && d < ((unsigned int)(j + 1) << ks)) ? (W) : 0u;     \
      }                                                                       \
    }

  PROC_MAT(A4, na, na, 1u)
  PROC_MAT(B4, nb, nb, 1u)
  PROC_MAT(C4, na, nb, 2u)
  #undef PROC_MAT

  // wave-level reduce then cross-wave
  #pragma unroll
  for (int j = 0; j < 15; ++j)
    for (int o = 32; o > 0; o >>= 1) cnt[j] += __shfl_down(cnt[j], o);
  if (t == 0)
    for (int o = 32; o > 0; o >>= 1) zc += __shfl_down(zc, o);
  int w = tid >> 6, lane = tid & 63;
  if (lane == 0) {
    #pragma unroll
    for (int j = 0; j < 15; ++j) wred[w][j] = cnt[j];
    wzc[w] = zc;
  }
  __syncthreads();
  if (tid < 15) {
    unsigned int s = wred[0][tid] + wred[1][tid] + wred[2][tid] + wred[3][tid];
    atomicAdd(&bufAll[((size_t)t * 25 + p) * 16 + tid], s);
  }
  if (t == 0 && tid == 15) {
    unsigned int s = wzc[0] + wzc[1] + wzc[2] + wzc[3];
    atomicAdd(&zcArr[p], s);
  }
}

// ============================================================================
// K8b: RBF partial sums (200 blocks), sigma from final select
// ============================================================================
__global__ __launch_bounds__(256) void k_rbf(const int* __restrict__ meta,
                                             const float* __restrict__ Da_all,
                                             const float* __restrict__ Db_all,
                                             const float* __restrict__ Dab_all,
                                             const unsigned int* __restrict__ bufAll,
                                             const unsigned int* __restrict__ loArr,
                                             const unsigned int* __restrict__ baseArr,
                                             const unsigned int* __restrict__ zcArr,
                                             double* __restrict__ mmdsum) { // [25][3]
  int b = blockIdx.x;
  int p = b / MSHARDS, sh = b % MSHARDS;
  int kcl = p / 5, ccl = p % 5;
  int tid = threadIdx.x;
  int nsf = meta[kcl], nqf = meta[5 + ccl];
  if (nsf < 2 || nqf < 2) return;
  int na = meta[10 + kcl], nb = meta[15 + ccl];
  const float4* A4 = (const float4*)(Da_all + kcl * 65536);
  const float4* B4 = (const float4*)(Db_all + ccl * 65536);
  const float4* C4 = (const float4*)(Dab_all + p * 65536);

  unsigned int N = (unsigned int)(na + nb) * (unsigned int)(na + nb);
  unsigned int nz = zcArr[p];
  float base_s;
  if (nz >= N) base_s = 1.0f;
  else {
    unsigned int r = nz + (N - nz - 1u) / 2u;
    unsigned int cprev[15];
    const unsigned int* cp = bufAll + ((size_t)(MPASSES - 1) * 25 + p) * 16;
    #pragma unroll
    for (int q = 0; q < 15; ++q) cprev[q] = cp[q];
    unsigned int lo, bs;
    med_select(cprev, loArr[(MPASSES - 1) * 25 + p], baseArr[(MPASSES - 1) * 25 + p],
               r, 0, &lo, &bs);
    base_s = sqrtf(__uint_as_float(lo) + 1e-6f);
  }
  float g2 = base_s * base_s;
  float c0 = 1.0f / (2.0f * g2 * 0.25f);
  float c1 = 1.0f / (2.0f * g2 * 1.0f);
  float c2 = 1.0f / (2.0f * g2 * 4.0f);
  float c3 = 1.0f / (2.0f * g2 * 16.0f);

  double accA = 0.0, accB = 0.0, accAB = 0.0;
  #define RBF_MAT(M4, nr, nc, ACC)                                            \
    for (int m = 0; m < 8; ++m) {                                             \
      int fidx = sh * 2048 + m * 256 + tid;                                   \
      float4 v = M4[fidx];                                                    \
      int row = fidx >> 6; int col0 = (fidx & 63) << 2;                       \
      float vv[4] = {v.x, v.y, v.z, v.w};                                     \
      _Pragma("unroll")                                                       \
      for (int cc = 0; cc < 4; ++cc) {                                        \
        if ((row < (nr)) && (col0 + cc < (nc))) {                             \
          float d = vv[cc];                                                   \
          ACC += (double)(expf(-d * c0) + expf(-d * c1)                       \
                        + expf(-d * c2) + expf(-d * c3));                     \
        }                                                                     \
      }                                                                       \
    }
  RBF_MAT(A4, na, na, accA)
  RBF_MAT(B4, nb, nb, accB)
  RBF_MAT(C4, na, nb, accAB)
  #undef RBF_MAT

  for (int o = 32; o > 0; o >>= 1) {
    accA += __shfl_down(accA, o);
    accB += __shfl_down(accB, o);
    accAB += __shfl_down(accAB, o);
  }
  __shared__ double wsum[4][3];
  int w = tid >> 6, lane = tid & 63;
  if (lane == 0) { wsum[w][0] = accA; wsum[w][1] = accB; wsum[w][2] = accAB; }
  __syncthreads();
  if (tid == 0) {
    double sA = wsum[0][0] + wsum[1][0] + wsum[2][0] + wsum[3][0];
    double sB = wsum[0][1] + wsum[1][1] + wsum[2][1] + wsum[3][1];
    double sC = wsum[0][2] + wsum[1][2] + wsum[2][2] + wsum[3][2];
    atomicAdd(&mmdsum[p * 3 + 0], sA);
    atomicAdd(&mmdsum[p * 3 + 1], sB);
    atomicAdd(&mmdsum[p * 3 + 2], sC);
  }
}

// ============================================================================
// K9: final weighted loss (mmd assembled from sums)
// ============================================================================
__global__ void k_final(const int* __restrict__ meta, const double* __restrict__ mmdsum,
                        float* out) {
  if (threadIdx.x != 0 || blockIdx.x != 0) return;
  double total = 0.0, vw = 0.0;
  for (int c = 0; c < 5; ++c) {
    int nsf = meta[c], nqf = meta[5 + c];
    if (nsf < 2 || nqf < 2) continue;
    int nbq = meta[15 + c];
    double mm[5];
    for (int k = 0; k < 5; ++k) {
      if (meta[k] < 2) { mm[k] = 0.0; continue; }
      int naa = meta[10 + k];
      int pp = k * 5 + c;
      double meanA  = mmdsum[pp * 3 + 0] / ((double)naa * (double)naa);
      double meanB  = mmdsum[pp * 3 + 1] / ((double)nbq * (double)nbq);
      double meanAB = mmdsum[pp * 3 + 2] / ((double)naa * (double)nbq);
      double m = meanA + meanB - 2.0 * meanAB;
      mm[k] = m > 0.0 ? m : 0.0;
    }
    double pos = mm[c];
    bool any = false; double best = 0.0;
    for (int k = 0; k < 5; ++k) {
      if (k == c || meta[k] < 2) continue;
      if (!any || mm[k] < best) { best = mm[k]; any = true; }
    }
    double lc = any ? fmax(pos - best + 0.1, 0.0) : pos;
    double w = sqrt((double)nsf * (double)nqf);
    total += w * lc; vw += w;
  }
  out[0] = (float)(0.1 * total / fmax(vw, 1e-12));
}

// ============================================================================
// host launcher
// ============================================================================
extern "C" void kernel_launch(void* const* d_in, const int* in_sizes, int n_in,
                              void* d_out, int out_size, void* d_ws, size_t ws_size,
                              hipStream_t stream) {
  const float* f_s = (const float*)d_in[0];
  const int*   l_s = (const int*)d_in[1];
  const float* f_q = (const float*)d_in[2];
  const int*   l_q = (const int*)d_in[3];
  float* out = (float*)d_out;
  char* ws = (char*)d_ws;

  size_t off = 0;
  auto take = [&](size_t bytes) -> void* {
    void* p = ws + off;
    off = (off + bytes + 255) & ~(size_t)255;
    return p;
  };
  int*   meta     = (int*)take(32 * 4);
  int*   cnts     = (int*)take(NBLK_C * 4);
  int*   offs     = (int*)take(NBLK_C * 4);
  int*   sup_list = (int*)take((size_t)5 * S_LEN * 4);
  int*   qry_list = (int*)take((size_t)5 * Q_TOT * 4);
  int*   Jsup     = (int*)take((size_t)5 * S_LEN * 4);
  int*   Jqry     = (int*)take((size_t)5 * Q_TOT * 4);
  unsigned int* draws = (unsigned int*)take((10ull * CAPS64 + 10ull * CAPQ64) * 4);
  int*   sel      = (int*)take((size_t)10 * MAXS * 4);
  float* xa       = (float*)take((size_t)5 * 65536 * 4);
  float* xb       = (float*)take((size_t)5 * 65536 * 4);
  float* Ga       = (float*)take((size_t)5 * 65536 * 4);
  float* Gb       = (float*)take((size_t)5 * 65536 * 4);
  float* Gab      = (float*)take((size_t)25 * 65536 * 4);
  float* diagA    = (float*)take((size_t)5 * 256 * 4);
  float* diagB    = (float*)take((size_t)5 * 256 * 4);
  unsigned int* bufAll  = (unsigned int*)take((size_t)MPASSES * 25 * 16 * 4);
  unsigned int* loArr   = (unsigned int*)take((size_t)MPASSES * 25 * 4);
  unsigned int* baseArr = (unsigned int*)take((size_t)MPASSES * 25 * 4);
  unsigned int* zcArr   = (unsigned int*)take(25 * 4);
  double* mmdsum  = (double*)take(25 * 3 * 8);
  if (off > ws_size) return;

  // H (next-hitter) arrays alias the draws buffer — draws dead after k_consume.
  unsigned int* Hsup = draws;
  unsigned int* Hqry = draws + (size_t)5 * S_LEN;
  size_t hbytes = ((size_t)5 * S_LEN + (size_t)5 * Q_TOT) * 4;

  k_draws<<<10, 256, 0, stream>>>(draws);
  k_count<<<NBLK_C, 256, 0, stream>>>(l_s, l_q, cnts);
  k_scan<<<1, 64, 0, stream>>>(cnts, offs, meta);
  k_write<<<NBLK_C, 256, 0, stream>>>(l_s, l_q, offs, sup_list, qry_list);
  k_consume<<<10, 64, 0, stream>>>(meta, draws, Jsup, Jqry);
  hipMemsetAsync(Hsup, 0xFF, hbytes, stream);
  {
    int nblk = 5 * (S_LEN / 256) + 5 * (Q_TOT / 256);   // 320 + 6400
    k_hfill<<<nblk, 256, 0, stream>>>(meta, Jsup, Jqry, Hsup, Hqry);
  }
  k_chase<<<10, 256, 0, stream>>>(meta, sup_list, qry_list, Hsup, Hqry, sel);
  k_gather<<<80, 256, 0, stream>>>(f_s, f_q, meta, sel, xa, xb);
  k_gram<<<140, 256, 0, stream>>>(xa, xb, Ga, Gb, Gab);
  k_diag<<<10, 256, 0, stream>>>(Ga, Gb, diagA, diagB);
  k_conv<<<280, 256, 0, stream>>>(Ga, Gb, Gab, diagA, diagB);

  hipMemsetAsync(bufAll, 0, (size_t)MPASSES * 25 * 16 * 4, stream);
  hipMemsetAsync(zcArr, 0, 25 * 4, stream);
  hipMemsetAsync(mmdsum, 0, 25 * 3 * 8, stream);
  for (int t = 0; t < MPASSES; ++t)
    k_medpass<<<25 * MSHARDS, 256, 0, stream>>>(t, meta, Ga, Gb, Gab,
                                                bufAll, loArr, baseArr, zcArr);
  k_rbf<<<25 * MSHARDS, 256, 0, stream>>>(meta, Ga, Gb, Gab,
                                          bufAll, loArr, baseArr, zcArr, mmdsum);
  k_final<<<1, 64, 0, stream>>>(meta, mmdsum, out);
}